// Round 1
// baseline (387.488 us; speedup 1.0000x reference)
//
#include <hip/hip_runtime.h>
#include <stdint.h>

// Problem constants
#define S_LEN 2048
#define EMB   2048
#define NH    16
#define HD    128
#define QKV_N 6144
#define ATT_SCALE 0.08838834764831845f   // 1/sqrt(128)

typedef __attribute__((ext_vector_type(8))) short short8;   // 8 bf16 (4 VGPRs)
typedef __attribute__((ext_vector_type(4))) float f32x4;

__device__ __forceinline__ uint16_t f2b(float x){
  uint32_t u = __float_as_uint(x);
  uint32_t r = (u + 0x7fffu + ((u >> 16) & 1u)) >> 16;   // RNE
  return (uint16_t)r;
}
__device__ __forceinline__ float b2f(uint16_t h){
  return __uint_as_float(((uint32_t)h) << 16);
}
__device__ __forceinline__ void g2l16(const void* g, void* l){
  __builtin_amdgcn_global_load_lds((const __attribute__((address_space(1))) void*)g,
                                   (__attribute__((address_space(3))) void*)l, 16, 0, 0);
}

// ---------------- fp32 -> bf16 convert (8 elems/thread) ----------------
__global__ __launch_bounds__(256) void k_f32_to_bf16(const float* __restrict__ in,
                                                     uint16_t* __restrict__ out, int n8){
  int i = blockIdx.x * 256 + threadIdx.x;
  if (i >= n8) return;
  const float4* p = (const float4*)in;
  float4 a = p[2*i], b = p[2*i+1];
  union { short8 v; uint16_t u[8]; } o;
  o.u[0]=f2b(a.x); o.u[1]=f2b(a.y); o.u[2]=f2b(a.z); o.u[3]=f2b(a.w);
  o.u[4]=f2b(b.x); o.u[5]=f2b(b.y); o.u[6]=f2b(b.z); o.u[7]=f2b(b.w);
  ((short8*)out)[i] = o.v;
}

// ---------------- RoPE cos/sin tables: [2048][32] ----------------
__global__ __launch_bounds__(256) void k_tables(float* __restrict__ ct, float* __restrict__ st){
  int i = blockIdx.x * 256 + threadIdx.x;   // 65536
  int s = i >> 5, d = i & 31;
  float inv = powf(10000.0f, -(float)d / 32.0f);
  float f = (float)s * inv;
  ct[i] = cosf(f);
  st[i] = sinf(f);
}

// ---------------- GEMM: C[m,n] = sum_k A[m,k]*B[n,k] + bias[n] ----------------
// A: MxK bf16 row-major, B: NxK bf16 row-major (i.e. the x @ W^T form).
template<bool OUT_BF16>
__global__ __launch_bounds__(256) void k_gemm_bt(const uint16_t* __restrict__ A,
                                                 const uint16_t* __restrict__ B,
                                                 const float* __restrict__ bias,
                                                 void* __restrict__ C,
                                                 int M, int N, int K){
  __shared__ uint16_t As[128*64];
  __shared__ uint16_t Bs[128*64];
  const int m0 = blockIdx.x * 128;
  const int n0 = blockIdx.y * 128;
  const int tid = threadIdx.x;
  const int w = tid >> 6, l = tid & 63;
  const int wr = w >> 1, wc = w & 1;           // wave -> 64x64 quadrant
  const int g = l >> 4, c = l & 15;

  f32x4 acc[4][4] = {};

  const int srow = w*8 + (l >> 3);             // staging row within 32-row chunk
  const int scol = (l & 7) * 8;                // staging col (elements)

  for (int k0 = 0; k0 < K; k0 += 64) {
    #pragma unroll
    for (int i = 0; i < 4; ++i) {
      g2l16(A + (size_t)(m0 + i*32 + srow)*K + k0 + scol, (void*)(As + i*2048 + tid*8));
      g2l16(B + (size_t)(n0 + i*32 + srow)*K + k0 + scol, (void*)(Bs + i*2048 + tid*8));
    }
    asm volatile("s_waitcnt vmcnt(0)" ::: "memory");
    __syncthreads();
    #pragma unroll
    for (int kk = 0; kk < 2; ++kk) {
      short8 a[4], b[4];
      #pragma unroll
      for (int m = 0; m < 4; ++m)
        a[m] = *(const short8*)&As[(wr*64 + m*16 + c)*64 + kk*32 + g*8];
      #pragma unroll
      for (int n = 0; n < 4; ++n)
        b[n] = *(const short8*)&Bs[(wc*64 + n*16 + c)*64 + kk*32 + g*8];
      #pragma unroll
      for (int m = 0; m < 4; ++m)
        #pragma unroll
        for (int n = 0; n < 4; ++n)
          acc[m][n] = __builtin_amdgcn_mfma_f32_16x16x32_bf16(a[m], b[n], acc[m][n], 0, 0, 0);
    }
    __syncthreads();
  }

  #pragma unroll
  for (int n = 0; n < 4; ++n) {
    int col = n0 + wc*64 + n*16 + c;
    float bv = bias ? bias[col] : 0.0f;
    #pragma unroll
    for (int m = 0; m < 4; ++m) {
      int row0 = m0 + wr*64 + m*16 + g*4;
      #pragma unroll
      for (int j = 0; j < 4; ++j) {
        float v = acc[m][n][j] + bv;
        if (OUT_BF16) ((uint16_t*)C)[(size_t)(row0 + j)*N + col] = f2b(v);
        else          ((float*)C)[(size_t)(row0 + j)*N + col] = v;
      }
    }
  }
}

// ---------------- bias already applied in GEMM1; RoPE + head-split ----------------
// qkv: [2048][6144] bf16 (bias included). Outputs q/k/v: [16][2048][128] bf16.
__global__ __launch_bounds__(256) void k_rope_split(const uint16_t* __restrict__ qkv,
                                                    const float* __restrict__ ct,
                                                    const float* __restrict__ st,
                                                    uint16_t* __restrict__ qo,
                                                    uint16_t* __restrict__ ko,
                                                    uint16_t* __restrict__ vo){
  int idx = blockIdx.x * 256 + threadIdx.x;   // 3 * 2^22
  int which = idx >> 22;
  int rem = idx & 0x3FFFFF;
  int h = rem >> 18;
  int s = (rem >> 7) & 2047;
  int d = rem & 127;
  int srcbase = s * QKV_N + which * 2048 + h * 128;
  uint16_t* dst = which == 0 ? qo : (which == 1 ? ko : vo);
  uint16_t outv;
  if (which == 2 || d >= 64) {
    outv = qkv[srcbase + d];
  } else {
    int dd = d & 31;
    float x1 = b2f(qkv[srcbase + dd]);
    float x2 = b2f(qkv[srcbase + dd + 32]);
    float cc = ct[s*32 + dd], sn = st[s*32 + dd];
    float v = (d < 32) ? (x1*cc - x2*sn) : (x1*sn + x2*cc);
    outv = f2b(v);
  }
  dst[((size_t)(h*2048 + s) << 7) + d] = outv;
}

// ---------------- causal flash attention ----------------
// Q/K/V: [16][2048][128] bf16.  Out: [2048][2048] bf16, col = h*128 + d.
// Block: 4 waves, 64 q-rows (16/wave). K-tiles of 32.
__global__ __launch_bounds__(256) void k_attn(const uint16_t* __restrict__ Q,
                                              const uint16_t* __restrict__ Kb,
                                              const uint16_t* __restrict__ Vb,
                                              uint16_t* __restrict__ Out){
  __shared__ uint16_t Klds[32*128];     // [k][d] linear (global_load_lds)
  __shared__ uint16_t Vt[128*40];       // [d][k] padded stride 40 (16B aligned reads)
  __shared__ uint16_t Plds[4][16*40];   // per-wave P [q][k], stride 40

  const int qb = blockIdx.x, h = blockIdx.y;
  const int tid = threadIdx.x, w = tid >> 6, l = tid & 63;
  const int g = l >> 4, c = l & 15;

  const uint16_t* Qh = Q  + (size_t)h * 2048 * 128;
  const uint16_t* Kh = Kb + (size_t)h * 2048 * 128;
  const uint16_t* Vh = Vb + (size_t)h * 2048 * 128;

  // Q A-fragments (row = c), 4 chunks of K=32
  const int qrow = qb*64 + w*16 + c;
  short8 qf[4];
  #pragma unroll
  for (int t = 0; t < 4; ++t)
    qf[t] = *(const short8*)&Qh[(size_t)qrow*128 + t*32 + g*8];

  f32x4 acc[8] = {};
  float mrow[4], lrow[4];
  #pragma unroll
  for (int j = 0; j < 4; ++j) { mrow[j] = -1e30f; lrow[j] = 0.0f; }

  const int q_g4 = qb*64 + w*16 + g*4;        // C-layout row base
  const int nt = qb*2 + 2;                    // causal: k tiles up to block end
  const int vrow = tid >> 3, vd0 = (tid & 7) * 16;

  for (int kt = 0; kt < nt; ++kt) {
    const int k0 = kt * 32;
    // stage K tile (32x128) via global_load_lds, linear
    #pragma unroll
    for (int i = 0; i < 2; ++i) {
      int r = i*16 + w*4 + (l >> 4);
      g2l16(Kh + (size_t)(k0 + r)*128 + (l & 15)*8, (void*)(Klds + i*2048 + tid*8));
    }
    // stage V transposed [d][k] with pad
    {
      short8 v0 = *(const short8*)&Vh[(size_t)(k0 + vrow)*128 + vd0];
      short8 v1 = *(const short8*)&Vh[(size_t)(k0 + vrow)*128 + vd0 + 8];
      #pragma unroll
      for (int e = 0; e < 8; ++e) {
        Vt[(vd0 + e)*40 + vrow]     = (uint16_t)v0[e];
        Vt[(vd0 + 8 + e)*40 + vrow] = (uint16_t)v1[e];
      }
    }
    asm volatile("s_waitcnt vmcnt(0)" ::: "memory");
    __syncthreads();

    // QK^T: two 16-col tiles, K=128 contraction (4 mfma each)
    f32x4 s[2] = {};
    #pragma unroll
    for (int ct2 = 0; ct2 < 2; ++ct2) {
      #pragma unroll
      for (int t = 0; t < 4; ++t) {
        short8 kb = *(const short8*)&Klds[(ct2*16 + c)*128 + t*32 + g*8];
        s[ct2] = __builtin_amdgcn_mfma_f32_16x16x32_bf16(qf[t], kb, s[ct2], 0, 0, 0);
      }
    }

    // online softmax per row (rows 4g+j, cols across 16 lanes)
    #pragma unroll
    for (int j = 0; j < 4; ++j) {
      int q = q_g4 + j;
      float v0 = s[0][j] * ATT_SCALE, v1 = s[1][j] * ATT_SCALE;
      if (k0 + c > q)      v0 = -1e30f;
      if (k0 + 16 + c > q) v1 = -1e30f;
      float t = fmaxf(v0, v1);
      #pragma unroll
      for (int dlt = 1; dlt < 16; dlt <<= 1) t = fmaxf(t, __shfl_xor(t, dlt, 64));
      float mnew = fmaxf(mrow[j], t);
      float sc = __expf(mrow[j] - mnew);
      float p0 = __expf(v0 - mnew);
      float p1 = __expf(v1 - mnew);
      float rs = p0 + p1;
      #pragma unroll
      for (int dlt = 1; dlt < 16; dlt <<= 1) rs += __shfl_xor(rs, dlt, 64);
      lrow[j] = lrow[j]*sc + rs;
      mrow[j] = mnew;
      #pragma unroll
      for (int n = 0; n < 8; ++n) acc[n][j] *= sc;
      Plds[w][(g*4 + j)*40 + c]      = f2b(p0);
      Plds[w][(g*4 + j)*40 + 16 + c] = f2b(p1);
    }

    // PV: P (16x32) x V (32x128)
    short8 pf = *(const short8*)&Plds[w][c*40 + g*8];
    #pragma unroll
    for (int n = 0; n < 8; ++n) {
      short8 vf = *(const short8*)&Vt[(n*16 + c)*40 + g*8];
      acc[n] = __builtin_amdgcn_mfma_f32_16x16x32_bf16(pf, vf, acc[n], 0, 0, 0);
    }
    __syncthreads();
  }

  // epilogue: divide by l, write bf16
  #pragma unroll
  for (int j = 0; j < 4; ++j) {
    int q = q_g4 + j;
    float inv = 1.0f / lrow[j];
    #pragma unroll
    for (int n = 0; n < 8; ++n) {
      int dcol = n*16 + c;
      Out[(size_t)q*2048 + h*128 + dcol] = f2b(acc[n][j] * inv);
    }
  }
}

extern "C" void kernel_launch(void* const* d_in, const int* in_sizes, int n_in,
                              void* d_out, int out_size, void* d_ws, size_t ws_size,
                              hipStream_t stream){
  const float* x    = (const float*)d_in[0];
  const float* Wqkv = (const float*)d_in[1];
  const float* bqkv = (const float*)d_in[2];
  const float* Wo   = (const float*)d_in[3];
  const float* bo   = (const float*)d_in[4];

  char* ws = (char*)d_ws;
  uint16_t* q_bf    = (uint16_t*)(ws);                 //  8.39 MB [16][2048][128]
  uint16_t* k_bf    = (uint16_t*)(ws + 8388608);       //  8.39 MB
  uint16_t* v_bf    = (uint16_t*)(ws + 16777216);      //  8.39 MB
  uint16_t* attn_bf = (uint16_t*)(ws + 25165824);      //  8.39 MB (aliased with x_bf)
  uint16_t* x_bf    = attn_bf;                         //  x dead before attn writes
  uint16_t* wqkv_bf = (uint16_t*)(ws + 33554432);      // 25.17 MB
  uint16_t* wo_bf   = (uint16_t*)(ws + 58720256);      //  8.39 MB
  uint16_t* qkv_bf  = (uint16_t*)(ws + 67108864);      // 25.17 MB
  float*    cos_t   = (float*)(ws + 92274688);         //  0.26 MB
  float*    sin_t   = (float*)(ws + 92536832);         //  0.26 MB

  k_tables<<<dim3(256), dim3(256), 0, stream>>>(cos_t, sin_t);
  k_f32_to_bf16<<<dim3(2048), dim3(256), 0, stream>>>(x, x_bf, 524288);
  k_f32_to_bf16<<<dim3(6144), dim3(256), 0, stream>>>(Wqkv, wqkv_bf, 1572864);
  k_f32_to_bf16<<<dim3(2048), dim3(256), 0, stream>>>(Wo, wo_bf, 524288);

  // qkv = x @ Wqkv^T + b   -> bf16 [2048][6144]
  k_gemm_bt<true><<<dim3(16, 48), dim3(256), 0, stream>>>(x_bf, wqkv_bf, bqkv,
                                                          (void*)qkv_bf, 2048, 6144, 2048);
  // RoPE + split to [h][s][d]
  k_rope_split<<<dim3(49152), dim3(256), 0, stream>>>(qkv_bf, cos_t, sin_t, q_bf, k_bf, v_bf);
  // causal flash attention -> attn_bf [2048][2048]
  k_attn<<<dim3(32, 16), dim3(256), 0, stream>>>(q_bf, k_bf, v_bf, attn_bf);
  // out = attn @ Wo^T + bo -> f32 d_out
  k_gemm_bt<false><<<dim3(16, 16), dim3(256), 0, stream>>>(attn_bf, wo_bf, bo,
                                                           d_out, 2048, 2048, 2048);
}

// Round 2
// 259.248 us; speedup vs baseline: 1.4947x; 1.4947x over previous
//
#include <hip/hip_runtime.h>
#include <stdint.h>

// Problem constants
#define QKV_N 6144
#define ATT_SCALE 0.08838834764831845f   // 1/sqrt(128)

typedef __attribute__((ext_vector_type(8))) short short8;   // 8 bf16 (4 VGPRs)
typedef __attribute__((ext_vector_type(4))) float f32x4;

__device__ __forceinline__ uint16_t f2b(float x){
  uint32_t u = __float_as_uint(x);
  uint32_t r = (u + 0x7fffu + ((u >> 16) & 1u)) >> 16;   // RNE
  return (uint16_t)r;
}
__device__ __forceinline__ float b2f(uint16_t h){
  return __uint_as_float(((uint32_t)h) << 16);
}
__device__ __forceinline__ void g2l16(const void* g, void* l){
  __builtin_amdgcn_global_load_lds((const __attribute__((address_space(1))) void*)g,
                                   (__attribute__((address_space(3))) void*)l, 16, 0, 0);
}

// ---------------- fp32 -> bf16 convert (8 elems/thread) ----------------
__global__ __launch_bounds__(256) void k_f32_to_bf16(const float* __restrict__ in,
                                                     uint16_t* __restrict__ out, int n8){
  int i = blockIdx.x * 256 + threadIdx.x;
  if (i >= n8) return;
  const float4* p = (const float4*)in;
  float4 a = p[2*i], b = p[2*i+1];
  union { short8 v; uint16_t u[8]; } o;
  o.u[0]=f2b(a.x); o.u[1]=f2b(a.y); o.u[2]=f2b(a.z); o.u[3]=f2b(a.w);
  o.u[4]=f2b(b.x); o.u[5]=f2b(b.y); o.u[6]=f2b(b.z); o.u[7]=f2b(b.w);
  ((short8*)out)[i] = o.v;
}

// ---------------- RoPE cos/sin tables: [2048][32] ----------------
__global__ __launch_bounds__(256) void k_tables(float* __restrict__ ct, float* __restrict__ st){
  int i = blockIdx.x * 256 + threadIdx.x;   // 65536
  int s = i >> 5, d = i & 31;
  float inv = __expf(-(float)d * (9.210340371976184f / 32.0f));  // 10000^(-d/32)
  float f = (float)s * inv;
  ct[i] = cosf(f);
  st[i] = sinf(f);
}

// ---------------- GEMM: C[m,n] = sum_k A[m,k]*B[n,k] + bias[n] ----------------
template<bool OUT_BF16>
__global__ __launch_bounds__(256) void k_gemm_bt(const uint16_t* __restrict__ A,
                                                 const uint16_t* __restrict__ B,
                                                 const float* __restrict__ bias,
                                                 void* __restrict__ C,
                                                 int M, int N, int K){
  __shared__ uint16_t As[128*64];
  __shared__ uint16_t Bs[128*64];
  const int m0 = blockIdx.x * 128;
  const int n0 = blockIdx.y * 128;
  const int tid = threadIdx.x;
  const int w = tid >> 6, l = tid & 63;
  const int wr = w >> 1, wc = w & 1;
  const int g = l >> 4, c = l & 15;

  f32x4 acc[4][4] = {};

  const int srow = w*8 + (l >> 3);
  const int scol = (l & 7) * 8;

  for (int k0 = 0; k0 < K; k0 += 64) {
    #pragma unroll
    for (int i = 0; i < 4; ++i) {
      g2l16(A + (size_t)(m0 + i*32 + srow)*K + k0 + scol, (void*)(As + i*2048 + tid*8));
      g2l16(B + (size_t)(n0 + i*32 + srow)*K + k0 + scol, (void*)(Bs + i*2048 + tid*8));
    }
    asm volatile("s_waitcnt vmcnt(0)" ::: "memory");
    __syncthreads();
    #pragma unroll
    for (int kk = 0; kk < 2; ++kk) {
      short8 a[4], b[4];
      #pragma unroll
      for (int m = 0; m < 4; ++m)
        a[m] = *(const short8*)&As[(wr*64 + m*16 + c)*64 + kk*32 + g*8];
      #pragma unroll
      for (int n = 0; n < 4; ++n)
        b[n] = *(const short8*)&Bs[(wc*64 + n*16 + c)*64 + kk*32 + g*8];
      #pragma unroll
      for (int m = 0; m < 4; ++m)
        #pragma unroll
        for (int n = 0; n < 4; ++n)
          acc[m][n] = __builtin_amdgcn_mfma_f32_16x16x32_bf16(a[m], b[n], acc[m][n], 0, 0, 0);
    }
    __syncthreads();
  }

  #pragma unroll
  for (int n = 0; n < 4; ++n) {
    int col = n0 + wc*64 + n*16 + c;
    float bv = bias ? bias[col] : 0.0f;
    #pragma unroll
    for (int m = 0; m < 4; ++m) {
      int row0 = m0 + wr*64 + m*16 + g*4;
      #pragma unroll
      for (int j = 0; j < 4; ++j) {
        float v = acc[m][n][j] + bv;
        if (OUT_BF16) ((uint16_t*)C)[(size_t)(row0 + j)*N + col] = f2b(v);
        else          ((float*)C)[(size_t)(row0 + j)*N + col] = v;
      }
    }
  }
}

// ---------------- RoPE + head-split for Q,K (V handled by k_vt) ----------------
// qkv: [2048][6144] bf16 (bias included). Outputs q/k: [16][2048][128] bf16.
// Q is pre-scaled by 1/sqrt(D). 8 elems per thread.
__global__ __launch_bounds__(256) void k_rope_split(const uint16_t* __restrict__ qkv,
                                                    const float* __restrict__ ct,
                                                    const float* __restrict__ st,
                                                    uint16_t* __restrict__ qo,
                                                    uint16_t* __restrict__ ko){
  int idx = blockIdx.x * 256 + threadIdx.x;   // which(2) x h(16) x s(2048) x db(16) = 2^20
  int db = idx & 15;
  int s  = (idx >> 4) & 2047;
  int h  = (idx >> 15) & 15;
  int which = idx >> 19;
  const uint16_t* src = qkv + (size_t)s * QKV_N + which * 2048 + h * 128;
  uint16_t* dst = (which ? ko : qo) + (((size_t)(h*2048 + s)) << 7) + db*8;
  const float scale = which ? 1.0f : ATT_SCALE;
  int d0 = db * 8;
  union { short8 v; uint16_t u[8]; } o;
  if (d0 >= 64) {
    short8 xv = *(const short8*)(src + d0);
    #pragma unroll
    for (int e = 0; e < 8; ++e) o.u[e] = f2b(b2f((uint16_t)xv[e]) * scale);
  } else {
    int dd = d0 & 31;
    short8 a = *(const short8*)(src + dd);
    short8 b = *(const short8*)(src + dd + 32);
    float4 c0 = *(const float4*)(ct + s*32 + dd);
    float4 c1 = *(const float4*)(ct + s*32 + dd + 4);
    float4 s0 = *(const float4*)(st + s*32 + dd);
    float4 s1 = *(const float4*)(st + s*32 + dd + 4);
    float cc[8] = {c0.x,c0.y,c0.z,c0.w,c1.x,c1.y,c1.z,c1.w};
    float ss[8] = {s0.x,s0.y,s0.z,s0.w,s1.x,s1.y,s1.z,s1.w};
    #pragma unroll
    for (int e = 0; e < 8; ++e) {
      float x1 = b2f((uint16_t)a[e]), x2 = b2f((uint16_t)b[e]);
      float v = (d0 < 32) ? (x1*cc[e] - x2*ss[e]) : (x1*ss[e] + x2*cc[e]);
      o.u[e] = f2b(v * scale);
    }
  }
  *(short8*)dst = o.v;
}

// ---------------- V transpose: qkv[s][4096+h*128+d] -> vt[h][d][s] ----------------
__global__ __launch_bounds__(256) void k_vt(const uint16_t* __restrict__ qkv,
                                            uint16_t* __restrict__ vt){
  __shared__ uint16_t tl[64][80];
  const int b = blockIdx.x;                 // h(16) x dt(2) x st(32)
  const int st_ = b & 31, dt = (b >> 5) & 1, h = b >> 6;
  const int tid = threadIdx.x;
  const int s_l = tid >> 2, cch = (tid & 3) * 16;
  const uint16_t* src = qkv + (size_t)(st_*64 + s_l) * QKV_N + 4096 + h*128 + dt*64 + cch;
  short8 a = *(const short8*)src;
  short8 b2 = *(const short8*)(src + 8);
  #pragma unroll
  for (int e = 0; e < 8; ++e) {
    tl[cch + e][s_l]     = (uint16_t)a[e];
    tl[cch + 8 + e][s_l] = (uint16_t)b2[e];
  }
  __syncthreads();
  const int d_l = tid >> 2;
  uint16_t* dst = vt + ((size_t)h << 18) + (size_t)(dt*64 + d_l) * 2048 + st_*64 + cch;
  *(short8*)dst       = *(const short8*)&tl[d_l][cch];
  *(short8*)(dst + 8) = *(const short8*)&tl[d_l][cch + 8];
}

// ---------------- causal flash attention v2 ----------------
// Q/K: [16][2048][128] bf16 (Q pre-scaled). Vt: [16][128][2048] bf16.
// Out: [2048][2048] bf16, col = h*128 + d.
// Block: 2 waves, 32 q-rows (16/wave). KV tiles of 64, double-buffered,
// XOR-swizzled LDS (pre-swizzled global source, swizzled ds_read).
// Causal balancing: block (pair,h) does q-tiles {pair, 63-pair} -> 33 KV-tiles each.
__global__ __launch_bounds__(128) void k_attn(const uint16_t* __restrict__ Q,
                                              const uint16_t* __restrict__ Kb,
                                              const uint16_t* __restrict__ Vtg,
                                              uint16_t* __restrict__ Out){
  __shared__ uint16_t Ks[2][64*128];   // [k][d] rows 256B, swizzled
  __shared__ uint16_t Vs[2][128*64];   // [d][k] rows 128B, swizzled
  __shared__ uint16_t Ps[2][16*80];    // per-wave P [q][k], stride 80 elems

  const int pair = blockIdx.x;         // 0..31
  const int h = blockIdx.y;
  const int tid = threadIdx.x, w = tid >> 6, l = tid & 63;
  const int g = l >> 4, c = l & 15;
  const int swz = (c & 7) << 4;        // read-side byte swizzle

  const uint16_t* __restrict__ Qh = Q   + ((size_t)h << 18);
  const uint16_t* __restrict__ Kh = Kb  + ((size_t)h << 18);
  const uint16_t* __restrict__ Vh = Vtg + ((size_t)h << 18);

  // per-thread staging source offsets (pre-swizzled), elems
  int koff[8], voff[8];
  #pragma unroll
  for (int j = 0; j < 8; ++j) {
    int r = j*8 + w*4 + (l >> 4);                       // K row in tile
    koff[j] = r*128 + (((l & 15) ^ (r & 7)) << 3);
    int d = j*16 + w*8 + (l >> 3);                      // V^T row (d)
    voff[j] = d*2048 + (((l & 7) ^ (d & 7)) << 3);
  }

  #pragma unroll 1
  for (int half = 0; half < 2; ++half) {
    const int qt = half ? (63 - pair) : pair;
    const int nt = (qt >> 1) + 1;
    const int qrow = qt*32 + w*16 + c;

    short8 qf[4];
    #pragma unroll
    for (int t = 0; t < 4; ++t)
      qf[t] = *(const short8*)&Qh[(size_t)qrow*128 + t*32 + g*8];

    f32x4 acc[8] = {};
    float mrow[4], lrow[4];
    #pragma unroll
    for (int j = 0; j < 4; ++j) { mrow[j] = -3e38f; lrow[j] = 0.0f; }

    // prologue: stage tile 0 -> buf 0
    #pragma unroll
    for (int j = 0; j < 8; ++j) {
      g2l16(Kh + koff[j], (void*)(&Ks[0][0] + j*1024 + tid*8));
      g2l16(Vh + voff[j], (void*)(&Vs[0][0] + j*1024 + tid*8));
    }
    asm volatile("s_waitcnt vmcnt(0)" ::: "memory");
    __syncthreads();

    for (int kt = 0; kt < nt; ++kt) {
      const int cur = kt & 1;
      const int k0 = kt * 64;
      // issue next tile's loads early (land before the end-of-iter barrier)
      if (kt + 1 < nt) {
        const int k1 = k0 + 64;
        #pragma unroll
        for (int j = 0; j < 8; ++j) {
          g2l16(Kh + (size_t)k1*128 + koff[j], (void*)(&Ks[cur^1][0] + j*1024 + tid*8));
          g2l16(Vh + k1 + voff[j],             (void*)(&Vs[cur^1][0] + j*1024 + tid*8));
        }
      }

      // QK^T: 16x64 scores, K=128 contraction
      f32x4 sc4[4] = {};
      #pragma unroll
      for (int ct2 = 0; ct2 < 4; ++ct2) {
        const char* krp = (const char*)&Ks[cur][0] + (ct2*16 + c)*256;
        #pragma unroll
        for (int t = 0; t < 4; ++t) {
          short8 kb = *(const short8*)(krp + ((t*64 + g*16) ^ swz));
          sc4[ct2] = __builtin_amdgcn_mfma_f32_16x16x32_bf16(qf[t], kb, sc4[ct2], 0, 0, 0);
        }
      }

      // online softmax (rows g*4+j across 16 lanes)
      const bool lastt = (kt == nt - 1);
      #pragma unroll
      for (int j = 0; j < 4; ++j) {
        const int qg = qt*32 + w*16 + g*4 + j;
        float v0 = sc4[0][j], v1 = sc4[1][j], v2 = sc4[2][j], v3 = sc4[3][j];
        if (lastt) {
          if (k0 +      c > qg) v0 = -3e38f;
          if (k0 + 16 + c > qg) v1 = -3e38f;
          if (k0 + 32 + c > qg) v2 = -3e38f;
          if (k0 + 48 + c > qg) v3 = -3e38f;
        }
        float t0 = fmaxf(fmaxf(v0, v1), fmaxf(v2, v3));
        #pragma unroll
        for (int d2 = 1; d2 < 16; d2 <<= 1) t0 = fmaxf(t0, __shfl_xor(t0, d2, 64));
        const float mn = fmaxf(mrow[j], t0);
        const float scl = __expf(mrow[j] - mn);
        const float p0 = __expf(v0 - mn), p1 = __expf(v1 - mn),
                    p2 = __expf(v2 - mn), p3 = __expf(v3 - mn);
        float rs = (p0 + p1) + (p2 + p3);
        #pragma unroll
        for (int d2 = 1; d2 < 16; d2 <<= 1) rs += __shfl_xor(rs, d2, 64);
        lrow[j] = lrow[j]*scl + rs;
        mrow[j] = mn;
        #pragma unroll
        for (int n = 0; n < 8; ++n) acc[n][j] *= scl;
        uint16_t* pw = &Ps[w][(g*4 + j)*80];
        pw[c] = f2b(p0); pw[16+c] = f2b(p1); pw[32+c] = f2b(p2); pw[48+c] = f2b(p3);
      }

      // PV: P(16x64) x V(64x128)
      #pragma unroll
      for (int kk = 0; kk < 2; ++kk) {
        short8 pf = *(const short8*)&Ps[w][c*80 + kk*32 + g*8];
        #pragma unroll
        for (int n = 0; n < 8; ++n) {
          const char* vrp = (const char*)&Vs[cur][0] + (n*16 + c)*128;
          short8 vf = *(const short8*)(vrp + ((kk*64 + g*16) ^ swz));
          acc[n] = __builtin_amdgcn_mfma_f32_16x16x32_bf16(pf, vf, acc[n], 0, 0, 0);
        }
      }

      asm volatile("s_waitcnt vmcnt(0)" ::: "memory");
      __syncthreads();
    }

    // epilogue
    #pragma unroll
    for (int j = 0; j < 4; ++j) {
      const int qg = qt*32 + w*16 + g*4 + j;
      const float inv = 1.0f / lrow[j];
      #pragma unroll
      for (int n = 0; n < 8; ++n)
        Out[(size_t)qg*2048 + h*128 + n*16 + c] = f2b(acc[n][j] * inv);
    }
  }
}

extern "C" void kernel_launch(void* const* d_in, const int* in_sizes, int n_in,
                              void* d_out, int out_size, void* d_ws, size_t ws_size,
                              hipStream_t stream){
  const float* x    = (const float*)d_in[0];
  const float* Wqkv = (const float*)d_in[1];
  const float* bqkv = (const float*)d_in[2];
  const float* Wo   = (const float*)d_in[3];
  const float* bo   = (const float*)d_in[4];

  char* ws = (char*)d_ws;
  uint16_t* q_bf    = (uint16_t*)(ws);                 //  8.39 MB [16][2048][128]
  uint16_t* k_bf    = (uint16_t*)(ws + 8388608);       //  8.39 MB [16][2048][128]
  uint16_t* vt_bf   = (uint16_t*)(ws + 16777216);      //  8.39 MB [16][128][2048]
  uint16_t* attn_bf = (uint16_t*)(ws + 25165824);      //  8.39 MB (aliased with x_bf)
  uint16_t* x_bf    = attn_bf;                         //  x dead before attn writes
  uint16_t* wqkv_bf = (uint16_t*)(ws + 33554432);      // 25.17 MB
  uint16_t* wo_bf   = (uint16_t*)(ws + 58720256);      //  8.39 MB
  uint16_t* qkv_bf  = (uint16_t*)(ws + 67108864);      // 25.17 MB
  float*    cos_t   = (float*)(ws + 92274688);         //  0.26 MB
  float*    sin_t   = (float*)(ws + 92536832);         //  0.26 MB

  k_tables<<<dim3(256), dim3(256), 0, stream>>>(cos_t, sin_t);
  k_f32_to_bf16<<<dim3(2048), dim3(256), 0, stream>>>(x, x_bf, 524288);
  k_f32_to_bf16<<<dim3(6144), dim3(256), 0, stream>>>(Wqkv, wqkv_bf, 1572864);
  k_f32_to_bf16<<<dim3(2048), dim3(256), 0, stream>>>(Wo, wo_bf, 524288);

  // qkv = x @ Wqkv^T + b   -> bf16 [2048][6144]
  k_gemm_bt<true><<<dim3(16, 48), dim3(256), 0, stream>>>(x_bf, wqkv_bf, bqkv,
                                                          (void*)qkv_bf, 2048, 6144, 2048);
  // RoPE + split Q,K (Q pre-scaled); V transposed to [h][d][s]
  k_rope_split<<<dim3(4096), dim3(256), 0, stream>>>(qkv_bf, cos_t, sin_t, q_bf, k_bf);
  k_vt<<<dim3(1024), dim3(256), 0, stream>>>(qkv_bf, vt_bf);
  // causal flash attention -> attn_bf [2048][2048]
  k_attn<<<dim3(32, 16), dim3(128), 0, stream>>>(q_bf, k_bf, vt_bf, attn_bf);
  // out = attn @ Wo^T + bo -> f32 d_out
  k_gemm_bt<false><<<dim3(16, 16), dim3(256), 0, stream>>>(attn_bf, wo_bf, bo,
                                                           d_out, 2048, 2048, 2048);
}

// Round 3
// 241.944 us; speedup vs baseline: 1.6016x; 1.0715x over previous
//
#include <hip/hip_runtime.h>
#include <stdint.h>

// Problem constants
#define QKV_N 6144
#define ATT_SCALE 0.08838834764831845f   // 1/sqrt(128)

typedef __attribute__((ext_vector_type(8))) short short8;   // 8 bf16 (4 VGPRs)
typedef __attribute__((ext_vector_type(4))) float f32x4;

__device__ __forceinline__ uint16_t f2b(float x){
  uint32_t u = __float_as_uint(x);
  uint32_t r = (u + 0x7fffu + ((u >> 16) & 1u)) >> 16;   // RNE
  return (uint16_t)r;
}
__device__ __forceinline__ float b2f(uint16_t h){
  return __uint_as_float(((uint32_t)h) << 16);
}
__device__ __forceinline__ void g2l16(const void* g, void* l){
  __builtin_amdgcn_global_load_lds((const __attribute__((address_space(1))) void*)g,
                                   (__attribute__((address_space(3))) void*)l, 16, 0, 0);
}

// ---------------- fp32 -> bf16 convert (8 elems/thread) ----------------
__global__ __launch_bounds__(256) void k_f32_to_bf16(const float* __restrict__ in,
                                                     uint16_t* __restrict__ out, int n8){
  int i = blockIdx.x * 256 + threadIdx.x;
  if (i >= n8) return;
  const float4* p = (const float4*)in;
  float4 a = p[2*i], b = p[2*i+1];
  union { short8 v; uint16_t u[8]; } o;
  o.u[0]=f2b(a.x); o.u[1]=f2b(a.y); o.u[2]=f2b(a.z); o.u[3]=f2b(a.w);
  o.u[4]=f2b(b.x); o.u[5]=f2b(b.y); o.u[6]=f2b(b.z); o.u[7]=f2b(b.w);
  ((short8*)out)[i] = o.v;
}

// ---------------- RoPE cos/sin tables: [2048][32] ----------------
__global__ __launch_bounds__(256) void k_tables(float* __restrict__ ct, float* __restrict__ st){
  int i = blockIdx.x * 256 + threadIdx.x;   // 65536
  int s = i >> 5, d = i & 31;
  float inv = __expf(-(float)d * (9.210340371976184f / 32.0f));  // 10000^(-d/32)
  float f = (float)s * inv;
  ct[i] = cosf(f);
  st[i] = sinf(f);
}

// ---------------- 256x256 8-phase GEMM (bf16 out): C = A @ B^T + bias ----------------
// A: MxK bf16, B: NxK bf16 row-major. 8 waves (2Mx4N), BK=64, 128KB LDS dbuf.
// T2 swizzle: linear global_load_lds dest + inverse-swizzled global source
// (16B slot ^= row&7) + same XOR on ds_read. T5 setprio around MFMA clusters.
__global__ __launch_bounds__(512, 1) void k_gemm256(const uint16_t* __restrict__ A,
                                                    const uint16_t* __restrict__ B,
                                                    const float* __restrict__ bias,
                                                    uint16_t* __restrict__ C,
                                                    int M, int N, int K, int nbm){
  __shared__ uint16_t As[2][256*64];
  __shared__ uint16_t Bs[2][256*64];

  // XCD-aware bijective swizzle (nwg % 8 == 0): each XCD gets contiguous chunk
  const int nwg = gridDim.x;
  const int wg = blockIdx.x;
  const int lin = (wg & 7) * (nwg >> 3) + (wg >> 3);
  const int m0 = (lin % nbm) * 256;
  const int n0 = (lin / nbm) * 256;

  const int tid = threadIdx.x;
  const int wid = tid >> 6, l = tid & 63;
  const int wm = wid >> 2, wn = wid & 3;       // 2 x 4 wave grid
  const int g = l >> 4, c = l & 15;
  const int rsw = c & 7;                       // read-side slot swizzle (row&7 == c&7)

  // staging: thread -> (row = tid>>3, slot = tid&7) within each 64-row issue
  const int srow = tid >> 3;
  const int sk = ((tid & 7) ^ (srow & 7)) << 3;   // pre-swizzled source col (elems)
  const uint16_t* Ap = A + (size_t)(m0 + srow) * K + sk;
  const uint16_t* Bp = B + (size_t)(n0 + srow) * K + sk;

  f32x4 acc[8][4] = {};

  const int NT = K >> 6;
  // prologue: stage tile 0 -> buf 0
  #pragma unroll
  for (int j = 0; j < 4; ++j) {
    g2l16(Ap + (size_t)j*64*K, (void*)(&As[0][0] + j*4096 + tid*8));
    g2l16(Bp + (size_t)j*64*K, (void*)(&Bs[0][0] + j*4096 + tid*8));
  }
  asm volatile("s_waitcnt vmcnt(0)" ::: "memory");
  __syncthreads();

  const int abase = wm*128 + c;
  const int bbase = wn*64 + c;

  for (int kt = 0; kt < NT; ++kt) {
    const int cur = kt & 1;
    const uint16_t* __restrict__ Asc = &As[cur][0];
    const uint16_t* __restrict__ Bsc = &Bs[cur][0];
    short8 a[8], b0[4], b1[4];

    // ---- phase 0: issue next-tile stage early; read A(mi0-3), B(ni0-1); MFMA Q00
    if (kt + 1 < NT) {
      const size_t ko = (size_t)(kt + 1) * 64;
      #pragma unroll
      for (int j = 0; j < 4; ++j) {
        g2l16(Ap + (size_t)j*64*K + ko, (void*)(&As[cur^1][0] + j*4096 + tid*8));
        g2l16(Bp + (size_t)j*64*K + ko, (void*)(&Bs[cur^1][0] + j*4096 + tid*8));
      }
    }
    #pragma unroll
    for (int mi = 0; mi < 4; ++mi)
      #pragma unroll
      for (int kk = 0; kk < 2; ++kk)
        a[mi*2+kk] = *(const short8*)&Asc[(abase + mi*16)*64 + (((kk*4+g) ^ rsw) << 3)];
    #pragma unroll
    for (int ni = 0; ni < 2; ++ni)
      #pragma unroll
      for (int kk = 0; kk < 2; ++kk)
        b0[ni*2+kk] = *(const short8*)&Bsc[(bbase + ni*16)*64 + (((kk*4+g) ^ rsw) << 3)];
    __builtin_amdgcn_s_barrier();
    __builtin_amdgcn_s_setprio(1);
    #pragma unroll
    for (int mi = 0; mi < 4; ++mi)
      #pragma unroll
      for (int ni = 0; ni < 2; ++ni)
        #pragma unroll
        for (int kk = 0; kk < 2; ++kk)
          acc[mi][ni] = __builtin_amdgcn_mfma_f32_16x16x32_bf16(a[mi*2+kk], b0[ni*2+kk], acc[mi][ni], 0, 0, 0);
    __builtin_amdgcn_s_setprio(0);
    __builtin_amdgcn_s_barrier();

    // ---- phase 1: read B(ni2-3); MFMA Q01
    #pragma unroll
    for (int ni = 0; ni < 2; ++ni)
      #pragma unroll
      for (int kk = 0; kk < 2; ++kk)
        b1[ni*2+kk] = *(const short8*)&Bsc[(bbase + (ni+2)*16)*64 + (((kk*4+g) ^ rsw) << 3)];
    __builtin_amdgcn_s_barrier();
    __builtin_amdgcn_s_setprio(1);
    #pragma unroll
    for (int mi = 0; mi < 4; ++mi)
      #pragma unroll
      for (int ni = 0; ni < 2; ++ni)
        #pragma unroll
        for (int kk = 0; kk < 2; ++kk)
          acc[mi][ni+2] = __builtin_amdgcn_mfma_f32_16x16x32_bf16(a[mi*2+kk], b1[ni*2+kk], acc[mi][ni+2], 0, 0, 0);
    __builtin_amdgcn_s_setprio(0);
    __builtin_amdgcn_s_barrier();

    // ---- phase 2: read A(mi4-7); MFMA Q11 (reuse b1)
    #pragma unroll
    for (int mi = 0; mi < 4; ++mi)
      #pragma unroll
      for (int kk = 0; kk < 2; ++kk)
        a[mi*2+kk] = *(const short8*)&Asc[(abase + (mi+4)*16)*64 + (((kk*4+g) ^ rsw) << 3)];
    __builtin_amdgcn_s_barrier();
    __builtin_amdgcn_s_setprio(1);
    #pragma unroll
    for (int mi = 0; mi < 4; ++mi)
      #pragma unroll
      for (int ni = 0; ni < 2; ++ni)
        #pragma unroll
        for (int kk = 0; kk < 2; ++kk)
          acc[mi+4][ni+2] = __builtin_amdgcn_mfma_f32_16x16x32_bf16(a[mi*2+kk], b1[ni*2+kk], acc[mi+4][ni+2], 0, 0, 0);
    __builtin_amdgcn_s_setprio(0);
    __builtin_amdgcn_s_barrier();

    // ---- phase 3: MFMA Q10 (reuse a(mi4-7), b0)
    __builtin_amdgcn_s_setprio(1);
    #pragma unroll
    for (int mi = 0; mi < 4; ++mi)
      #pragma unroll
      for (int ni = 0; ni < 2; ++ni)
        #pragma unroll
        for (int kk = 0; kk < 2; ++kk)
          acc[mi+4][ni] = __builtin_amdgcn_mfma_f32_16x16x32_bf16(a[mi*2+kk], b0[ni*2+kk], acc[mi+4][ni], 0, 0, 0);
    __builtin_amdgcn_s_setprio(0);

    // ---- tile boundary: next-tile stage must have landed
    asm volatile("s_waitcnt vmcnt(0)" ::: "memory");
    __syncthreads();
  }

  // epilogue: bias + bf16 store
  #pragma unroll
  for (int ni = 0; ni < 4; ++ni) {
    const int col = n0 + wn*64 + ni*16 + c;
    const float bv = bias[col];
    #pragma unroll
    for (int mi = 0; mi < 8; ++mi) {
      const int row0 = m0 + wm*128 + mi*16 + g*4;
      #pragma unroll
      for (int j = 0; j < 4; ++j)
        C[(size_t)(row0 + j)*N + col] = f2b(acc[mi][ni][j] + bv);
    }
  }
}

// ---------------- GEMM: C[m,n] = sum_k A[m,k]*B[n,k] + bias[n] (128^2 tile) ----------------
template<bool OUT_BF16>
__global__ __launch_bounds__(256) void k_gemm_bt(const uint16_t* __restrict__ A,
                                                 const uint16_t* __restrict__ B,
                                                 const float* __restrict__ bias,
                                                 void* __restrict__ C,
                                                 int M, int N, int K){
  __shared__ uint16_t As[128*64];
  __shared__ uint16_t Bs[128*64];
  const int m0 = blockIdx.x * 128;
  const int n0 = blockIdx.y * 128;
  const int tid = threadIdx.x;
  const int w = tid >> 6, l = tid & 63;
  const int wr = w >> 1, wc = w & 1;
  const int g = l >> 4, c = l & 15;

  f32x4 acc[4][4] = {};

  const int srow = w*8 + (l >> 3);
  const int scol = (l & 7) * 8;

  for (int k0 = 0; k0 < K; k0 += 64) {
    #pragma unroll
    for (int i = 0; i < 4; ++i) {
      g2l16(A + (size_t)(m0 + i*32 + srow)*K + k0 + scol, (void*)(As + i*2048 + tid*8));
      g2l16(B + (size_t)(n0 + i*32 + srow)*K + k0 + scol, (void*)(Bs + i*2048 + tid*8));
    }
    asm volatile("s_waitcnt vmcnt(0)" ::: "memory");
    __syncthreads();
    #pragma unroll
    for (int kk = 0; kk < 2; ++kk) {
      short8 a[4], b[4];
      #pragma unroll
      for (int m = 0; m < 4; ++m)
        a[m] = *(const short8*)&As[(wr*64 + m*16 + c)*64 + kk*32 + g*8];
      #pragma unroll
      for (int n = 0; n < 4; ++n)
        b[n] = *(const short8*)&Bs[(wc*64 + n*16 + c)*64 + kk*32 + g*8];
      #pragma unroll
      for (int m = 0; m < 4; ++m)
        #pragma unroll
        for (int n = 0; n < 4; ++n)
          acc[m][n] = __builtin_amdgcn_mfma_f32_16x16x32_bf16(a[m], b[n], acc[m][n], 0, 0, 0);
    }
    __syncthreads();
  }

  #pragma unroll
  for (int n = 0; n < 4; ++n) {
    int col = n0 + wc*64 + n*16 + c;
    float bv = bias ? bias[col] : 0.0f;
    #pragma unroll
    for (int m = 0; m < 4; ++m) {
      int row0 = m0 + wr*64 + m*16 + g*4;
      #pragma unroll
      for (int j = 0; j < 4; ++j) {
        float v = acc[m][n][j] + bv;
        if (OUT_BF16) ((uint16_t*)C)[(size_t)(row0 + j)*N + col] = f2b(v);
        else          ((float*)C)[(size_t)(row0 + j)*N + col] = v;
      }
    }
  }
}

// ---------------- RoPE + head-split for Q,K (V handled by k_vt) ----------------
__global__ __launch_bounds__(256) void k_rope_split(const uint16_t* __restrict__ qkv,
                                                    const float* __restrict__ ct,
                                                    const float* __restrict__ st,
                                                    uint16_t* __restrict__ qo,
                                                    uint16_t* __restrict__ ko){
  int idx = blockIdx.x * 256 + threadIdx.x;   // which(2) x h(16) x s(2048) x db(16) = 2^20
  int db = idx & 15;
  int s  = (idx >> 4) & 2047;
  int h  = (idx >> 15) & 15;
  int which = idx >> 19;
  const uint16_t* src = qkv + (size_t)s * QKV_N + which * 2048 + h * 128;
  uint16_t* dst = (which ? ko : qo) + (((size_t)(h*2048 + s)) << 7) + db*8;
  const float scale = which ? 1.0f : ATT_SCALE;
  int d0 = db * 8;
  union { short8 v; uint16_t u[8]; } o;
  if (d0 >= 64) {
    short8 xv = *(const short8*)(src + d0);
    #pragma unroll
    for (int e = 0; e < 8; ++e) o.u[e] = f2b(b2f((uint16_t)xv[e]) * scale);
  } else {
    int dd = d0 & 31;
    short8 a = *(const short8*)(src + dd);
    short8 b = *(const short8*)(src + dd + 32);
    float4 c0 = *(const float4*)(ct + s*32 + dd);
    float4 c1 = *(const float4*)(ct + s*32 + dd + 4);
    float4 s0 = *(const float4*)(st + s*32 + dd);
    float4 s1 = *(const float4*)(st + s*32 + dd + 4);
    float cc[8] = {c0.x,c0.y,c0.z,c0.w,c1.x,c1.y,c1.z,c1.w};
    float ss[8] = {s0.x,s0.y,s0.z,s0.w,s1.x,s1.y,s1.z,s1.w};
    #pragma unroll
    for (int e = 0; e < 8; ++e) {
      float x1 = b2f((uint16_t)a[e]), x2 = b2f((uint16_t)b[e]);
      float v = (d0 < 32) ? (x1*cc[e] - x2*ss[e]) : (x1*ss[e] + x2*cc[e]);
      o.u[e] = f2b(v * scale);
    }
  }
  *(short8*)dst = o.v;
}

// ---------------- V transpose: qkv[s][4096+h*128+d] -> vt[h][d][s] ----------------
__global__ __launch_bounds__(256) void k_vt(const uint16_t* __restrict__ qkv,
                                            uint16_t* __restrict__ vt){
  __shared__ uint16_t tl[64][80];
  const int b = blockIdx.x;                 // h(16) x dt(2) x st(32)
  const int st_ = b & 31, dt = (b >> 5) & 1, h = b >> 6;
  const int tid = threadIdx.x;
  const int s_l = tid >> 2, cch = (tid & 3) * 16;
  const uint16_t* src = qkv + (size_t)(st_*64 + s_l) * QKV_N + 4096 + h*128 + dt*64 + cch;
  short8 a = *(const short8*)src;
  short8 b2 = *(const short8*)(src + 8);
  #pragma unroll
  for (int e = 0; e < 8; ++e) {
    tl[cch + e][s_l]     = (uint16_t)a[e];
    tl[cch + 8 + e][s_l] = (uint16_t)b2[e];
  }
  __syncthreads();
  const int d_l = tid >> 2;
  uint16_t* dst = vt + ((size_t)h << 18) + (size_t)(dt*64 + d_l) * 2048 + st_*64 + cch;
  *(short8*)dst       = *(const short8*)&tl[d_l][cch];
  *(short8*)(dst + 8) = *(const short8*)&tl[d_l][cch + 8];
}

// ---------------- causal flash attention v2 ----------------
__global__ __launch_bounds__(128) void k_attn(const uint16_t* __restrict__ Q,
                                              const uint16_t* __restrict__ Kb,
                                              const uint16_t* __restrict__ Vtg,
                                              uint16_t* __restrict__ Out){
  __shared__ uint16_t Ks[2][64*128];   // [k][d] rows 256B, swizzled
  __shared__ uint16_t Vs[2][128*64];   // [d][k] rows 128B, swizzled
  __shared__ uint16_t Ps[2][16*80];    // per-wave P [q][k], stride 80 elems

  const int pair = blockIdx.x;         // 0..31
  const int h = blockIdx.y;
  const int tid = threadIdx.x, w = tid >> 6, l = tid & 63;
  const int g = l >> 4, c = l & 15;
  const int swz = (c & 7) << 4;        // read-side byte swizzle

  const uint16_t* __restrict__ Qh = Q   + ((size_t)h << 18);
  const uint16_t* __restrict__ Kh = Kb  + ((size_t)h << 18);
  const uint16_t* __restrict__ Vh = Vtg + ((size_t)h << 18);

  int koff[8], voff[8];
  #pragma unroll
  for (int j = 0; j < 8; ++j) {
    int r = j*8 + w*4 + (l >> 4);
    koff[j] = r*128 + (((l & 15) ^ (r & 7)) << 3);
    int d = j*16 + w*8 + (l >> 3);
    voff[j] = d*2048 + (((l & 7) ^ (d & 7)) << 3);
  }

  #pragma unroll 1
  for (int half = 0; half < 2; ++half) {
    const int qt = half ? (63 - pair) : pair;
    const int nt = (qt >> 1) + 1;
    const int qrow = qt*32 + w*16 + c;

    short8 qf[4];
    #pragma unroll
    for (int t = 0; t < 4; ++t)
      qf[t] = *(const short8*)&Qh[(size_t)qrow*128 + t*32 + g*8];

    f32x4 acc[8] = {};
    float mrow[4], lrow[4];
    #pragma unroll
    for (int j = 0; j < 4; ++j) { mrow[j] = -3e38f; lrow[j] = 0.0f; }

    #pragma unroll
    for (int j = 0; j < 8; ++j) {
      g2l16(Kh + koff[j], (void*)(&Ks[0][0] + j*1024 + tid*8));
      g2l16(Vh + voff[j], (void*)(&Vs[0][0] + j*1024 + tid*8));
    }
    asm volatile("s_waitcnt vmcnt(0)" ::: "memory");
    __syncthreads();

    for (int kt = 0; kt < nt; ++kt) {
      const int cur = kt & 1;
      const int k0 = kt * 64;
      if (kt + 1 < nt) {
        const int k1 = k0 + 64;
        #pragma unroll
        for (int j = 0; j < 8; ++j) {
          g2l16(Kh + (size_t)k1*128 + koff[j], (void*)(&Ks[cur^1][0] + j*1024 + tid*8));
          g2l16(Vh + k1 + voff[j],             (void*)(&Vs[cur^1][0] + j*1024 + tid*8));
        }
      }

      f32x4 sc4[4] = {};
      #pragma unroll
      for (int ct2 = 0; ct2 < 4; ++ct2) {
        const char* krp = (const char*)&Ks[cur][0] + (ct2*16 + c)*256;
        #pragma unroll
        for (int t = 0; t < 4; ++t) {
          short8 kb = *(const short8*)(krp + ((t*64 + g*16) ^ swz));
          sc4[ct2] = __builtin_amdgcn_mfma_f32_16x16x32_bf16(qf[t], kb, sc4[ct2], 0, 0, 0);
        }
      }

      const bool lastt = (kt == nt - 1);
      #pragma unroll
      for (int j = 0; j < 4; ++j) {
        const int qg = qt*32 + w*16 + g*4 + j;
        float v0 = sc4[0][j], v1 = sc4[1][j], v2 = sc4[2][j], v3 = sc4[3][j];
        if (lastt) {
          if (k0 +      c > qg) v0 = -3e38f;
          if (k0 + 16 + c > qg) v1 = -3e38f;
          if (k0 + 32 + c > qg) v2 = -3e38f;
          if (k0 + 48 + c > qg) v3 = -3e38f;
        }
        float t0 = fmaxf(fmaxf(v0, v1), fmaxf(v2, v3));
        #pragma unroll
        for (int d2 = 1; d2 < 16; d2 <<= 1) t0 = fmaxf(t0, __shfl_xor(t0, d2, 64));
        const float mn = fmaxf(mrow[j], t0);
        const float scl = __expf(mrow[j] - mn);
        const float p0 = __expf(v0 - mn), p1 = __expf(v1 - mn),
                    p2 = __expf(v2 - mn), p3 = __expf(v3 - mn);
        float rs = (p0 + p1) + (p2 + p3);
        #pragma unroll
        for (int d2 = 1; d2 < 16; d2 <<= 1) rs += __shfl_xor(rs, d2, 64);
        lrow[j] = lrow[j]*scl + rs;
        mrow[j] = mn;
        #pragma unroll
        for (int n = 0; n < 8; ++n) acc[n][j] *= scl;
        uint16_t* pw = &Ps[w][(g*4 + j)*80];
        pw[c] = f2b(p0); pw[16+c] = f2b(p1); pw[32+c] = f2b(p2); pw[48+c] = f2b(p3);
      }

      #pragma unroll
      for (int kk = 0; kk < 2; ++kk) {
        short8 pf = *(const short8*)&Ps[w][c*80 + kk*32 + g*8];
        #pragma unroll
        for (int n = 0; n < 8; ++n) {
          const char* vrp = (const char*)&Vs[cur][0] + (n*16 + c)*128;
          short8 vf = *(const short8*)(vrp + ((kk*64 + g*16) ^ swz));
          acc[n] = __builtin_amdgcn_mfma_f32_16x16x32_bf16(pf, vf, acc[n], 0, 0, 0);
        }
      }

      asm volatile("s_waitcnt vmcnt(0)" ::: "memory");
      __syncthreads();
    }

    #pragma unroll
    for (int j = 0; j < 4; ++j) {
      const int qg = qt*32 + w*16 + g*4 + j;
      const float inv = 1.0f / lrow[j];
      #pragma unroll
      for (int n = 0; n < 8; ++n)
        Out[(size_t)qg*2048 + h*128 + n*16 + c] = f2b(acc[n][j] * inv);
    }
  }
}

extern "C" void kernel_launch(void* const* d_in, const int* in_sizes, int n_in,
                              void* d_out, int out_size, void* d_ws, size_t ws_size,
                              hipStream_t stream){
  const float* x    = (const float*)d_in[0];
  const float* Wqkv = (const float*)d_in[1];
  const float* bqkv = (const float*)d_in[2];
  const float* Wo   = (const float*)d_in[3];
  const float* bo   = (const float*)d_in[4];

  char* ws = (char*)d_ws;
  uint16_t* q_bf    = (uint16_t*)(ws);                 //  8.39 MB [16][2048][128]
  uint16_t* k_bf    = (uint16_t*)(ws + 8388608);       //  8.39 MB [16][2048][128]
  uint16_t* vt_bf   = (uint16_t*)(ws + 16777216);      //  8.39 MB [16][128][2048]
  uint16_t* attn_bf = (uint16_t*)(ws + 25165824);      //  8.39 MB (aliased with x_bf)
  uint16_t* x_bf    = attn_bf;                         //  x dead before attn writes
  uint16_t* wqkv_bf = (uint16_t*)(ws + 33554432);      // 25.17 MB
  uint16_t* wo_bf   = (uint16_t*)(ws + 58720256);      //  8.39 MB
  uint16_t* qkv_bf  = (uint16_t*)(ws + 67108864);      // 25.17 MB
  float*    cos_t   = (float*)(ws + 92274688);         //  0.26 MB
  float*    sin_t   = (float*)(ws + 92536832);         //  0.26 MB

  k_tables<<<dim3(256), dim3(256), 0, stream>>>(cos_t, sin_t);
  k_f32_to_bf16<<<dim3(2048), dim3(256), 0, stream>>>(x, x_bf, 524288);
  k_f32_to_bf16<<<dim3(6144), dim3(256), 0, stream>>>(Wqkv, wqkv_bf, 1572864);
  k_f32_to_bf16<<<dim3(2048), dim3(256), 0, stream>>>(Wo, wo_bf, 524288);

  // qkv = x @ Wqkv^T + b   -> bf16 [2048][6144]  (256^2 8-phase, 192 blocks)
  k_gemm256<<<dim3(192), dim3(512), 0, stream>>>(x_bf, wqkv_bf, bqkv, qkv_bf,
                                                 2048, 6144, 2048, 8);
  // RoPE + split Q,K (Q pre-scaled); V transposed to [h][d][s]
  k_rope_split<<<dim3(4096), dim3(256), 0, stream>>>(qkv_bf, cos_t, sin_t, q_bf, k_bf);
  k_vt<<<dim3(1024), dim3(256), 0, stream>>>(qkv_bf, vt_bf);
  // causal flash attention -> attn_bf [2048][2048]
  k_attn<<<dim3(32, 16), dim3(128), 0, stream>>>(q_bf, k_bf, vt_bf, attn_bf);
  // out = attn @ Wo^T + bo -> f32 d_out (128^2 tile, 256 blocks = full CU coverage)
  k_gemm_bt<false><<<dim3(16, 16), dim3(256), 0, stream>>>(attn_bf, wo_bf, bo,
                                                           d_out, 2048, 2048, 2048);
}

// Round 4
// 241.319 us; speedup vs baseline: 1.6057x; 1.0026x over previous
//
#include <hip/hip_runtime.h>
#include <stdint.h>

// Problem constants
#define QKV_N 6144
#define ATT_SCALE 0.08838834764831845f   // 1/sqrt(128)

typedef __attribute__((ext_vector_type(8))) short short8;   // 8 bf16 (4 VGPRs)
typedef __attribute__((ext_vector_type(4))) float f32x4;

__device__ __forceinline__ uint16_t f2b(float x){
  uint32_t u = __float_as_uint(x);
  uint32_t r = (u + 0x7fffu + ((u >> 16) & 1u)) >> 16;   // RNE
  return (uint16_t)r;
}
__device__ __forceinline__ float b2f(uint16_t h){
  return __uint_as_float(((uint32_t)h) << 16);
}
__device__ __forceinline__ void g2l16(const void* g, void* l){
  __builtin_amdgcn_global_load_lds((const __attribute__((address_space(1))) void*)g,
                                   (__attribute__((address_space(3))) void*)l, 16, 0, 0);
}

// ---------------- fp32 -> bf16 convert (8 elems/thread) ----------------
__global__ __launch_bounds__(256) void k_f32_to_bf16(const float* __restrict__ in,
                                                     uint16_t* __restrict__ out, int n8){
  int i = blockIdx.x * 256 + threadIdx.x;
  if (i >= n8) return;
  const float4* p = (const float4*)in;
  float4 a = p[2*i], b = p[2*i+1];
  union { short8 v; uint16_t u[8]; } o;
  o.u[0]=f2b(a.x); o.u[1]=f2b(a.y); o.u[2]=f2b(a.z); o.u[3]=f2b(a.w);
  o.u[4]=f2b(b.x); o.u[5]=f2b(b.y); o.u[6]=f2b(b.z); o.u[7]=f2b(b.w);
  ((short8*)out)[i] = o.v;
}

// ---------------- RoPE cos/sin tables: [2048][32] ----------------
__global__ __launch_bounds__(256) void k_tables(float* __restrict__ ct, float* __restrict__ st){
  int i = blockIdx.x * 256 + threadIdx.x;   // 65536
  int s = i >> 5, d = i & 31;
  float inv = __expf(-(float)d * (9.210340371976184f / 32.0f));  // 10000^(-d/32)
  float f = (float)s * inv;
  ct[i] = cosf(f);
  st[i] = sinf(f);
}

// ---------------- 256x256 8-phase GEMM (bf16 out): C = A @ B^T + bias ----------------
__global__ __launch_bounds__(512, 1) void k_gemm256(const uint16_t* __restrict__ A,
                                                    const uint16_t* __restrict__ B,
                                                    const float* __restrict__ bias,
                                                    uint16_t* __restrict__ C,
                                                    int M, int N, int K, int nbm){
  __shared__ uint16_t As[2][256*64];
  __shared__ uint16_t Bs[2][256*64];

  const int nwg = gridDim.x;
  const int wg = blockIdx.x;
  const int lin = (wg & 7) * (nwg >> 3) + (wg >> 3);
  const int m0 = (lin % nbm) * 256;
  const int n0 = (lin / nbm) * 256;

  const int tid = threadIdx.x;
  const int wid = tid >> 6, l = tid & 63;
  const int wm = wid >> 2, wn = wid & 3;       // 2 x 4 wave grid
  const int g = l >> 4, c = l & 15;
  const int rsw = c & 7;

  const int srow = tid >> 3;
  const int sk = ((tid & 7) ^ (srow & 7)) << 3;
  const uint16_t* Ap = A + (size_t)(m0 + srow) * K + sk;
  const uint16_t* Bp = B + (size_t)(n0 + srow) * K + sk;

  f32x4 acc[8][4] = {};

  const int NT = K >> 6;
  #pragma unroll
  for (int j = 0; j < 4; ++j) {
    g2l16(Ap + (size_t)j*64*K, (void*)(&As[0][0] + j*4096 + tid*8));
    g2l16(Bp + (size_t)j*64*K, (void*)(&Bs[0][0] + j*4096 + tid*8));
  }
  asm volatile("s_waitcnt vmcnt(0)" ::: "memory");
  __syncthreads();

  const int abase = wm*128 + c;
  const int bbase = wn*64 + c;

  for (int kt = 0; kt < NT; ++kt) {
    const int cur = kt & 1;
    const uint16_t* __restrict__ Asc = &As[cur][0];
    const uint16_t* __restrict__ Bsc = &Bs[cur][0];
    short8 a[8], b0[4], b1[4];

    // ---- phase 0: issue next-tile stage early; read A(mi0-3), B(ni0-1); MFMA Q00
    if (kt + 1 < NT) {
      const size_t ko = (size_t)(kt + 1) * 64;
      #pragma unroll
      for (int j = 0; j < 4; ++j) {
        g2l16(Ap + (size_t)j*64*K + ko, (void*)(&As[cur^1][0] + j*4096 + tid*8));
        g2l16(Bp + (size_t)j*64*K + ko, (void*)(&Bs[cur^1][0] + j*4096 + tid*8));
      }
    }
    #pragma unroll
    for (int mi = 0; mi < 4; ++mi)
      #pragma unroll
      for (int kk = 0; kk < 2; ++kk)
        a[mi*2+kk] = *(const short8*)&Asc[(abase + mi*16)*64 + (((kk*4+g) ^ rsw) << 3)];
    #pragma unroll
    for (int ni = 0; ni < 2; ++ni)
      #pragma unroll
      for (int kk = 0; kk < 2; ++kk)
        b0[ni*2+kk] = *(const short8*)&Bsc[(bbase + ni*16)*64 + (((kk*4+g) ^ rsw) << 3)];
    __builtin_amdgcn_s_barrier();
    __builtin_amdgcn_s_setprio(1);
    #pragma unroll
    for (int mi = 0; mi < 4; ++mi)
      #pragma unroll
      for (int ni = 0; ni < 2; ++ni)
        #pragma unroll
        for (int kk = 0; kk < 2; ++kk)
          acc[mi][ni] = __builtin_amdgcn_mfma_f32_16x16x32_bf16(a[mi*2+kk], b0[ni*2+kk], acc[mi][ni], 0, 0, 0);
    __builtin_amdgcn_s_setprio(0);
    __builtin_amdgcn_s_barrier();

    // ---- phase 1: read B(ni2-3); MFMA Q01
    #pragma unroll
    for (int ni = 0; ni < 2; ++ni)
      #pragma unroll
      for (int kk = 0; kk < 2; ++kk)
        b1[ni*2+kk] = *(const short8*)&Bsc[(bbase + (ni+2)*16)*64 + (((kk*4+g) ^ rsw) << 3)];
    __builtin_amdgcn_s_barrier();
    __builtin_amdgcn_s_setprio(1);
    #pragma unroll
    for (int mi = 0; mi < 4; ++mi)
      #pragma unroll
      for (int ni = 0; ni < 2; ++ni)
        #pragma unroll
        for (int kk = 0; kk < 2; ++kk)
          acc[mi][ni+2] = __builtin_amdgcn_mfma_f32_16x16x32_bf16(a[mi*2+kk], b1[ni*2+kk], acc[mi][ni+2], 0, 0, 0);
    __builtin_amdgcn_s_setprio(0);
    __builtin_amdgcn_s_barrier();

    // ---- phase 2: read A(mi4-7); MFMA Q11 (reuse b1)
    #pragma unroll
    for (int mi = 0; mi < 4; ++mi)
      #pragma unroll
      for (int kk = 0; kk < 2; ++kk)
        a[mi*2+kk] = *(const short8*)&Asc[(abase + (mi+4)*16)*64 + (((kk*4+g) ^ rsw) << 3)];
    __builtin_amdgcn_s_barrier();
    __builtin_amdgcn_s_setprio(1);
    #pragma unroll
    for (int mi = 0; mi < 4; ++mi)
      #pragma unroll
      for (int ni = 0; ni < 2; ++ni)
        #pragma unroll
        for (int kk = 0; kk < 2; ++kk)
          acc[mi+4][ni+2] = __builtin_amdgcn_mfma_f32_16x16x32_bf16(a[mi*2+kk], b1[ni*2+kk], acc[mi+4][ni+2], 0, 0, 0);
    __builtin_amdgcn_s_setprio(0);
    __builtin_amdgcn_s_barrier();

    // ---- phase 3: MFMA Q10 (reuse a(mi4-7), b0)
    __builtin_amdgcn_s_setprio(1);
    #pragma unroll
    for (int mi = 0; mi < 4; ++mi)
      #pragma unroll
      for (int ni = 0; ni < 2; ++ni)
        #pragma unroll
        for (int kk = 0; kk < 2; ++kk)
          acc[mi+4][ni] = __builtin_amdgcn_mfma_f32_16x16x32_bf16(a[mi*2+kk], b0[ni*2+kk], acc[mi+4][ni], 0, 0, 0);
    __builtin_amdgcn_s_setprio(0);

    asm volatile("s_waitcnt vmcnt(0)" ::: "memory");
    __syncthreads();
  }

  #pragma unroll
  for (int ni = 0; ni < 4; ++ni) {
    const int col = n0 + wn*64 + ni*16 + c;
    const float bv = bias[col];
    #pragma unroll
    for (int mi = 0; mi < 8; ++mi) {
      const int row0 = m0 + wm*128 + mi*16 + g*4;
      #pragma unroll
      for (int j = 0; j < 4; ++j)
        C[(size_t)(row0 + j)*N + col] = f2b(acc[mi][ni][j] + bv);
    }
  }
}

// ---------------- GEMM: C[m,n] = sum_k A[m,k]*B[n,k] + bias[n] (128^2 tile) ----------------
template<bool OUT_BF16>
__global__ __launch_bounds__(256) void k_gemm_bt(const uint16_t* __restrict__ A,
                                                 const uint16_t* __restrict__ B,
                                                 const float* __restrict__ bias,
                                                 void* __restrict__ C,
                                                 int M, int N, int K){
  __shared__ uint16_t As[128*64];
  __shared__ uint16_t Bs[128*64];
  const int m0 = blockIdx.x * 128;
  const int n0 = blockIdx.y * 128;
  const int tid = threadIdx.x;
  const int w = tid >> 6, l = tid & 63;
  const int wr = w >> 1, wc = w & 1;
  const int g = l >> 4, c = l & 15;

  f32x4 acc[4][4] = {};

  const int srow = w*8 + (l >> 3);
  const int scol = (l & 7) * 8;

  for (int k0 = 0; k0 < K; k0 += 64) {
    #pragma unroll
    for (int i = 0; i < 4; ++i) {
      g2l16(A + (size_t)(m0 + i*32 + srow)*K + k0 + scol, (void*)(As + i*2048 + tid*8));
      g2l16(B + (size_t)(n0 + i*32 + srow)*K + k0 + scol, (void*)(Bs + i*2048 + tid*8));
    }
    asm volatile("s_waitcnt vmcnt(0)" ::: "memory");
    __syncthreads();
    #pragma unroll
    for (int kk = 0; kk < 2; ++kk) {
      short8 a[4], b[4];
      #pragma unroll
      for (int m = 0; m < 4; ++m)
        a[m] = *(const short8*)&As[(wr*64 + m*16 + c)*64 + kk*32 + g*8];
      #pragma unroll
      for (int n = 0; n < 4; ++n)
        b[n] = *(const short8*)&Bs[(wc*64 + n*16 + c)*64 + kk*32 + g*8];
      #pragma unroll
      for (int m = 0; m < 4; ++m)
        #pragma unroll
        for (int n = 0; n < 4; ++n)
          acc[m][n] = __builtin_amdgcn_mfma_f32_16x16x32_bf16(a[m], b[n], acc[m][n], 0, 0, 0);
    }
    __syncthreads();
  }

  #pragma unroll
  for (int n = 0; n < 4; ++n) {
    int col = n0 + wc*64 + n*16 + c;
    float bv = bias ? bias[col] : 0.0f;
    #pragma unroll
    for (int m = 0; m < 4; ++m) {
      int row0 = m0 + wr*64 + m*16 + g*4;
      #pragma unroll
      for (int j = 0; j < 4; ++j) {
        float v = acc[m][n][j] + bv;
        if (OUT_BF16) ((uint16_t*)C)[(size_t)(row0 + j)*N + col] = f2b(v);
        else          ((float*)C)[(size_t)(row0 + j)*N + col] = v;
      }
    }
  }
}

// ---------------- RoPE + head-split for Q,K (V handled by k_vt) ----------------
__global__ __launch_bounds__(256) void k_rope_split(const uint16_t* __restrict__ qkv,
                                                    const float* __restrict__ ct,
                                                    const float* __restrict__ st,
                                                    uint16_t* __restrict__ qo,
                                                    uint16_t* __restrict__ ko){
  int idx = blockIdx.x * 256 + threadIdx.x;   // which(2) x h(16) x s(2048) x db(16) = 2^20
  int db = idx & 15;
  int s  = (idx >> 4) & 2047;
  int h  = (idx >> 15) & 15;
  int which = idx >> 19;
  const uint16_t* src = qkv + (size_t)s * QKV_N + which * 2048 + h * 128;
  uint16_t* dst = (which ? ko : qo) + (((size_t)(h*2048 + s)) << 7) + db*8;
  const float scale = which ? 1.0f : ATT_SCALE;
  int d0 = db * 8;
  union { short8 v; uint16_t u[8]; } o;
  if (d0 >= 64) {
    short8 xv = *(const short8*)(src + d0);
    #pragma unroll
    for (int e = 0; e < 8; ++e) o.u[e] = f2b(b2f((uint16_t)xv[e]) * scale);
  } else {
    int dd = d0 & 31;
    short8 a = *(const short8*)(src + dd);
    short8 b = *(const short8*)(src + dd + 32);
    float4 c0 = *(const float4*)(ct + s*32 + dd);
    float4 c1 = *(const float4*)(ct + s*32 + dd + 4);
    float4 s0 = *(const float4*)(st + s*32 + dd);
    float4 s1 = *(const float4*)(st + s*32 + dd + 4);
    float cc[8] = {c0.x,c0.y,c0.z,c0.w,c1.x,c1.y,c1.z,c1.w};
    float ss[8] = {s0.x,s0.y,s0.z,s0.w,s1.x,s1.y,s1.z,s1.w};
    #pragma unroll
    for (int e = 0; e < 8; ++e) {
      float x1 = b2f((uint16_t)a[e]), x2 = b2f((uint16_t)b[e]);
      float v = (d0 < 32) ? (x1*cc[e] - x2*ss[e]) : (x1*ss[e] + x2*cc[e]);
      o.u[e] = f2b(v * scale);
    }
  }
  *(short8*)dst = o.v;
}

// ---------------- V transpose: qkv[s][4096+h*128+d] -> vt[h][d][s] ----------------
__global__ __launch_bounds__(256) void k_vt(const uint16_t* __restrict__ qkv,
                                            uint16_t* __restrict__ vt){
  __shared__ uint16_t tl[64][80];
  const int b = blockIdx.x;                 // h(16) x dt(2) x st(32)
  const int st_ = b & 31, dt = (b >> 5) & 1, h = b >> 6;
  const int tid = threadIdx.x;
  const int s_l = tid >> 2, cch = (tid & 3) * 16;
  const uint16_t* src = qkv + (size_t)(st_*64 + s_l) * QKV_N + 4096 + h*128 + dt*64 + cch;
  short8 a = *(const short8*)src;
  short8 b2 = *(const short8*)(src + 8);
  #pragma unroll
  for (int e = 0; e < 8; ++e) {
    tl[cch + e][s_l]     = (uint16_t)a[e];
    tl[cch + 8 + e][s_l] = (uint16_t)b2[e];
  }
  __syncthreads();
  const int d_l = tid >> 2;
  uint16_t* dst = vt + ((size_t)h << 18) + (size_t)(dt*64 + d_l) * 2048 + st_*64 + cch;
  *(short8*)dst       = *(const short8*)&tl[d_l][cch];
  *(short8*)(dst + 8) = *(const short8*)&tl[d_l][cch + 8];
}

// ---------------- causal flash attention v3 ----------------
// Q/K: [16][2048][128] bf16 (Q pre-scaled). Vt: [16][128][2048] bf16.
// Out: [2048][2048] bf16, col = h*128 + d.
// Block: 4 waves, QBLK=64 q-rows (16/wave). KV tiles of 64, double-buffered,
// XOR-swizzled LDS. Flat grid 256 blocks; XCD remap clusters heads 2x,2x+1
// on XCD x so K/V (~2MB) stays L2-resident. Fold-pair {p, 31-p} = 33 tiles.
__global__ __launch_bounds__(256) void k_attn(const uint16_t* __restrict__ Q,
                                              const uint16_t* __restrict__ Kb,
                                              const uint16_t* __restrict__ Vtg,
                                              uint16_t* __restrict__ Out){
  __shared__ uint16_t Ks[2][64*128];   // [k][d] rows 256B, swizzled
  __shared__ uint16_t Vs[2][128*64];   // [d][k] rows 128B, swizzled
  __shared__ uint16_t Ps[4][16*88];    // per-wave P [q][k], stride 88 elems

  const int bid = blockIdx.x;          // 256 blocks
  const int lin = (bid & 7) * 32 + (bid >> 3);
  const int h = lin >> 4;              // XCD x gets heads {2x, 2x+1}
  const int pair = lin & 15;           // fold-pair within head

  const int tid = threadIdx.x, w = tid >> 6, l = tid & 63;
  const int g = l >> 4, c = l & 15;
  const int swz = (c & 7) << 4;        // read-side byte swizzle

  const uint16_t* __restrict__ Qh = Q   + ((size_t)h << 18);
  const uint16_t* __restrict__ Kh = Kb  + ((size_t)h << 18);
  const uint16_t* __restrict__ Vh = Vtg + ((size_t)h << 18);

  // per-thread staging source offsets (pre-swizzled), 4 slots each of K and V
  int koff[4], voff[4];
  #pragma unroll
  for (int j = 0; j < 4; ++j) {
    int kr = j*16 + (tid >> 4);                          // K row in tile
    koff[j] = kr*128 + (((tid & 15) ^ (kr & 7)) << 3);
    int vd = j*32 + (tid >> 3);                          // V^T row (d)
    voff[j] = vd*2048 + (((tid & 7) ^ (vd & 7)) << 3);
  }

  #pragma unroll 1
  for (int half = 0; half < 2; ++half) {
    const int qt = half ? (31 - pair) : pair;   // 64-row q-tile index
    const int nt = qt + 1;                      // KV tiles (KVBLK=64)
    const int qrow = qt*64 + w*16 + c;

    short8 qf[4];
    #pragma unroll
    for (int t = 0; t < 4; ++t)
      qf[t] = *(const short8*)&Qh[(size_t)qrow*128 + t*32 + g*8];

    f32x4 acc[8] = {};
    float mrow[4], lrow[4];
    #pragma unroll
    for (int j = 0; j < 4; ++j) { mrow[j] = -3e38f; lrow[j] = 0.0f; }

    // prologue: stage tile 0 -> buf 0
    #pragma unroll
    for (int j = 0; j < 4; ++j) {
      g2l16(Kh + koff[j], (void*)(&Ks[0][0] + j*2048 + tid*8));
      g2l16(Vh + voff[j], (void*)(&Vs[0][0] + j*2048 + tid*8));
    }
    asm volatile("s_waitcnt vmcnt(0)" ::: "memory");
    __syncthreads();

    for (int kt = 0; kt < nt; ++kt) {
      const int cur = kt & 1;
      const int k0 = kt * 64;
      // issue next tile's loads early
      if (kt + 1 < nt) {
        const int k1 = k0 + 64;
        #pragma unroll
        for (int j = 0; j < 4; ++j) {
          g2l16(Kh + (size_t)k1*128 + koff[j], (void*)(&Ks[cur^1][0] + j*2048 + tid*8));
          g2l16(Vh + k1 + voff[j],             (void*)(&Vs[cur^1][0] + j*2048 + tid*8));
        }
      }

      // QK^T: 16x64 scores per wave, K=128 contraction
      f32x4 sc4[4] = {};
      #pragma unroll
      for (int ct2 = 0; ct2 < 4; ++ct2) {
        const char* krp = (const char*)&Ks[cur][0] + (ct2*16 + c)*256;
        #pragma unroll
        for (int t = 0; t < 4; ++t) {
          short8 kb = *(const short8*)(krp + ((t*64 + g*16) ^ swz));
          sc4[ct2] = __builtin_amdgcn_mfma_f32_16x16x32_bf16(qf[t], kb, sc4[ct2], 0, 0, 0);
        }
      }

      // online softmax (rows g*4+j across 16 lanes)
      const bool lastt = (kt == nt - 1);
      #pragma unroll
      for (int j = 0; j < 4; ++j) {
        const int qg = qt*64 + w*16 + g*4 + j;
        float v0 = sc4[0][j], v1 = sc4[1][j], v2 = sc4[2][j], v3 = sc4[3][j];
        if (lastt) {
          if (k0 +      c > qg) v0 = -3e38f;
          if (k0 + 16 + c > qg) v1 = -3e38f;
          if (k0 + 32 + c > qg) v2 = -3e38f;
          if (k0 + 48 + c > qg) v3 = -3e38f;
        }
        float t0 = fmaxf(fmaxf(v0, v1), fmaxf(v2, v3));
        #pragma unroll
        for (int d2 = 1; d2 < 16; d2 <<= 1) t0 = fmaxf(t0, __shfl_xor(t0, d2, 64));
        const float mn = fmaxf(mrow[j], t0);
        const float scl = __expf(mrow[j] - mn);
        const float p0 = __expf(v0 - mn), p1 = __expf(v1 - mn),
                    p2 = __expf(v2 - mn), p3 = __expf(v3 - mn);
        float rs = (p0 + p1) + (p2 + p3);
        #pragma unroll
        for (int d2 = 1; d2 < 16; d2 <<= 1) rs += __shfl_xor(rs, d2, 64);
        lrow[j] = lrow[j]*scl + rs;
        mrow[j] = mn;
        #pragma unroll
        for (int n = 0; n < 8; ++n) acc[n][j] *= scl;
        uint16_t* pw = &Ps[w][(g*4 + j)*88];
        pw[c] = f2b(p0); pw[16+c] = f2b(p1); pw[32+c] = f2b(p2); pw[48+c] = f2b(p3);
      }

      // PV: P(16x64) x V(64x128)
      #pragma unroll
      for (int kk = 0; kk < 2; ++kk) {
        short8 pf = *(const short8*)&Ps[w][c*88 + kk*32 + g*8];
        #pragma unroll
        for (int n = 0; n < 8; ++n) {
          const char* vrp = (const char*)&Vs[cur][0] + (n*16 + c)*128;
          short8 vf = *(const short8*)(vrp + ((kk*64 + g*16) ^ swz));
          acc[n] = __builtin_amdgcn_mfma_f32_16x16x32_bf16(pf, vf, acc[n], 0, 0, 0);
        }
      }

      asm volatile("s_waitcnt vmcnt(0)" ::: "memory");
      __syncthreads();
    }

    // epilogue
    #pragma unroll
    for (int j = 0; j < 4; ++j) {
      const int qg = qt*64 + w*16 + g*4 + j;
      const float inv = 1.0f / lrow[j];
      #pragma unroll
      for (int n = 0; n < 8; ++n)
        Out[(size_t)qg*2048 + h*128 + n*16 + c] = f2b(acc[n][j] * inv);
    }
  }
}

extern "C" void kernel_launch(void* const* d_in, const int* in_sizes, int n_in,
                              void* d_out, int out_size, void* d_ws, size_t ws_size,
                              hipStream_t stream){
  const float* x    = (const float*)d_in[0];
  const float* Wqkv = (const float*)d_in[1];
  const float* bqkv = (const float*)d_in[2];
  const float* Wo   = (const float*)d_in[3];
  const float* bo   = (const float*)d_in[4];

  char* ws = (char*)d_ws;
  uint16_t* q_bf    = (uint16_t*)(ws);                 //  8.39 MB [16][2048][128]
  uint16_t* k_bf    = (uint16_t*)(ws + 8388608);       //  8.39 MB [16][2048][128]
  uint16_t* vt_bf   = (uint16_t*)(ws + 16777216);      //  8.39 MB [16][128][2048]
  uint16_t* attn_bf = (uint16_t*)(ws + 25165824);      //  8.39 MB (aliased with x_bf)
  uint16_t* x_bf    = attn_bf;                         //  x dead before attn writes
  uint16_t* wqkv_bf = (uint16_t*)(ws + 33554432);      // 25.17 MB
  uint16_t* wo_bf   = (uint16_t*)(ws + 58720256);      //  8.39 MB
  uint16_t* qkv_bf  = (uint16_t*)(ws + 67108864);      // 25.17 MB
  float*    cos_t   = (float*)(ws + 92274688);         //  0.26 MB
  float*    sin_t   = (float*)(ws + 92536832);         //  0.26 MB

  k_tables<<<dim3(256), dim3(256), 0, stream>>>(cos_t, sin_t);
  k_f32_to_bf16<<<dim3(2048), dim3(256), 0, stream>>>(x, x_bf, 524288);
  k_f32_to_bf16<<<dim3(6144), dim3(256), 0, stream>>>(Wqkv, wqkv_bf, 1572864);
  k_f32_to_bf16<<<dim3(2048), dim3(256), 0, stream>>>(Wo, wo_bf, 524288);

  // qkv = x @ Wqkv^T + b   -> bf16 [2048][6144]  (256^2 8-phase, 192 blocks)
  k_gemm256<<<dim3(192), dim3(512), 0, stream>>>(x_bf, wqkv_bf, bqkv, qkv_bf,
                                                 2048, 6144, 2048, 8);
  // RoPE + split Q,K (Q pre-scaled); V transposed to [h][d][s]
  k_rope_split<<<dim3(4096), dim3(256), 0, stream>>>(qkv_bf, cos_t, sin_t, q_bf, k_bf);
  k_vt<<<dim3(1024), dim3(256), 0, stream>>>(qkv_bf, vt_bf);
  // causal flash attention -> attn_bf [2048][2048]
  k_attn<<<dim3(256), dim3(256), 0, stream>>>(q_bf, k_bf, vt_bf, attn_bf);
  // out = attn @ Wo^T + bo -> f32 d_out (128^2 tile, 256 blocks = full CU coverage)
  k_gemm_bt<false><<<dim3(16, 16), dim3(256), 0, stream>>>(attn_bf, wo_bf, bo,
                                                           d_out, 2048, 2048, 2048);
}

// Round 5
// 215.310 us; speedup vs baseline: 1.7997x; 1.1208x over previous
//
#include <hip/hip_runtime.h>
#include <stdint.h>

// Problem constants
#define QKV_N 6144
#define ATT_SCALE 0.08838834764831845f   // 1/sqrt(128)

typedef __attribute__((ext_vector_type(8))) short short8;   // 8 bf16 (4 VGPRs)
typedef __attribute__((ext_vector_type(4))) float f32x4;

__device__ __forceinline__ uint16_t f2b(float x){
  uint32_t u = __float_as_uint(x);
  uint32_t r = (u + 0x7fffu + ((u >> 16) & 1u)) >> 16;   // RNE
  return (uint16_t)r;
}
__device__ __forceinline__ float b2f(uint16_t h){
  return __uint_as_float(((uint32_t)h) << 16);
}
__device__ __forceinline__ void g2l16(const void* g, void* l){
  __builtin_amdgcn_global_load_lds((const __attribute__((address_space(1))) void*)g,
                                   (__attribute__((address_space(3))) void*)l, 16, 0, 0);
}

// ---------------- fp32 -> bf16 convert (8 elems/thread) ----------------
__global__ __launch_bounds__(256) void k_f32_to_bf16(const float* __restrict__ in,
                                                     uint16_t* __restrict__ out, int n8){
  int i = blockIdx.x * 256 + threadIdx.x;
  if (i >= n8) return;
  const float4* p = (const float4*)in;
  float4 a = p[2*i], b = p[2*i+1];
  union { short8 v; uint16_t u[8]; } o;
  o.u[0]=f2b(a.x); o.u[1]=f2b(a.y); o.u[2]=f2b(a.z); o.u[3]=f2b(a.w);
  o.u[4]=f2b(b.x); o.u[5]=f2b(b.y); o.u[6]=f2b(b.z); o.u[7]=f2b(b.w);
  ((short8*)out)[i] = o.v;
}

// ---------------- RoPE cos/sin tables: [2048][32] ----------------
__global__ __launch_bounds__(256) void k_tables(float* __restrict__ ct, float* __restrict__ st){
  int i = blockIdx.x * 256 + threadIdx.x;   // 65536
  int s = i >> 5, d = i & 31;
  float inv = __expf(-(float)d * (9.210340371976184f / 32.0f));  // 10000^(-d/32)
  float f = (float)s * inv;
  ct[i] = cosf(f);
  st[i] = sinf(f);
}

// ---------------- 256x256 8-phase GEMM (bf16 out): C = A @ B^T + bias ----------------
__global__ __launch_bounds__(512, 1) void k_gemm256(const uint16_t* __restrict__ A,
                                                    const uint16_t* __restrict__ B,
                                                    const float* __restrict__ bias,
                                                    uint16_t* __restrict__ C,
                                                    int M, int N, int K, int nbm){
  __shared__ uint16_t As[2][256*64];
  __shared__ uint16_t Bs[2][256*64];

  const int nwg = gridDim.x;
  const int wg = blockIdx.x;
  const int lin = (wg & 7) * (nwg >> 3) + (wg >> 3);
  const int m0 = (lin % nbm) * 256;
  const int n0 = (lin / nbm) * 256;

  const int tid = threadIdx.x;
  const int wid = tid >> 6, l = tid & 63;
  const int wm = wid >> 2, wn = wid & 3;       // 2 x 4 wave grid
  const int g = l >> 4, c = l & 15;
  const int rsw = c & 7;

  const int srow = tid >> 3;
  const int sk = ((tid & 7) ^ (srow & 7)) << 3;
  const uint16_t* Ap = A + (size_t)(m0 + srow) * K + sk;
  const uint16_t* Bp = B + (size_t)(n0 + srow) * K + sk;

  f32x4 acc[8][4] = {};

  const int NT = K >> 6;
  #pragma unroll
  for (int j = 0; j < 4; ++j) {
    g2l16(Ap + (size_t)j*64*K, (void*)(&As[0][0] + j*4096 + tid*8));
    g2l16(Bp + (size_t)j*64*K, (void*)(&Bs[0][0] + j*4096 + tid*8));
  }
  asm volatile("s_waitcnt vmcnt(0)" ::: "memory");
  __syncthreads();

  const int abase = wm*128 + c;
  const int bbase = wn*64 + c;

  for (int kt = 0; kt < NT; ++kt) {
    const int cur = kt & 1;
    const uint16_t* __restrict__ Asc = &As[cur][0];
    const uint16_t* __restrict__ Bsc = &Bs[cur][0];
    short8 a[8], b0[4], b1[4];

    // ---- phase 0: issue next-tile stage early; read A(mi0-3), B(ni0-1); MFMA Q00
    if (kt + 1 < NT) {
      const size_t ko = (size_t)(kt + 1) * 64;
      #pragma unroll
      for (int j = 0; j < 4; ++j) {
        g2l16(Ap + (size_t)j*64*K + ko, (void*)(&As[cur^1][0] + j*4096 + tid*8));
        g2l16(Bp + (size_t)j*64*K + ko, (void*)(&Bs[cur^1][0] + j*4096 + tid*8));
      }
    }
    #pragma unroll
    for (int mi = 0; mi < 4; ++mi)
      #pragma unroll
      for (int kk = 0; kk < 2; ++kk)
        a[mi*2+kk] = *(const short8*)&Asc[(abase + mi*16)*64 + (((kk*4+g) ^ rsw) << 3)];
    #pragma unroll
    for (int ni = 0; ni < 2; ++ni)
      #pragma unroll
      for (int kk = 0; kk < 2; ++kk)
        b0[ni*2+kk] = *(const short8*)&Bsc[(bbase + ni*16)*64 + (((kk*4+g) ^ rsw) << 3)];
    __builtin_amdgcn_s_barrier();
    __builtin_amdgcn_s_setprio(1);
    #pragma unroll
    for (int mi = 0; mi < 4; ++mi)
      #pragma unroll
      for (int ni = 0; ni < 2; ++ni)
        #pragma unroll
        for (int kk = 0; kk < 2; ++kk)
          acc[mi][ni] = __builtin_amdgcn_mfma_f32_16x16x32_bf16(a[mi*2+kk], b0[ni*2+kk], acc[mi][ni], 0, 0, 0);
    __builtin_amdgcn_s_setprio(0);
    __builtin_amdgcn_s_barrier();

    // ---- phase 1: read B(ni2-3); MFMA Q01
    #pragma unroll
    for (int ni = 0; ni < 2; ++ni)
      #pragma unroll
      for (int kk = 0; kk < 2; ++kk)
        b1[ni*2+kk] = *(const short8*)&Bsc[(bbase + (ni+2)*16)*64 + (((kk*4+g) ^ rsw) << 3)];
    __builtin_amdgcn_s_barrier();
    __builtin_amdgcn_s_setprio(1);
    #pragma unroll
    for (int mi = 0; mi < 4; ++mi)
      #pragma unroll
      for (int ni = 0; ni < 2; ++ni)
        #pragma unroll
        for (int kk = 0; kk < 2; ++kk)
          acc[mi][ni+2] = __builtin_amdgcn_mfma_f32_16x16x32_bf16(a[mi*2+kk], b1[ni*2+kk], acc[mi][ni+2], 0, 0, 0);
    __builtin_amdgcn_s_setprio(0);
    __builtin_amdgcn_s_barrier();

    // ---- phase 2: read A(mi4-7); MFMA Q11 (reuse b1)
    #pragma unroll
    for (int mi = 0; mi < 4; ++mi)
      #pragma unroll
      for (int kk = 0; kk < 2; ++kk)
        a[mi*2+kk] = *(const short8*)&Asc[(abase + (mi+4)*16)*64 + (((kk*4+g) ^ rsw) << 3)];
    __builtin_amdgcn_s_barrier();
    __builtin_amdgcn_s_setprio(1);
    #pragma unroll
    for (int mi = 0; mi < 4; ++mi)
      #pragma unroll
      for (int ni = 0; ni < 2; ++ni)
        #pragma unroll
        for (int kk = 0; kk < 2; ++kk)
          acc[mi+4][ni+2] = __builtin_amdgcn_mfma_f32_16x16x32_bf16(a[mi*2+kk], b1[ni*2+kk], acc[mi+4][ni+2], 0, 0, 0);
    __builtin_amdgcn_s_setprio(0);
    __builtin_amdgcn_s_barrier();

    // ---- phase 3: MFMA Q10 (reuse a(mi4-7), b0)
    __builtin_amdgcn_s_setprio(1);
    #pragma unroll
    for (int mi = 0; mi < 4; ++mi)
      #pragma unroll
      for (int ni = 0; ni < 2; ++ni)
        #pragma unroll
        for (int kk = 0; kk < 2; ++kk)
          acc[mi+4][ni] = __builtin_amdgcn_mfma_f32_16x16x32_bf16(a[mi*2+kk], b0[ni*2+kk], acc[mi+4][ni], 0, 0, 0);
    __builtin_amdgcn_s_setprio(0);

    asm volatile("s_waitcnt vmcnt(0)" ::: "memory");
    __syncthreads();
  }

  #pragma unroll
  for (int ni = 0; ni < 4; ++ni) {
    const int col = n0 + wn*64 + ni*16 + c;
    const float bv = bias[col];
    #pragma unroll
    for (int mi = 0; mi < 8; ++mi) {
      const int row0 = m0 + wm*128 + mi*16 + g*4;
      #pragma unroll
      for (int j = 0; j < 4; ++j)
        C[(size_t)(row0 + j)*N + col] = f2b(acc[mi][ni][j] + bv);
    }
  }
}

// ---------------- GEMM: C[m,n] = sum_k A[m,k]*B[n,k] + bias[n] (128^2 tile) ----------------
template<bool OUT_BF16>
__global__ __launch_bounds__(256) void k_gemm_bt(const uint16_t* __restrict__ A,
                                                 const uint16_t* __restrict__ B,
                                                 const float* __restrict__ bias,
                                                 void* __restrict__ C,
                                                 int M, int N, int K){
  __shared__ uint16_t As[128*64];
  __shared__ uint16_t Bs[128*64];
  const int m0 = blockIdx.x * 128;
  const int n0 = blockIdx.y * 128;
  const int tid = threadIdx.x;
  const int w = tid >> 6, l = tid & 63;
  const int wr = w >> 1, wc = w & 1;
  const int g = l >> 4, c = l & 15;

  f32x4 acc[4][4] = {};

  const int srow = w*8 + (l >> 3);
  const int scol = (l & 7) * 8;

  for (int k0 = 0; k0 < K; k0 += 64) {
    #pragma unroll
    for (int i = 0; i < 4; ++i) {
      g2l16(A + (size_t)(m0 + i*32 + srow)*K + k0 + scol, (void*)(As + i*2048 + tid*8));
      g2l16(B + (size_t)(n0 + i*32 + srow)*K + k0 + scol, (void*)(Bs + i*2048 + tid*8));
    }
    asm volatile("s_waitcnt vmcnt(0)" ::: "memory");
    __syncthreads();
    #pragma unroll
    for (int kk = 0; kk < 2; ++kk) {
      short8 a[4], b[4];
      #pragma unroll
      for (int m = 0; m < 4; ++m)
        a[m] = *(const short8*)&As[(wr*64 + m*16 + c)*64 + kk*32 + g*8];
      #pragma unroll
      for (int n = 0; n < 4; ++n)
        b[n] = *(const short8*)&Bs[(wc*64 + n*16 + c)*64 + kk*32 + g*8];
      #pragma unroll
      for (int m = 0; m < 4; ++m)
        #pragma unroll
        for (int n = 0; n < 4; ++n)
          acc[m][n] = __builtin_amdgcn_mfma_f32_16x16x32_bf16(a[m], b[n], acc[m][n], 0, 0, 0);
    }
    __syncthreads();
  }

  #pragma unroll
  for (int n = 0; n < 4; ++n) {
    int col = n0 + wc*64 + n*16 + c;
    float bv = bias ? bias[col] : 0.0f;
    #pragma unroll
    for (int m = 0; m < 4; ++m) {
      int row0 = m0 + wr*64 + m*16 + g*4;
      #pragma unroll
      for (int j = 0; j < 4; ++j) {
        float v = acc[m][n][j] + bv;
        if (OUT_BF16) ((uint16_t*)C)[(size_t)(row0 + j)*N + col] = f2b(v);
        else          ((float*)C)[(size_t)(row0 + j)*N + col] = v;
      }
    }
  }
}

// ---------------- RoPE + head-split for Q,K (V handled by k_vt) ----------------
__global__ __launch_bounds__(256) void k_rope_split(const uint16_t* __restrict__ qkv,
                                                    const float* __restrict__ ct,
                                                    const float* __restrict__ st,
                                                    uint16_t* __restrict__ qo,
                                                    uint16_t* __restrict__ ko){
  int idx = blockIdx.x * 256 + threadIdx.x;   // which(2) x h(16) x s(2048) x db(16) = 2^20
  int db = idx & 15;
  int s  = (idx >> 4) & 2047;
  int h  = (idx >> 15) & 15;
  int which = idx >> 19;
  const uint16_t* src = qkv + (size_t)s * QKV_N + which * 2048 + h * 128;
  uint16_t* dst = (which ? ko : qo) + (((size_t)(h*2048 + s)) << 7) + db*8;
  const float scale = which ? 1.0f : ATT_SCALE;
  int d0 = db * 8;
  union { short8 v; uint16_t u[8]; } o;
  if (d0 >= 64) {
    short8 xv = *(const short8*)(src + d0);
    #pragma unroll
    for (int e = 0; e < 8; ++e) o.u[e] = f2b(b2f((uint16_t)xv[e]) * scale);
  } else {
    int dd = d0 & 31;
    short8 a = *(const short8*)(src + dd);
    short8 b = *(const short8*)(src + dd + 32);
    float4 c0 = *(const float4*)(ct + s*32 + dd);
    float4 c1 = *(const float4*)(ct + s*32 + dd + 4);
    float4 s0 = *(const float4*)(st + s*32 + dd);
    float4 s1 = *(const float4*)(st + s*32 + dd + 4);
    float cc[8] = {c0.x,c0.y,c0.z,c0.w,c1.x,c1.y,c1.z,c1.w};
    float ss[8] = {s0.x,s0.y,s0.z,s0.w,s1.x,s1.y,s1.z,s1.w};
    #pragma unroll
    for (int e = 0; e < 8; ++e) {
      float x1 = b2f((uint16_t)a[e]), x2 = b2f((uint16_t)b[e]);
      float v = (d0 < 32) ? (x1*cc[e] - x2*ss[e]) : (x1*ss[e] + x2*cc[e]);
      o.u[e] = f2b(v * scale);
    }
  }
  *(short8*)dst = o.v;
}

// ---------------- V transpose: qkv[s][4096+h*128+d] -> vt[h][d][s] ----------------
__global__ __launch_bounds__(256) void k_vt(const uint16_t* __restrict__ qkv,
                                            uint16_t* __restrict__ vt){
  __shared__ uint16_t tl[64][80];
  const int b = blockIdx.x;                 // h(16) x dt(2) x st(32)
  const int st_ = b & 31, dt = (b >> 5) & 1, h = b >> 6;
  const int tid = threadIdx.x;
  const int s_l = tid >> 2, cch = (tid & 3) * 16;
  const uint16_t* src = qkv + (size_t)(st_*64 + s_l) * QKV_N + 4096 + h*128 + dt*64 + cch;
  short8 a = *(const short8*)src;
  short8 b2 = *(const short8*)(src + 8);
  #pragma unroll
  for (int e = 0; e < 8; ++e) {
    tl[cch + e][s_l]     = (uint16_t)a[e];
    tl[cch + 8 + e][s_l] = (uint16_t)b2[e];
  }
  __syncthreads();
  const int d_l = tid >> 2;
  uint16_t* dst = vt + ((size_t)h << 18) + (size_t)(dt*64 + d_l) * 2048 + st_*64 + cch;
  *(short8*)dst       = *(const short8*)&tl[d_l][cch];
  *(short8*)(dst + 8) = *(const short8*)&tl[d_l][cch + 8];
}

// ---------------- causal flash attention v4: 8 waves, even/odd KV split ----------------
// Q/K: [16][2048][128] bf16 (Q pre-scaled). Vt: [16][128][2048] bf16.
// Out: [2048][2048] bf16, col = h*128 + d.
// Block: 8 waves = 2 groups x 4 waves. Group 0 does even KV tiles, group 1 odd,
// each group with its own double-buffered K/V LDS. Partial online-softmax states
// merged through LDS scratch (aliases K buffers) at the end of each q-tile.
// 256 blocks, head-clustered on XCDs; fold-pair {p, 31-p} balances causal work.
__global__ __launch_bounds__(512, 1) void k_attn(const uint16_t* __restrict__ Q,
                                                 const uint16_t* __restrict__ Kb,
                                                 const uint16_t* __restrict__ Vtg,
                                                 uint16_t* __restrict__ Out){
  __shared__ uint16_t Ks[2][2][64*128];   // [group][buf][k][d], swizzled
  __shared__ uint16_t Vs[2][2][128*64];   // [group][buf][d][k], swizzled
  __shared__ uint16_t Ps[8][16*88];       // per-wave P [q][k], stride 88

  const int bid = blockIdx.x;             // 256 blocks
  const int lin = (bid & 7) * 32 + (bid >> 3);
  const int h = lin >> 4;                 // XCD x gets heads {2x, 2x+1}
  const int pair = lin & 15;              // fold-pair within head

  const int tid = threadIdx.x, w = tid >> 6, l = tid & 63;
  const int gid = w >> 2, wq = w & 3;     // group, wave-in-group
  const int tg = tid & 255;               // thread index within group
  const int g = l >> 4, c = l & 15;
  const int swz = (c & 7) << 4;           // read-side byte swizzle

  const uint16_t* __restrict__ Qh = Q   + ((size_t)h << 18);
  const uint16_t* __restrict__ Kh = Kb  + ((size_t)h << 18);
  const uint16_t* __restrict__ Vh = Vtg + ((size_t)h << 18);
  float* scratch = (float*)&Ks[0][0][0];  // merge scratch (safe after last barrier)

  // per-thread staging source offsets (pre-swizzled), 4 slots each of K and V
  int koff[4], voff[4];
  #pragma unroll
  for (int j = 0; j < 4; ++j) {
    int kr = j*16 + (tg >> 4);                           // K row in tile
    koff[j] = kr*128 + (((tg & 15) ^ (kr & 7)) << 3);
    int vd = j*32 + (tg >> 3);                           // V^T row (d)
    voff[j] = vd*2048 + (((tg & 7) ^ (vd & 7)) << 3);
  }

  uint16_t* KsG = &Ks[gid][0][0];   // my group's K buffers (2 x 8192 elems)
  uint16_t* VsG = &Vs[gid][0][0];

  #pragma unroll 1
  for (int half = 0; half < 2; ++half) {
    const int qt = half ? (31 - pair) : pair;   // 64-row q-tile index
    const int nt = qt + 1;                      // KV tiles (KVBLK=64)
    const int nsteps = (nt + 1) >> 1;
    const int qrow = qt*64 + wq*16 + c;

    short8 qf[4];
    #pragma unroll
    for (int t = 0; t < 4; ++t)
      qf[t] = *(const short8*)&Qh[(size_t)qrow*128 + t*32 + g*8];

    f32x4 acc[8] = {};
    float mrow[4], lrow[4];
    #pragma unroll
    for (int j = 0; j < 4; ++j) { mrow[j] = -3e38f; lrow[j] = 0.0f; }

    // prologue: stage my group's first tile (kt = gid) -> buf 0
    if (gid < nt) {
      #pragma unroll
      for (int j = 0; j < 4; ++j) {
        g2l16(Kh + (size_t)gid*8192 + koff[j], (void*)(KsG + j*2048 + tg*8));
        g2l16(Vh + gid*64 + voff[j],           (void*)(VsG + j*2048 + tg*8));
      }
    }
    asm volatile("s_waitcnt vmcnt(0)" ::: "memory");
    __syncthreads();

    #pragma unroll 1
    for (int step = 0; step < nsteps; ++step) {
      const int kt = 2*step + gid;
      const int cur = step & 1;
      // issue my group's next tile (kt+2) early
      if (kt + 2 < nt) {
        const int k1 = kt + 2;
        #pragma unroll
        for (int j = 0; j < 4; ++j) {
          g2l16(Kh + (size_t)k1*8192 + koff[j], (void*)(KsG + (cur^1)*8192 + j*2048 + tg*8));
          g2l16(Vh + k1*64 + voff[j],           (void*)(VsG + (cur^1)*8192 + j*2048 + tg*8));
        }
      }

      if (kt < nt) {
        const int k0 = kt * 64;
        const uint16_t* Kcur = KsG + cur*8192;
        const uint16_t* Vcur = VsG + cur*8192;

        // QK^T: 16x64 scores per wave, K=128 contraction
        f32x4 sc4[4] = {};
        #pragma unroll
        for (int ct2 = 0; ct2 < 4; ++ct2) {
          const char* krp = (const char*)Kcur + (ct2*16 + c)*256;
          #pragma unroll
          for (int t = 0; t < 4; ++t) {
            short8 kb = *(const short8*)(krp + ((t*64 + g*16) ^ swz));
            sc4[ct2] = __builtin_amdgcn_mfma_f32_16x16x32_bf16(qf[t], kb, sc4[ct2], 0, 0, 0);
          }
        }

        // online softmax (rows g*4+j across 16 lanes)
        const bool lastt = (kt == nt - 1);
        #pragma unroll
        for (int j = 0; j < 4; ++j) {
          const int qg = qt*64 + wq*16 + g*4 + j;
          float v0 = sc4[0][j], v1 = sc4[1][j], v2 = sc4[2][j], v3 = sc4[3][j];
          if (lastt) {
            if (k0 +      c > qg) v0 = -3e38f;
            if (k0 + 16 + c > qg) v1 = -3e38f;
            if (k0 + 32 + c > qg) v2 = -3e38f;
            if (k0 + 48 + c > qg) v3 = -3e38f;
          }
          float t0 = fmaxf(fmaxf(v0, v1), fmaxf(v2, v3));
          #pragma unroll
          for (int d2 = 1; d2 < 16; d2 <<= 1) t0 = fmaxf(t0, __shfl_xor(t0, d2, 64));
          const float mn = fmaxf(mrow[j], t0);
          const float scl = __expf(mrow[j] - mn);
          const float p0 = __expf(v0 - mn), p1 = __expf(v1 - mn),
                      p2 = __expf(v2 - mn), p3 = __expf(v3 - mn);
          float rs = (p0 + p1) + (p2 + p3);
          #pragma unroll
          for (int d2 = 1; d2 < 16; d2 <<= 1) rs += __shfl_xor(rs, d2, 64);
          lrow[j] = lrow[j]*scl + rs;
          mrow[j] = mn;
          #pragma unroll
          for (int n = 0; n < 8; ++n) acc[n][j] *= scl;
          uint16_t* pw = &Ps[w][(g*4 + j)*88];
          pw[c] = f2b(p0); pw[16+c] = f2b(p1); pw[32+c] = f2b(p2); pw[48+c] = f2b(p3);
        }

        // PV: P(16x64) x V(64x128)
        #pragma unroll
        for (int kk = 0; kk < 2; ++kk) {
          short8 pf = *(const short8*)&Ps[w][c*88 + kk*32 + g*8];
          #pragma unroll
          for (int n = 0; n < 8; ++n) {
            const char* vrp = (const char*)Vcur + (n*16 + c)*128;
            short8 vf = *(const short8*)(vrp + ((kk*64 + g*16) ^ swz));
            acc[n] = __builtin_amdgcn_mfma_f32_16x16x32_bf16(pf, vf, acc[n], 0, 0, 0);
          }
        }
      }

      asm volatile("s_waitcnt vmcnt(0)" ::: "memory");
      __syncthreads();
    }

    // ---- merge group partial states: B (gid=1) publishes, A (gid=0) combines ----
    float* Up = scratch + wq * 2112;      // U[16][128] + m[16] + l[16]
    if (gid == 1) {
      #pragma unroll
      for (int j = 0; j < 4; ++j) {
        const int row = g*4 + j;
        #pragma unroll
        for (int n = 0; n < 8; ++n)
          Up[row*128 + n*16 + c] = acc[n][j];
        if (c == 0) { Up[2048 + row] = mrow[j]; Up[2064 + row] = lrow[j]; }
      }
    }
    __syncthreads();
    if (gid == 0) {
      #pragma unroll
      for (int j = 0; j < 4; ++j) {
        const int row = g*4 + j;
        const int qg = qt*64 + wq*16 + row;
        const float mB = Up[2048 + row], lB = Up[2064 + row];
        const float mn = fmaxf(mrow[j], mB);
        const float e1 = __expf(mrow[j] - mn);
        const float e2 = __expf(mB - mn);
        const float inv = 1.0f / (lrow[j]*e1 + lB*e2);
        #pragma unroll
        for (int n = 0; n < 8; ++n) {
          const float u = acc[n][j]*e1 + Up[row*128 + n*16 + c]*e2;
          Out[(size_t)qg*2048 + h*128 + n*16 + c] = f2b(u * inv);
        }
      }
    }
    __syncthreads();   // protect scratch before next half's staging overwrites K bufs
  }
}

extern "C" void kernel_launch(void* const* d_in, const int* in_sizes, int n_in,
                              void* d_out, int out_size, void* d_ws, size_t ws_size,
                              hipStream_t stream){
  const float* x    = (const float*)d_in[0];
  const float* Wqkv = (const float*)d_in[1];
  const float* bqkv = (const float*)d_in[2];
  const float* Wo   = (const float*)d_in[3];
  const float* bo   = (const float*)d_in[4];

  char* ws = (char*)d_ws;
  uint16_t* q_bf    = (uint16_t*)(ws);                 //  8.39 MB [16][2048][128]
  uint16_t* k_bf    = (uint16_t*)(ws + 8388608);       //  8.39 MB [16][2048][128]
  uint16_t* vt_bf   = (uint16_t*)(ws + 16777216);      //  8.39 MB [16][128][2048]
  uint16_t* attn_bf = (uint16_t*)(ws + 25165824);      //  8.39 MB (aliased with x_bf)
  uint16_t* x_bf    = attn_bf;                         //  x dead before attn writes
  uint16_t* wqkv_bf = (uint16_t*)(ws + 33554432);      // 25.17 MB
  uint16_t* wo_bf   = (uint16_t*)(ws + 58720256);      //  8.39 MB
  uint16_t* qkv_bf  = (uint16_t*)(ws + 67108864);      // 25.17 MB
  float*    cos_t   = (float*)(ws + 92274688);         //  0.26 MB
  float*    sin_t   = (float*)(ws + 92536832);         //  0.26 MB

  k_tables<<<dim3(256), dim3(256), 0, stream>>>(cos_t, sin_t);
  k_f32_to_bf16<<<dim3(2048), dim3(256), 0, stream>>>(x, x_bf, 524288);
  k_f32_to_bf16<<<dim3(6144), dim3(256), 0, stream>>>(Wqkv, wqkv_bf, 1572864);
  k_f32_to_bf16<<<dim3(2048), dim3(256), 0, stream>>>(Wo, wo_bf, 524288);

  // qkv = x @ Wqkv^T + b   -> bf16 [2048][6144]  (256^2 8-phase, 192 blocks)
  k_gemm256<<<dim3(192), dim3(512), 0, stream>>>(x_bf, wqkv_bf, bqkv, qkv_bf,
                                                 2048, 6144, 2048, 8);
  // RoPE + split Q,K (Q pre-scaled); V transposed to [h][d][s]
  k_rope_split<<<dim3(4096), dim3(256), 0, stream>>>(qkv_bf, cos_t, sin_t, q_bf, k_bf);
  k_vt<<<dim3(1024), dim3(256), 0, stream>>>(qkv_bf, vt_bf);
  // causal flash attention -> attn_bf [2048][2048]
  k_attn<<<dim3(256), dim3(512), 0, stream>>>(q_bf, k_bf, vt_bf, attn_bf);
  // out = attn @ Wo^T + bo -> f32 d_out (128^2 tile, 256 blocks = full CU coverage)
  k_gemm_bt<false><<<dim3(16, 16), dim3(256), 0, stream>>>(attn_bf, wo_bf, bo,
                                                           d_out, 2048, 2048, 2048);
}

// Round 6
// 202.352 us; speedup vs baseline: 1.9149x; 1.0640x over previous
//
#include <hip/hip_runtime.h>
#include <stdint.h>

// Problem constants
#define QKV_N 6144
#define ATT_SCALE 0.08838834764831845f   // 1/sqrt(128)

typedef __attribute__((ext_vector_type(8))) short short8;   // 8 bf16 (4 VGPRs)
typedef __attribute__((ext_vector_type(4))) float f32x4;

__device__ __forceinline__ uint16_t f2b(float x){
  uint32_t u = __float_as_uint(x);
  uint32_t r = (u + 0x7fffu + ((u >> 16) & 1u)) >> 16;   // RNE
  return (uint16_t)r;
}
__device__ __forceinline__ float b2f(uint16_t h){
  return __uint_as_float(((uint32_t)h) << 16);
}
__device__ __forceinline__ void g2l16(const void* g, void* l){
  __builtin_amdgcn_global_load_lds((const __attribute__((address_space(1))) void*)g,
                                   (__attribute__((address_space(3))) void*)l, 16, 0, 0);
}

// ---------------- fp32 -> bf16 convert (8 elems/thread) ----------------
__global__ __launch_bounds__(256) void k_f32_to_bf16(const float* __restrict__ in,
                                                     uint16_t* __restrict__ out, int n8){
  int i = blockIdx.x * 256 + threadIdx.x;
  if (i >= n8) return;
  const float4* p = (const float4*)in;
  float4 a = p[2*i], b = p[2*i+1];
  union { short8 v; uint16_t u[8]; } o;
  o.u[0]=f2b(a.x); o.u[1]=f2b(a.y); o.u[2]=f2b(a.z); o.u[3]=f2b(a.w);
  o.u[4]=f2b(b.x); o.u[5]=f2b(b.y); o.u[6]=f2b(b.z); o.u[7]=f2b(b.w);
  ((short8*)out)[i] = o.v;
}

// ---------------- RoPE cos/sin tables: [2048][32] ----------------
__global__ __launch_bounds__(256) void k_tables(float* __restrict__ ct, float* __restrict__ st){
  int i = blockIdx.x * 256 + threadIdx.x;   // 65536
  int s = i >> 5, d = i & 31;
  float inv = __expf(-(float)d * (9.210340371976184f / 32.0f));  // 10000^(-d/32)
  float f = (float)s * inv;
  ct[i] = cosf(f);
  st[i] = sinf(f);
}

// ---------------- 256x256 GEMM, BK=32, 4-buffer counted-vmcnt pipeline ----------------
// C = A @ B^T + bias, bf16 out. 8 waves (2Mx4N), per-wave 128x64 output.
// LDS: A,B each [4 buf][256 rows][32 cols] = 128 KB total. Stage lookahead = 3
// tiles; per-tile boundary wait is vmcnt(8) (t+2,t+3 stay in flight) - never 0.
// Rowpair swizzle: 128B rowpair, slot8 = ((row&1)*4+g) ^ ((row>>1)&7); linear
// gload_lds dest + inverse-swizzled global source + same XOR on reads.
__global__ __launch_bounds__(512, 1) void k_gemm256(const uint16_t* __restrict__ A,
                                                    const uint16_t* __restrict__ B,
                                                    const float* __restrict__ bias,
                                                    uint16_t* __restrict__ C,
                                                    int M, int N, int K, int nbm){
  __shared__ uint16_t As[4*8192];   // [buf][rp(128)][slot8][8]
  __shared__ uint16_t Bs[4*8192];

  // XCD-aware bijective swizzle (nwg % 8 == 0)
  const int nwg = gridDim.x;
  const int wg = blockIdx.x;
  const int lin = (wg & 7) * (nwg >> 3) + (wg >> 3);
  const int m0 = (lin % nbm) * 256;
  const int n0 = (lin / nbm) * 256;

  const int tid = threadIdx.x;
  const int wid = tid >> 6, l = tid & 63;
  const int wm = wid >> 2, wn = wid & 3;       // 2 x 4 wave grid
  const int g = l >> 4, c = l & 15;

  // staging source offsets (inverse-swizzled), elems; add kt*32 at issue
  int srcA[2], srcB[2];
  #pragma unroll
  for (int j = 0; j < 2; ++j) {
    int rp = j*64 + (tid >> 3);
    int q  = tid & 7;
    int s  = q ^ (rp & 7);
    srcA[j] = (m0 + rp*2 + (s >> 2)) * K + (s & 3) * 8;
    srcB[j] = (n0 + rp*2 + (s >> 2)) * K + (s & 3) * 8;
  }

  // read-side addressing
  const int pg  = ((c & 1) << 2) | g;          // logical slot base
  const int ra0 = wm*64 + (c >> 1);            // A rowpair base (rows wm*128+c)
  const int rb0 = wn*32 + (c >> 1);            // B rowpair base (rows wn*64+c)

  f32x4 acc[8][4] = {};
  const int NT = K >> 5;                       // 64 K-tiles of 32

  // prologue: stage tiles 0,1,2
  #pragma unroll
  for (int t0 = 0; t0 < 3; ++t0) {
    #pragma unroll
    for (int j = 0; j < 2; ++j)
      g2l16(A + srcA[j] + t0*32, (void*)(As + t0*8192 + j*4096 + tid*8));
    #pragma unroll
    for (int j = 0; j < 2; ++j)
      g2l16(B + srcB[j] + t0*32, (void*)(Bs + t0*8192 + j*4096 + tid*8));
  }
  asm volatile("s_waitcnt vmcnt(8)" ::: "memory");   // tile 0 resident
  __builtin_amdgcn_s_barrier();

  for (int t = 0; t < NT; ++t) {
    const uint16_t* __restrict__ Ab = As + (t & 3)*8192;
    const uint16_t* __restrict__ Bb = Bs + (t & 3)*8192;
    const int t3 = t + 3;
    const bool pf = t3 < NT;
    const int b3 = (t3 & 3)*8192;

    // ---- phase 0: read a(mi0-3) + b(ni0-3); stage A(t+3); MFMA mi0-3 x ni0-3
    short8 av[4], bv[4];
    #pragma unroll
    for (int mi = 0; mi < 4; ++mi) {
      int rp = ra0 + mi*8;
      av[mi] = *(const short8*)&Ab[rp*64 + (pg ^ (rp & 7))*8];
    }
    #pragma unroll
    for (int ni = 0; ni < 4; ++ni) {
      int rp = rb0 + ni*8;
      bv[ni] = *(const short8*)&Bb[rp*64 + (pg ^ (rp & 7))*8];
    }
    if (pf) {
      #pragma unroll
      for (int j = 0; j < 2; ++j)
        g2l16(A + srcA[j] + t3*32, (void*)(As + b3 + j*4096 + tid*8));
    }
    __builtin_amdgcn_s_barrier();
    __builtin_amdgcn_s_setprio(1);
    #pragma unroll
    for (int mi = 0; mi < 4; ++mi)
      #pragma unroll
      for (int ni = 0; ni < 4; ++ni)
        acc[mi][ni] = __builtin_amdgcn_mfma_f32_16x16x32_bf16(av[mi], bv[ni], acc[mi][ni], 0, 0, 0);
    __builtin_amdgcn_s_setprio(0);
    __builtin_amdgcn_s_barrier();

    // ---- phase 1: read a(mi4-7); stage B(t+3); MFMA mi4-7 x ni0-3 (reuse bv)
    short8 av2[4];
    #pragma unroll
    for (int mi = 0; mi < 4; ++mi) {
      int rp = ra0 + (mi + 4)*8;
      av2[mi] = *(const short8*)&Ab[rp*64 + (pg ^ (rp & 7))*8];
    }
    if (pf) {
      #pragma unroll
      for (int j = 0; j < 2; ++j)
        g2l16(B + srcB[j] + t3*32, (void*)(Bs + b3 + j*4096 + tid*8));
    }
    __builtin_amdgcn_s_barrier();
    __builtin_amdgcn_s_setprio(1);
    #pragma unroll
    for (int mi = 0; mi < 4; ++mi)
      #pragma unroll
      for (int ni = 0; ni < 4; ++ni)
        acc[mi+4][ni] = __builtin_amdgcn_mfma_f32_16x16x32_bf16(av2[mi], bv[ni], acc[mi+4][ni], 0, 0, 0);
    __builtin_amdgcn_s_setprio(0);
    // counted boundary wait: t+1 resident, t+2/t+3 stay in flight (never 0)
    asm volatile("s_waitcnt vmcnt(8)" ::: "memory");
    __builtin_amdgcn_s_barrier();
  }

  // epilogue: bias + bf16 store
  #pragma unroll
  for (int ni = 0; ni < 4; ++ni) {
    const int col = n0 + wn*64 + ni*16 + c;
    const float bv = bias[col];
    #pragma unroll
    for (int mi = 0; mi < 8; ++mi) {
      const int row0 = m0 + wm*128 + mi*16 + g*4;
      #pragma unroll
      for (int j = 0; j < 4; ++j)
        C[(size_t)(row0 + j)*N + col] = f2b(acc[mi][ni][j] + bv);
    }
  }
}

// ---------------- GEMM: C[m,n] = sum_k A[m,k]*B[n,k] + bias[n] (128^2 tile) ----------------
template<bool OUT_BF16>
__global__ __launch_bounds__(256) void k_gemm_bt(const uint16_t* __restrict__ A,
                                                 const uint16_t* __restrict__ B,
                                                 const float* __restrict__ bias,
                                                 void* __restrict__ C,
                                                 int M, int N, int K){
  __shared__ uint16_t As[128*64];
  __shared__ uint16_t Bs[128*64];
  const int m0 = blockIdx.x * 128;
  const int n0 = blockIdx.y * 128;
  const int tid = threadIdx.x;
  const int w = tid >> 6, l = tid & 63;
  const int wr = w >> 1, wc = w & 1;
  const int g = l >> 4, c = l & 15;

  f32x4 acc[4][4] = {};

  const int srow = w*8 + (l >> 3);
  const int scol = (l & 7) * 8;

  for (int k0 = 0; k0 < K; k0 += 64) {
    #pragma unroll
    for (int i = 0; i < 4; ++i) {
      g2l16(A + (size_t)(m0 + i*32 + srow)*K + k0 + scol, (void*)(As + i*2048 + tid*8));
      g2l16(B + (size_t)(n0 + i*32 + srow)*K + k0 + scol, (void*)(Bs + i*2048 + tid*8));
    }
    asm volatile("s_waitcnt vmcnt(0)" ::: "memory");
    __syncthreads();
    #pragma unroll
    for (int kk = 0; kk < 2; ++kk) {
      short8 a[4], b[4];
      #pragma unroll
      for (int m = 0; m < 4; ++m)
        a[m] = *(const short8*)&As[(wr*64 + m*16 + c)*64 + kk*32 + g*8];
      #pragma unroll
      for (int n = 0; n < 4; ++n)
        b[n] = *(const short8*)&Bs[(wc*64 + n*16 + c)*64 + kk*32 + g*8];
      #pragma unroll
      for (int m = 0; m < 4; ++m)
        #pragma unroll
        for (int n = 0; n < 4; ++n)
          acc[m][n] = __builtin_amdgcn_mfma_f32_16x16x32_bf16(a[m], b[n], acc[m][n], 0, 0, 0);
    }
    __syncthreads();
  }

  #pragma unroll
  for (int n = 0; n < 4; ++n) {
    int col = n0 + wc*64 + n*16 + c;
    float bv = bias ? bias[col] : 0.0f;
    #pragma unroll
    for (int m = 0; m < 4; ++m) {
      int row0 = m0 + wr*64 + m*16 + g*4;
      #pragma unroll
      for (int j = 0; j < 4; ++j) {
        float v = acc[m][n][j] + bv;
        if (OUT_BF16) ((uint16_t*)C)[(size_t)(row0 + j)*N + col] = f2b(v);
        else          ((float*)C)[(size_t)(row0 + j)*N + col] = v;
      }
    }
  }
}

// ---------------- RoPE + head-split for Q,K (V handled by k_vt) ----------------
__global__ __launch_bounds__(256) void k_rope_split(const uint16_t* __restrict__ qkv,
                                                    const float* __restrict__ ct,
                                                    const float* __restrict__ st,
                                                    uint16_t* __restrict__ qo,
                                                    uint16_t* __restrict__ ko){
  int idx = blockIdx.x * 256 + threadIdx.x;   // which(2) x h(16) x s(2048) x db(16) = 2^20
  int db = idx & 15;
  int s  = (idx >> 4) & 2047;
  int h  = (idx >> 15) & 15;
  int which = idx >> 19;
  const uint16_t* src = qkv + (size_t)s * QKV_N + which * 2048 + h * 128;
  uint16_t* dst = (which ? ko : qo) + (((size_t)(h*2048 + s)) << 7) + db*8;
  const float scale = which ? 1.0f : ATT_SCALE;
  int d0 = db * 8;
  union { short8 v; uint16_t u[8]; } o;
  if (d0 >= 64) {
    short8 xv = *(const short8*)(src + d0);
    #pragma unroll
    for (int e = 0; e < 8; ++e) o.u[e] = f2b(b2f((uint16_t)xv[e]) * scale);
  } else {
    int dd = d0 & 31;
    short8 a = *(const short8*)(src + dd);
    short8 b = *(const short8*)(src + dd + 32);
    float4 c0 = *(const float4*)(ct + s*32 + dd);
    float4 c1 = *(const float4*)(ct + s*32 + dd + 4);
    float4 s0 = *(const float4*)(st + s*32 + dd);
    float4 s1 = *(const float4*)(st + s*32 + dd + 4);
    float cc[8] = {c0.x,c0.y,c0.z,c0.w,c1.x,c1.y,c1.z,c1.w};
    float ss[8] = {s0.x,s0.y,s0.z,s0.w,s1.x,s1.y,s1.z,s1.w};
    #pragma unroll
    for (int e = 0; e < 8; ++e) {
      float x1 = b2f((uint16_t)a[e]), x2 = b2f((uint16_t)b[e]);
      float v = (d0 < 32) ? (x1*cc[e] - x2*ss[e]) : (x1*ss[e] + x2*cc[e]);
      o.u[e] = f2b(v * scale);
    }
  }
  *(short8*)dst = o.v;
}

// ---------------- V transpose: qkv[s][4096+h*128+d] -> vt[h][d][s] ----------------
__global__ __launch_bounds__(256) void k_vt(const uint16_t* __restrict__ qkv,
                                            uint16_t* __restrict__ vt){
  __shared__ uint16_t tl[64][80];
  const int b = blockIdx.x;                 // h(16) x dt(2) x st(32)
  const int st_ = b & 31, dt = (b >> 5) & 1, h = b >> 6;
  const int tid = threadIdx.x;
  const int s_l = tid >> 2, cch = (tid & 3) * 16;
  const uint16_t* src = qkv + (size_t)(st_*64 + s_l) * QKV_N + 4096 + h*128 + dt*64 + cch;
  short8 a = *(const short8*)src;
  short8 b2 = *(const short8*)(src + 8);
  #pragma unroll
  for (int e = 0; e < 8; ++e) {
    tl[cch + e][s_l]     = (uint16_t)a[e];
    tl[cch + 8 + e][s_l] = (uint16_t)b2[e];
  }
  __syncthreads();
  const int d_l = tid >> 2;
  uint16_t* dst = vt + ((size_t)h << 18) + (size_t)(dt*64 + d_l) * 2048 + st_*64 + cch;
  *(short8*)dst       = *(const short8*)&tl[d_l][cch];
  *(short8*)(dst + 8) = *(const short8*)&tl[d_l][cch + 8];
}

// ---------------- causal flash attention v4: 8 waves, even/odd KV split ----------------
__global__ __launch_bounds__(512, 1) void k_attn(const uint16_t* __restrict__ Q,
                                                 const uint16_t* __restrict__ Kb,
                                                 const uint16_t* __restrict__ Vtg,
                                                 uint16_t* __restrict__ Out){
  __shared__ uint16_t Ks[2][2][64*128];   // [group][buf][k][d], swizzled
  __shared__ uint16_t Vs[2][2][128*64];   // [group][buf][d][k], swizzled
  __shared__ uint16_t Ps[8][16*88];       // per-wave P [q][k], stride 88

  const int bid = blockIdx.x;             // 256 blocks
  const int lin = (bid & 7) * 32 + (bid >> 3);
  const int h = lin >> 4;                 // XCD x gets heads {2x, 2x+1}
  const int pair = lin & 15;              // fold-pair within head

  const int tid = threadIdx.x, w = tid >> 6, l = tid & 63;
  const int gid = w >> 2, wq = w & 3;     // group, wave-in-group
  const int tg = tid & 255;               // thread index within group
  const int g = l >> 4, c = l & 15;
  const int swz = (c & 7) << 4;           // read-side byte swizzle

  const uint16_t* __restrict__ Qh = Q   + ((size_t)h << 18);
  const uint16_t* __restrict__ Kh = Kb  + ((size_t)h << 18);
  const uint16_t* __restrict__ Vh = Vtg + ((size_t)h << 18);
  float* scratch = (float*)&Ks[0][0][0];  // merge scratch (safe after last barrier)

  int koff[4], voff[4];
  #pragma unroll
  for (int j = 0; j < 4; ++j) {
    int kr = j*16 + (tg >> 4);                           // K row in tile
    koff[j] = kr*128 + (((tg & 15) ^ (kr & 7)) << 3);
    int vd = j*32 + (tg >> 3);                           // V^T row (d)
    voff[j] = vd*2048 + (((tg & 7) ^ (vd & 7)) << 3);
  }

  uint16_t* KsG = &Ks[gid][0][0];   // my group's K buffers (2 x 8192 elems)
  uint16_t* VsG = &Vs[gid][0][0];

  #pragma unroll 1
  for (int half = 0; half < 2; ++half) {
    const int qt = half ? (31 - pair) : pair;   // 64-row q-tile index
    const int nt = qt + 1;                      // KV tiles (KVBLK=64)
    const int nsteps = (nt + 1) >> 1;
    const int qrow = qt*64 + wq*16 + c;

    short8 qf[4];
    #pragma unroll
    for (int t = 0; t < 4; ++t)
      qf[t] = *(const short8*)&Qh[(size_t)qrow*128 + t*32 + g*8];

    f32x4 acc[8] = {};
    float mrow[4], lrow[4];
    #pragma unroll
    for (int j = 0; j < 4; ++j) { mrow[j] = -3e38f; lrow[j] = 0.0f; }

    if (gid < nt) {
      #pragma unroll
      for (int j = 0; j < 4; ++j) {
        g2l16(Kh + (size_t)gid*8192 + koff[j], (void*)(KsG + j*2048 + tg*8));
        g2l16(Vh + gid*64 + voff[j],           (void*)(VsG + j*2048 + tg*8));
      }
    }
    asm volatile("s_waitcnt vmcnt(0)" ::: "memory");
    __syncthreads();

    #pragma unroll 1
    for (int step = 0; step < nsteps; ++step) {
      const int kt = 2*step + gid;
      const int cur = step & 1;
      if (kt + 2 < nt) {
        const int k1 = kt + 2;
        #pragma unroll
        for (int j = 0; j < 4; ++j) {
          g2l16(Kh + (size_t)k1*8192 + koff[j], (void*)(KsG + (cur^1)*8192 + j*2048 + tg*8));
          g2l16(Vh + k1*64 + voff[j],           (void*)(VsG + (cur^1)*8192 + j*2048 + tg*8));
        }
      }

      if (kt < nt) {
        const int k0 = kt * 64;
        const uint16_t* Kcur = KsG + cur*8192;
        const uint16_t* Vcur = VsG + cur*8192;

        f32x4 sc4[4] = {};
        #pragma unroll
        for (int ct2 = 0; ct2 < 4; ++ct2) {
          const char* krp = (const char*)Kcur + (ct2*16 + c)*256;
          #pragma unroll
          for (int t = 0; t < 4; ++t) {
            short8 kb = *(const short8*)(krp + ((t*64 + g*16) ^ swz));
            sc4[ct2] = __builtin_amdgcn_mfma_f32_16x16x32_bf16(qf[t], kb, sc4[ct2], 0, 0, 0);
          }
        }

        const bool lastt = (kt == nt - 1);
        #pragma unroll
        for (int j = 0; j < 4; ++j) {
          const int qg = qt*64 + wq*16 + g*4 + j;
          float v0 = sc4[0][j], v1 = sc4[1][j], v2 = sc4[2][j], v3 = sc4[3][j];
          if (lastt) {
            if (k0 +      c > qg) v0 = -3e38f;
            if (k0 + 16 + c > qg) v1 = -3e38f;
            if (k0 + 32 + c > qg) v2 = -3e38f;
            if (k0 + 48 + c > qg) v3 = -3e38f;
          }
          float t0 = fmaxf(fmaxf(v0, v1), fmaxf(v2, v3));
          #pragma unroll
          for (int d2 = 1; d2 < 16; d2 <<= 1) t0 = fmaxf(t0, __shfl_xor(t0, d2, 64));
          const float mn = fmaxf(mrow[j], t0);
          const float scl = __expf(mrow[j] - mn);
          const float p0 = __expf(v0 - mn), p1 = __expf(v1 - mn),
                      p2 = __expf(v2 - mn), p3 = __expf(v3 - mn);
          float rs = (p0 + p1) + (p2 + p3);
          #pragma unroll
          for (int d2 = 1; d2 < 16; d2 <<= 1) rs += __shfl_xor(rs, d2, 64);
          lrow[j] = lrow[j]*scl + rs;
          mrow[j] = mn;
          #pragma unroll
          for (int n = 0; n < 8; ++n) acc[n][j] *= scl;
          uint16_t* pw = &Ps[w][(g*4 + j)*88];
          pw[c] = f2b(p0); pw[16+c] = f2b(p1); pw[32+c] = f2b(p2); pw[48+c] = f2b(p3);
        }

        #pragma unroll
        for (int kk = 0; kk < 2; ++kk) {
          short8 pf = *(const short8*)&Ps[w][c*88 + kk*32 + g*8];
          #pragma unroll
          for (int n = 0; n < 8; ++n) {
            const char* vrp = (const char*)Vcur + (n*16 + c)*128;
            short8 vf = *(const short8*)(vrp + ((kk*64 + g*16) ^ swz));
            acc[n] = __builtin_amdgcn_mfma_f32_16x16x32_bf16(pf, vf, acc[n], 0, 0, 0);
          }
        }
      }

      asm volatile("s_waitcnt vmcnt(0)" ::: "memory");
      __syncthreads();
    }

    // ---- merge group partial states: B (gid=1) publishes, A (gid=0) combines ----
    float* Up = scratch + wq * 2112;      // U[16][128] + m[16] + l[16]
    if (gid == 1) {
      #pragma unroll
      for (int j = 0; j < 4; ++j) {
        const int row = g*4 + j;
        #pragma unroll
        for (int n = 0; n < 8; ++n)
          Up[row*128 + n*16 + c] = acc[n][j];
        if (c == 0) { Up[2048 + row] = mrow[j]; Up[2064 + row] = lrow[j]; }
      }
    }
    __syncthreads();
    if (gid == 0) {
      #pragma unroll
      for (int j = 0; j < 4; ++j) {
        const int row = g*4 + j;
        const int qg = qt*64 + wq*16 + row;
        const float mB = Up[2048 + row], lB = Up[2064 + row];
        const float mn = fmaxf(mrow[j], mB);
        const float e1 = __expf(mrow[j] - mn);
        const float e2 = __expf(mB - mn);
        const float inv = 1.0f / (lrow[j]*e1 + lB*e2);
        #pragma unroll
        for (int n = 0; n < 8; ++n) {
          const float u = acc[n][j]*e1 + Up[row*128 + n*16 + c]*e2;
          Out[(size_t)qg*2048 + h*128 + n*16 + c] = f2b(u * inv);
        }
      }
    }
    __syncthreads();   // protect scratch before next half's staging overwrites K bufs
  }
}

extern "C" void kernel_launch(void* const* d_in, const int* in_sizes, int n_in,
                              void* d_out, int out_size, void* d_ws, size_t ws_size,
                              hipStream_t stream){
  const float* x    = (const float*)d_in[0];
  const float* Wqkv = (const float*)d_in[1];
  const float* bqkv = (const float*)d_in[2];
  const float* Wo   = (const float*)d_in[3];
  const float* bo   = (const float*)d_in[4];

  char* ws = (char*)d_ws;
  uint16_t* q_bf    = (uint16_t*)(ws);                 //  8.39 MB [16][2048][128]
  uint16_t* k_bf    = (uint16_t*)(ws + 8388608);       //  8.39 MB [16][2048][128]
  uint16_t* vt_bf   = (uint16_t*)(ws + 16777216);      //  8.39 MB [16][128][2048]
  uint16_t* attn_bf = (uint16_t*)(ws + 25165824);      //  8.39 MB (aliased with x_bf)
  uint16_t* x_bf    = attn_bf;                         //  x dead before attn writes
  uint16_t* wqkv_bf = (uint16_t*)(ws + 33554432);      // 25.17 MB
  uint16_t* wo_bf   = (uint16_t*)(ws + 58720256);      //  8.39 MB
  uint16_t* qkv_bf  = (uint16_t*)(ws + 67108864);      // 25.17 MB
  float*    cos_t   = (float*)(ws + 92274688);         //  0.26 MB
  float*    sin_t   = (float*)(ws + 92536832);         //  0.26 MB

  k_tables<<<dim3(256), dim3(256), 0, stream>>>(cos_t, sin_t);
  k_f32_to_bf16<<<dim3(2048), dim3(256), 0, stream>>>(x, x_bf, 524288);
  k_f32_to_bf16<<<dim3(6144), dim3(256), 0, stream>>>(Wqkv, wqkv_bf, 1572864);
  k_f32_to_bf16<<<dim3(2048), dim3(256), 0, stream>>>(Wo, wo_bf, 524288);

  // qkv = x @ Wqkv^T + b   -> bf16 [2048][6144]  (256^2 BK=32 4-buf pipeline)
  k_gemm256<<<dim3(192), dim3(512), 0, stream>>>(x_bf, wqkv_bf, bqkv, qkv_bf,
                                                 2048, 6144, 2048, 8);
  // RoPE + split Q,K (Q pre-scaled); V transposed to [h][d][s]
  k_rope_split<<<dim3(4096), dim3(256), 0, stream>>>(qkv_bf, cos_t, sin_t, q_bf, k_bf);
  k_vt<<<dim3(1024), dim3(256), 0, stream>>>(qkv_bf, vt_bf);
  // causal flash attention -> attn_bf [2048][2048]
  k_attn<<<dim3(256), dim3(512), 0, stream>>>(q_bf, k_bf, vt_bf, attn_bf);
  // out = attn @ Wo^T + bo -> f32 d_out (128^2 tile, 256 blocks = full CU coverage)
  k_gemm_bt<false><<<dim3(16, 16), dim3(256), 0, stream>>>(attn_bf, wo_bf, bo,
                                                           d_out, 2048, 2048, 2048);
}

// Round 7
// 186.920 us; speedup vs baseline: 2.0730x; 1.0826x over previous
//
#include <hip/hip_runtime.h>
#include <stdint.h>

// Problem constants
#define QKV_N 6144
#define ATT_SCALE 0.08838834764831845f   // 1/sqrt(128)

typedef __attribute__((ext_vector_type(8))) short short8;   // 8 bf16 (4 VGPRs)
typedef __attribute__((ext_vector_type(4))) float f32x4;

__device__ __forceinline__ uint16_t f2b(float x){
  uint32_t u = __float_as_uint(x);
  uint32_t r = (u + 0x7fffu + ((u >> 16) & 1u)) >> 16;   // RNE
  return (uint16_t)r;
}
__device__ __forceinline__ float b2f(uint16_t h){
  return __uint_as_float(((uint32_t)h) << 16);
}
__device__ __forceinline__ void g2l16(const void* g, void* l){
  __builtin_amdgcn_global_load_lds((const __attribute__((address_space(1))) void*)g,
                                   (__attribute__((address_space(3))) void*)l, 16, 0, 0);
}

// ---------------- fp32 -> bf16 convert (8 elems/thread) ----------------
__global__ __launch_bounds__(256) void k_f32_to_bf16(const float* __restrict__ in,
                                                     uint16_t* __restrict__ out, int n8){
  int i = blockIdx.x * 256 + threadIdx.x;
  if (i >= n8) return;
  const float4* p = (const float4*)in;
  float4 a = p[2*i], b = p[2*i+1];
  union { short8 v; uint16_t u[8]; } o;
  o.u[0]=f2b(a.x); o.u[1]=f2b(a.y); o.u[2]=f2b(a.z); o.u[3]=f2b(a.w);
  o.u[4]=f2b(b.x); o.u[5]=f2b(b.y); o.u[6]=f2b(b.z); o.u[7]=f2b(b.w);
  ((short8*)out)[i] = o.v;
}

// ---------------- RoPE cos/sin tables: [2048][32] ----------------
__global__ __launch_bounds__(256) void k_tables(float* __restrict__ ct, float* __restrict__ st){
  int i = blockIdx.x * 256 + threadIdx.x;   // 65536
  int s = i >> 5, d = i & 31;
  float inv = __expf(-(float)d * (9.210340371976184f / 32.0f));  // 10000^(-d/32)
  float f = (float)s * inv;
  ct[i] = cosf(f);
  st[i] = sinf(f);
}

// ---------------- 256x192 GEMM, BK=32, 4-buffer counted-vmcnt pipeline ----------------
// C = A @ B^T + bias, bf16 out. 8 waves (2Mx4N), per-wave 128x48 output.
// Grid (M/256)x(N/192) = 256 blocks -> full CU coverage.
// Rowpair swizzle: slot8 = ((row&1)*4+g) ^ ((row>>1)&7); linear gload_lds dest
// + inverse-swizzled global source + same XOR on reads. Boundary wait is
// counted vmcnt (8 for waves 0-3, 6 for waves 4-7; B half-issue is tid<256).
__global__ __launch_bounds__(512, 1) void k_gemm256(const uint16_t* __restrict__ A,
                                                    const uint16_t* __restrict__ B,
                                                    const float* __restrict__ bias,
                                                    uint16_t* __restrict__ C,
                                                    int M, int N, int K, int nbm){
  __shared__ uint16_t As[4*8192];   // [buf][rp(128)][slot8][8]  BM=256
  __shared__ uint16_t Bs[4*6144];   // [buf][rp(96)][slot8][8]   BN=192

  const int nwg = gridDim.x;
  const int wg = blockIdx.x;
  const int lin = (wg & 7) * (nwg >> 3) + (wg >> 3);
  const int m0 = (lin % nbm) * 256;
  const int n0 = (lin / nbm) * 192;

  const int tid = threadIdx.x;
  const int wid = tid >> 6, l = tid & 63;
  const int wm = wid >> 2, wn = wid & 3;       // 2 x 4 wave grid
  const int g = l >> 4, c = l & 15;

  // staging source offsets (inverse-swizzled), elems; add kt*32 at issue
  int srcA[2], srcB[2];
  #pragma unroll
  for (int j = 0; j < 2; ++j) {
    int rp = j*64 + (tid >> 3);
    int q  = tid & 7;
    int s  = q ^ (rp & 7);
    srcA[j] = (m0 + rp*2 + (s >> 2)) * K + (s & 3) * 8;
    srcB[j] = (n0 + rp*2 + (s >> 2)) * K + (s & 3) * 8;   // j=1 only used by tid<256
  }

  // read-side addressing
  const int pg  = ((c & 1) << 2) | g;          // logical slot base
  const int ra0 = wm*64 + (c >> 1);            // A rowpair base (rows wm*128+c)
  const int rb0 = wn*24 + (c >> 1);            // B rowpair base (rows wn*48+c)

  f32x4 acc[8][3] = {};
  const int NT = K >> 5;                       // 64 K-tiles of 32

  // prologue: stage tiles 0,1,2
  #pragma unroll
  for (int t0 = 0; t0 < 3; ++t0) {
    #pragma unroll
    for (int j = 0; j < 2; ++j)
      g2l16(A + srcA[j] + t0*32, (void*)(As + t0*8192 + j*4096 + tid*8));
    g2l16(B + srcB[0] + t0*32, (void*)(Bs + t0*6144 + tid*8));
    if (tid < 256)
      g2l16(B + srcB[1] + t0*32, (void*)(Bs + t0*6144 + 4096 + tid*8));
  }
  if (wid < 4) { asm volatile("s_waitcnt vmcnt(8)" ::: "memory"); }
  else         { asm volatile("s_waitcnt vmcnt(6)" ::: "memory"); }
  __builtin_amdgcn_s_barrier();

  for (int t = 0; t < NT; ++t) {
    const uint16_t* __restrict__ Ab = As + (t & 3)*8192;
    const uint16_t* __restrict__ Bb = Bs + (t & 3)*6144;
    const int t3 = t + 3;
    const bool pf = t3 < NT;
    const int a3 = (t3 & 3)*8192;
    const int b3 = (t3 & 3)*6144;

    // ---- phase 0: read a(mi0-3) + b(ni0-2); stage A(t+3); MFMA mi0-3 x ni0-2
    short8 av[4], bv[3];
    #pragma unroll
    for (int mi = 0; mi < 4; ++mi) {
      int rp = ra0 + mi*8;
      av[mi] = *(const short8*)&Ab[rp*64 + (pg ^ (rp & 7))*8];
    }
    #pragma unroll
    for (int ni = 0; ni < 3; ++ni) {
      int rp = rb0 + ni*8;
      bv[ni] = *(const short8*)&Bb[rp*64 + (pg ^ (rp & 7))*8];
    }
    if (pf) {
      #pragma unroll
      for (int j = 0; j < 2; ++j)
        g2l16(A + srcA[j] + t3*32, (void*)(As + a3 + j*4096 + tid*8));
    }
    __builtin_amdgcn_s_barrier();
    __builtin_amdgcn_s_setprio(1);
    #pragma unroll
    for (int mi = 0; mi < 4; ++mi)
      #pragma unroll
      for (int ni = 0; ni < 3; ++ni)
        acc[mi][ni] = __builtin_amdgcn_mfma_f32_16x16x32_bf16(av[mi], bv[ni], acc[mi][ni], 0, 0, 0);
    __builtin_amdgcn_s_setprio(0);
    __builtin_amdgcn_s_barrier();

    // ---- phase 1: read a(mi4-7); stage B(t+3); MFMA mi4-7 x ni0-2 (reuse bv)
    short8 av2[4];
    #pragma unroll
    for (int mi = 0; mi < 4; ++mi) {
      int rp = ra0 + (mi + 4)*8;
      av2[mi] = *(const short8*)&Ab[rp*64 + (pg ^ (rp & 7))*8];
    }
    if (pf) {
      g2l16(B + srcB[0] + t3*32, (void*)(Bs + b3 + tid*8));
      if (tid < 256)
        g2l16(B + srcB[1] + t3*32, (void*)(Bs + b3 + 4096 + tid*8));
    }
    __builtin_amdgcn_s_barrier();
    __builtin_amdgcn_s_setprio(1);
    #pragma unroll
    for (int mi = 0; mi < 4; ++mi)
      #pragma unroll
      for (int ni = 0; ni < 3; ++ni)
        acc[mi+4][ni] = __builtin_amdgcn_mfma_f32_16x16x32_bf16(av2[mi], bv[ni], acc[mi+4][ni], 0, 0, 0);
    __builtin_amdgcn_s_setprio(0);
    // counted boundary wait: t+1 resident, t+2/t+3 stay in flight (never 0)
    if (wid < 4) { asm volatile("s_waitcnt vmcnt(8)" ::: "memory"); }
    else         { asm volatile("s_waitcnt vmcnt(6)" ::: "memory"); }
    __builtin_amdgcn_s_barrier();
  }

  // epilogue: bias + bf16 store
  #pragma unroll
  for (int ni = 0; ni < 3; ++ni) {
    const int col = n0 + wn*48 + ni*16 + c;
    const float bv = bias[col];
    #pragma unroll
    for (int mi = 0; mi < 8; ++mi) {
      const int row0 = m0 + wm*128 + mi*16 + g*4;
      #pragma unroll
      for (int j = 0; j < 4; ++j)
        C[(size_t)(row0 + j)*N + col] = f2b(acc[mi][ni][j] + bv);
    }
  }
}

// ---------------- 128x128 GEMM, BK=32, 4-buffer counted-vmcnt, f32 out ----------------
// 8 waves (2Mx4N), per-wave 64x32 output. Grid (M/128)x(N/128) blocks.
__global__ __launch_bounds__(512, 1) void k_gemm128(const uint16_t* __restrict__ A,
                                                    const uint16_t* __restrict__ B,
                                                    const float* __restrict__ bias,
                                                    float* __restrict__ C,
                                                    int M, int N, int K, int nbm){
  __shared__ uint16_t As[4*4096];   // [buf][rp(64)][slot8][8]
  __shared__ uint16_t Bs[4*4096];

  const int nwg = gridDim.x;
  const int wg = blockIdx.x;
  const int lin = (wg & 7) * (nwg >> 3) + (wg >> 3);
  const int m0 = (lin % nbm) * 128;
  const int n0 = (lin / nbm) * 128;

  const int tid = threadIdx.x;
  const int wid = tid >> 6, l = tid & 63;
  const int wm = wid >> 2, wn = wid & 3;
  const int g = l >> 4, c = l & 15;

  const int rp_s = tid >> 3, q_s = tid & 7, s_s = q_s ^ (rp_s & 7);
  const int srcA = (m0 + rp_s*2 + (s_s >> 2)) * K + (s_s & 3) * 8;
  const int srcB = (n0 + rp_s*2 + (s_s >> 2)) * K + (s_s & 3) * 8;

  const int pg  = ((c & 1) << 2) | g;
  const int ra0 = wm*32 + (c >> 1);            // rows wm*64+c
  const int rb0 = wn*16 + (c >> 1);            // rows wn*32+c

  f32x4 acc[4][2] = {};
  const int NT = K >> 5;

  #pragma unroll
  for (int t0 = 0; t0 < 3; ++t0) {
    g2l16(A + srcA + t0*32, (void*)(As + t0*4096 + tid*8));
    g2l16(B + srcB + t0*32, (void*)(Bs + t0*4096 + tid*8));
  }
  asm volatile("s_waitcnt vmcnt(4)" ::: "memory");
  __builtin_amdgcn_s_barrier();

  for (int t = 0; t < NT; ++t) {
    const uint16_t* __restrict__ Ab = As + (t & 3)*4096;
    const uint16_t* __restrict__ Bb = Bs + (t & 3)*4096;
    const int t3 = t + 3;
    const int b3 = (t3 & 3)*4096;

    short8 av[4], bv[2];
    #pragma unroll
    for (int mi = 0; mi < 4; ++mi) {
      int rp = ra0 + mi*8;
      av[mi] = *(const short8*)&Ab[rp*64 + (pg ^ (rp & 7))*8];
    }
    #pragma unroll
    for (int ni = 0; ni < 2; ++ni) {
      int rp = rb0 + ni*8;
      bv[ni] = *(const short8*)&Bb[rp*64 + (pg ^ (rp & 7))*8];
    }
    if (t3 < NT) {
      g2l16(A + srcA + t3*32, (void*)(As + b3 + tid*8));
      g2l16(B + srcB + t3*32, (void*)(Bs + b3 + tid*8));
    }
    __builtin_amdgcn_s_barrier();
    __builtin_amdgcn_s_setprio(1);
    #pragma unroll
    for (int mi = 0; mi < 4; ++mi)
      #pragma unroll
      for (int ni = 0; ni < 2; ++ni)
        acc[mi][ni] = __builtin_amdgcn_mfma_f32_16x16x32_bf16(av[mi], bv[ni], acc[mi][ni], 0, 0, 0);
    __builtin_amdgcn_s_setprio(0);
    asm volatile("s_waitcnt vmcnt(4)" ::: "memory");
    __builtin_amdgcn_s_barrier();
  }

  #pragma unroll
  for (int ni = 0; ni < 2; ++ni) {
    const int col = n0 + wn*32 + ni*16 + c;
    const float bvl = bias[col];
    #pragma unroll
    for (int mi = 0; mi < 4; ++mi) {
      const int row0 = m0 + wm*64 + mi*16 + g*4;
      #pragma unroll
      for (int j = 0; j < 4; ++j)
        C[(size_t)(row0 + j)*N + col] = acc[mi][ni][j] + bvl;
    }
  }
}

// ---------------- RoPE + head-split for Q,K (V handled by k_vt) ----------------
__global__ __launch_bounds__(256) void k_rope_split(const uint16_t* __restrict__ qkv,
                                                    const float* __restrict__ ct,
                                                    const float* __restrict__ st,
                                                    uint16_t* __restrict__ qo,
                                                    uint16_t* __restrict__ ko){
  int idx = blockIdx.x * 256 + threadIdx.x;   // which(2) x h(16) x s(2048) x db(16) = 2^20
  int db = idx & 15;
  int s  = (idx >> 4) & 2047;
  int h  = (idx >> 15) & 15;
  int which = idx >> 19;
  const uint16_t* src = qkv + (size_t)s * QKV_N + which * 2048 + h * 128;
  uint16_t* dst = (which ? ko : qo) + (((size_t)(h*2048 + s)) << 7) + db*8;
  const float scale = which ? 1.0f : ATT_SCALE;
  int d0 = db * 8;
  union { short8 v; uint16_t u[8]; } o;
  if (d0 >= 64) {
    short8 xv = *(const short8*)(src + d0);
    #pragma unroll
    for (int e = 0; e < 8; ++e) o.u[e] = f2b(b2f((uint16_t)xv[e]) * scale);
  } else {
    int dd = d0 & 31;
    short8 a = *(const short8*)(src + dd);
    short8 b = *(const short8*)(src + dd + 32);
    float4 c0 = *(const float4*)(ct + s*32 + dd);
    float4 c1 = *(const float4*)(ct + s*32 + dd + 4);
    float4 s0 = *(const float4*)(st + s*32 + dd);
    float4 s1 = *(const float4*)(st + s*32 + dd + 4);
    float cc[8] = {c0.x,c0.y,c0.z,c0.w,c1.x,c1.y,c1.z,c1.w};
    float ss[8] = {s0.x,s0.y,s0.z,s0.w,s1.x,s1.y,s1.z,s1.w};
    #pragma unroll
    for (int e = 0; e < 8; ++e) {
      float x1 = b2f((uint16_t)a[e]), x2 = b2f((uint16_t)b[e]);
      float v = (d0 < 32) ? (x1*cc[e] - x2*ss[e]) : (x1*ss[e] + x2*cc[e]);
      o.u[e] = f2b(v * scale);
    }
  }
  *(short8*)dst = o.v;
}

// ---------------- V transpose: qkv[s][4096+h*128+d] -> vt[h][d][s] ----------------
__global__ __launch_bounds__(256) void k_vt(const uint16_t* __restrict__ qkv,
                                            uint16_t* __restrict__ vt){
  __shared__ uint16_t tl[64][80];
  const int b = blockIdx.x;                 // h(16) x dt(2) x st(32)
  const int st_ = b & 31, dt = (b >> 5) & 1, h = b >> 6;
  const int tid = threadIdx.x;
  const int s_l = tid >> 2, cch = (tid & 3) * 16;
  const uint16_t* src = qkv + (size_t)(st_*64 + s_l) * QKV_N + 4096 + h*128 + dt*64 + cch;
  short8 a = *(const short8*)src;
  short8 b2 = *(const short8*)(src + 8);
  #pragma unroll
  for (int e = 0; e < 8; ++e) {
    tl[cch + e][s_l]     = (uint16_t)a[e];
    tl[cch + 8 + e][s_l] = (uint16_t)b2[e];
  }
  __syncthreads();
  const int d_l = tid >> 2;
  uint16_t* dst = vt + ((size_t)h << 18) + (size_t)(dt*64 + d_l) * 2048 + st_*64 + cch;
  *(short8*)dst       = *(const short8*)&tl[d_l][cch];
  *(short8*)(dst + 8) = *(const short8*)&tl[d_l][cch + 8];
}

// ---------------- causal flash attention v4: 8 waves, even/odd KV split ----------------
__global__ __launch_bounds__(512, 1) void k_attn(const uint16_t* __restrict__ Q,
                                                 const uint16_t* __restrict__ Kb,
                                                 const uint16_t* __restrict__ Vtg,
                                                 uint16_t* __restrict__ Out){
  __shared__ uint16_t Ks[2][2][64*128];   // [group][buf][k][d], swizzled
  __shared__ uint16_t Vs[2][2][128*64];   // [group][buf][d][k], swizzled
  __shared__ uint16_t Ps[8][16*88];       // per-wave P [q][k], stride 88

  const int bid = blockIdx.x;             // 256 blocks
  const int lin = (bid & 7) * 32 + (bid >> 3);
  const int h = lin >> 4;                 // XCD x gets heads {2x, 2x+1}
  const int pair = lin & 15;              // fold-pair within head

  const int tid = threadIdx.x, w = tid >> 6, l = tid & 63;
  const int gid = w >> 2, wq = w & 3;     // group, wave-in-group
  const int tg = tid & 255;               // thread index within group
  const int g = l >> 4, c = l & 15;
  const int swz = (c & 7) << 4;           // read-side byte swizzle

  const uint16_t* __restrict__ Qh = Q   + ((size_t)h << 18);
  const uint16_t* __restrict__ Kh = Kb  + ((size_t)h << 18);
  const uint16_t* __restrict__ Vh = Vtg + ((size_t)h << 18);
  float* scratch = (float*)&Ks[0][0][0];  // merge scratch (safe after last barrier)

  int koff[4], voff[4];
  #pragma unroll
  for (int j = 0; j < 4; ++j) {
    int kr = j*16 + (tg >> 4);                           // K row in tile
    koff[j] = kr*128 + (((tg & 15) ^ (kr & 7)) << 3);
    int vd = j*32 + (tg >> 3);                           // V^T row (d)
    voff[j] = vd*2048 + (((tg & 7) ^ (vd & 7)) << 3);
  }

  uint16_t* KsG = &Ks[gid][0][0];   // my group's K buffers (2 x 8192 elems)
  uint16_t* VsG = &Vs[gid][0][0];

  #pragma unroll 1
  for (int half = 0; half < 2; ++half) {
    const int qt = half ? (31 - pair) : pair;   // 64-row q-tile index
    const int nt = qt + 1;                      // KV tiles (KVBLK=64)
    const int nsteps = (nt + 1) >> 1;
    const int qrow = qt*64 + wq*16 + c;

    short8 qf[4];
    #pragma unroll
    for (int t = 0; t < 4; ++t)
      qf[t] = *(const short8*)&Qh[(size_t)qrow*128 + t*32 + g*8];

    f32x4 acc[8] = {};
    float mrow[4], lrow[4];
    #pragma unroll
    for (int j = 0; j < 4; ++j) { mrow[j] = -3e38f; lrow[j] = 0.0f; }

    if (gid < nt) {
      #pragma unroll
      for (int j = 0; j < 4; ++j) {
        g2l16(Kh + (size_t)gid*8192 + koff[j], (void*)(KsG + j*2048 + tg*8));
        g2l16(Vh + gid*64 + voff[j],           (void*)(VsG + j*2048 + tg*8));
      }
    }
    asm volatile("s_waitcnt vmcnt(0)" ::: "memory");
    __syncthreads();

    #pragma unroll 1
    for (int step = 0; step < nsteps; ++step) {
      const int kt = 2*step + gid;
      const int cur = step & 1;
      if (kt + 2 < nt) {
        const int k1 = kt + 2;
        #pragma unroll
        for (int j = 0; j < 4; ++j) {
          g2l16(Kh + (size_t)k1*8192 + koff[j], (void*)(KsG + (cur^1)*8192 + j*2048 + tg*8));
          g2l16(Vh + k1*64 + voff[j],           (void*)(VsG + (cur^1)*8192 + j*2048 + tg*8));
        }
      }

      if (kt < nt) {
        const int k0 = kt * 64;
        const uint16_t* Kcur = KsG + cur*8192;
        const uint16_t* Vcur = VsG + cur*8192;

        f32x4 sc4[4] = {};
        #pragma unroll
        for (int ct2 = 0; ct2 < 4; ++ct2) {
          const char* krp = (const char*)Kcur + (ct2*16 + c)*256;
          #pragma unroll
          for (int t = 0; t < 4; ++t) {
            short8 kb = *(const short8*)(krp + ((t*64 + g*16) ^ swz));
            sc4[ct2] = __builtin_amdgcn_mfma_f32_16x16x32_bf16(qf[t], kb, sc4[ct2], 0, 0, 0);
          }
        }

        const bool lastt = (kt == nt - 1);
        #pragma unroll
        for (int j = 0; j < 4; ++j) {
          const int qg = qt*64 + wq*16 + g*4 + j;
          float v0 = sc4[0][j], v1 = sc4[1][j], v2 = sc4[2][j], v3 = sc4[3][j];
          if (lastt) {
            if (k0 +      c > qg) v0 = -3e38f;
            if (k0 + 16 + c > qg) v1 = -3e38f;
            if (k0 + 32 + c > qg) v2 = -3e38f;
            if (k0 + 48 + c > qg) v3 = -3e38f;
          }
          float t0 = fmaxf(fmaxf(v0, v1), fmaxf(v2, v3));
          #pragma unroll
          for (int d2 = 1; d2 < 16; d2 <<= 1) t0 = fmaxf(t0, __shfl_xor(t0, d2, 64));
          const float mn = fmaxf(mrow[j], t0);
          const float scl = __expf(mrow[j] - mn);
          const float p0 = __expf(v0 - mn), p1 = __expf(v1 - mn),
                      p2 = __expf(v2 - mn), p3 = __expf(v3 - mn);
          float rs = (p0 + p1) + (p2 + p3);
          #pragma unroll
          for (int d2 = 1; d2 < 16; d2 <<= 1) rs += __shfl_xor(rs, d2, 64);
          lrow[j] = lrow[j]*scl + rs;
          mrow[j] = mn;
          #pragma unroll
          for (int n = 0; n < 8; ++n) acc[n][j] *= scl;
          uint16_t* pw = &Ps[w][(g*4 + j)*88];
          pw[c] = f2b(p0); pw[16+c] = f2b(p1); pw[32+c] = f2b(p2); pw[48+c] = f2b(p3);
        }

        #pragma unroll
        for (int kk = 0; kk < 2; ++kk) {
          short8 pf = *(const short8*)&Ps[w][c*88 + kk*32 + g*8];
          #pragma unroll
          for (int n = 0; n < 8; ++n) {
            const char* vrp = (const char*)Vcur + (n*16 + c)*128;
            short8 vf = *(const short8*)(vrp + ((kk*64 + g*16) ^ swz));
            acc[n] = __builtin_amdgcn_mfma_f32_16x16x32_bf16(pf, vf, acc[n], 0, 0, 0);
          }
        }
      }

      asm volatile("s_waitcnt vmcnt(0)" ::: "memory");
      __syncthreads();
    }

    // ---- merge group partial states: B (gid=1) publishes, A (gid=0) combines ----
    float* Up = scratch + wq * 2112;      // U[16][128] + m[16] + l[16]
    if (gid == 1) {
      #pragma unroll
      for (int j = 0; j < 4; ++j) {
        const int row = g*4 + j;
        #pragma unroll
        for (int n = 0; n < 8; ++n)
          Up[row*128 + n*16 + c] = acc[n][j];
        if (c == 0) { Up[2048 + row] = mrow[j]; Up[2064 + row] = lrow[j]; }
      }
    }
    __syncthreads();
    if (gid == 0) {
      #pragma unroll
      for (int j = 0; j < 4; ++j) {
        const int row = g*4 + j;
        const int qg = qt*64 + wq*16 + row;
        const float mB = Up[2048 + row], lB = Up[2064 + row];
        const float mn = fmaxf(mrow[j], mB);
        const float e1 = __expf(mrow[j] - mn);
        const float e2 = __expf(mB - mn);
        const float inv = 1.0f / (lrow[j]*e1 + lB*e2);
        #pragma unroll
        for (int n = 0; n < 8; ++n) {
          const float u = acc[n][j]*e1 + Up[row*128 + n*16 + c]*e2;
          Out[(size_t)qg*2048 + h*128 + n*16 + c] = f2b(u * inv);
        }
      }
    }
    __syncthreads();   // protect scratch before next half's staging overwrites K bufs
  }
}

extern "C" void kernel_launch(void* const* d_in, const int* in_sizes, int n_in,
                              void* d_out, int out_size, void* d_ws, size_t ws_size,
                              hipStream_t stream){
  const float* x    = (const float*)d_in[0];
  const float* Wqkv = (const float*)d_in[1];
  const float* bqkv = (const float*)d_in[2];
  const float* Wo   = (const float*)d_in[3];
  const float* bo   = (const float*)d_in[4];

  char* ws = (char*)d_ws;
  uint16_t* q_bf    = (uint16_t*)(ws);                 //  8.39 MB [16][2048][128]
  uint16_t* k_bf    = (uint16_t*)(ws + 8388608);       //  8.39 MB [16][2048][128]
  uint16_t* vt_bf   = (uint16_t*)(ws + 16777216);      //  8.39 MB [16][128][2048]
  uint16_t* attn_bf = (uint16_t*)(ws + 25165824);      //  8.39 MB (aliased with x_bf)
  uint16_t* x_bf    = attn_bf;                         //  x dead before attn writes
  uint16_t* wqkv_bf = (uint16_t*)(ws + 33554432);      // 25.17 MB
  uint16_t* wo_bf   = (uint16_t*)(ws + 58720256);      //  8.39 MB
  uint16_t* qkv_bf  = (uint16_t*)(ws + 67108864);      // 25.17 MB
  float*    cos_t   = (float*)(ws + 92274688);         //  0.26 MB
  float*    sin_t   = (float*)(ws + 92536832);         //  0.26 MB

  k_tables<<<dim3(256), dim3(256), 0, stream>>>(cos_t, sin_t);
  k_f32_to_bf16<<<dim3(2048), dim3(256), 0, stream>>>(x, x_bf, 524288);
  k_f32_to_bf16<<<dim3(6144), dim3(256), 0, stream>>>(Wqkv, wqkv_bf, 1572864);
  k_f32_to_bf16<<<dim3(2048), dim3(256), 0, stream>>>(Wo, wo_bf, 524288);

  // qkv = x @ Wqkv^T + b   -> bf16 [2048][6144]  (256x192 tiles, 256 blocks)
  k_gemm256<<<dim3(256), dim3(512), 0, stream>>>(x_bf, wqkv_bf, bqkv, qkv_bf,
                                                 2048, 6144, 2048, 8);
  // RoPE + split Q,K (Q pre-scaled); V transposed to [h][d][s]
  k_rope_split<<<dim3(4096), dim3(256), 0, stream>>>(qkv_bf, cos_t, sin_t, q_bf, k_bf);
  k_vt<<<dim3(1024), dim3(256), 0, stream>>>(qkv_bf, vt_bf);
  // causal flash attention -> attn_bf [2048][2048]
  k_attn<<<dim3(256), dim3(512), 0, stream>>>(q_bf, k_bf, vt_bf, attn_bf);
  // out = attn @ Wo^T + bo -> f32 d_out (128^2 pipeline, 256 blocks)
  k_gemm128<<<dim3(256), dim3(512), 0, stream>>>(attn_bf, wo_bf, bo, (float*)d_out,
                                                 2048, 2048, 2048, 16);
}

// Round 8
// 173.505 us; speedup vs baseline: 2.2333x; 1.0773x over previous
//
#include <hip/hip_runtime.h>
#include <stdint.h>

// Problem constants
#define QKV_N 6144
#define ATT_SCALE 0.08838834764831845f   // 1/sqrt(128)

typedef __attribute__((ext_vector_type(8))) short short8;   // 8 bf16 (4 VGPRs)
typedef __attribute__((ext_vector_type(4))) float f32x4;

__device__ __forceinline__ uint16_t f2b(float x){
  uint32_t u = __float_as_uint(x);
  uint32_t r = (u + 0x7fffu + ((u >> 16) & 1u)) >> 16;   // RNE
  return (uint16_t)r;
}
__device__ __forceinline__ float b2f(uint16_t h){
  return __uint_as_float(((uint32_t)h) << 16);
}
__device__ __forceinline__ void g2l16(const void* g, void* l){
  __builtin_amdgcn_global_load_lds((const __attribute__((address_space(1))) void*)g,
                                   (__attribute__((address_space(3))) void*)l, 16, 0, 0);
}

// ---------------- fused prep: fp32->bf16 converts + RoPE tables ----------------
__device__ __forceinline__ void cvt8(const float* __restrict__ in, uint16_t* __restrict__ out, int i){
  const float4* p = (const float4*)in;
  float4 a = p[2*i], b = p[2*i+1];
  union { short8 v; uint16_t u[8]; } o;
  o.u[0]=f2b(a.x); o.u[1]=f2b(a.y); o.u[2]=f2b(a.z); o.u[3]=f2b(a.w);
  o.u[4]=f2b(b.x); o.u[5]=f2b(b.y); o.u[6]=f2b(b.z); o.u[7]=f2b(b.w);
  ((short8*)out)[i] = o.v;
}

__global__ __launch_bounds__(256) void k_prep(const float* __restrict__ x,
                                              const float* __restrict__ wqkv,
                                              const float* __restrict__ wo,
                                              uint16_t* __restrict__ xb,
                                              uint16_t* __restrict__ wqkvb,
                                              uint16_t* __restrict__ wob,
                                              float* __restrict__ ct,
                                              float* __restrict__ st){
  const int b = blockIdx.x, tid = threadIdx.x;
  if (b < 2048) {                         // x: 4.19M elems
    cvt8(x, xb, b*256 + tid);
  } else if (b < 8192) {                  // Wqkv: 12.58M elems
    cvt8(wqkv, wqkvb, (b - 2048)*256 + tid);
  } else if (b < 10240) {                 // Wo: 4.19M elems
    cvt8(wo, wob, (b - 8192)*256 + tid);
  } else {                                // tables [2048][32]
    int i = (b - 10240)*256 + tid;
    int s = i >> 5, d = i & 31;
    float inv = __expf(-(float)d * (9.210340371976184f / 32.0f));
    float f = (float)s * inv;
    ct[i] = cosf(f);
    st[i] = sinf(f);
  }
}

// ---------------- gemmA: 128x384 tile, BK=32, 4-buffer counted-vmcnt ----------------
// qkv = x @ Wqkv^T + bias, bf16 out. M=2048 N=6144 K=2048.
// 8 waves (2Mx4N), per-wave 64x96 (mi=4, ni=6): reads/MFMA = 10/24 = 0.417.
// Grid 16x16 = 256 blocks = full CU coverage; bijective XCD swizzle.
// Uniform 4 loads/thread/tile; boundary wait vmcnt(8) (t+2,t+3 in flight).
// Rowpair swizzle: slot8 = ((row&1)*4+g) ^ ((row>>1)&7); linear gload_lds dest
// + inverse-swizzled global source + same XOR on reads.  Unrolled x4 so all
// LDS buffer offsets are compile-time.
__global__ __launch_bounds__(512, 1) void k_gemmA(const uint16_t* __restrict__ A,
                                                  const uint16_t* __restrict__ B,
                                                  const float* __restrict__ bias,
                                                  uint16_t* __restrict__ C){
  __shared__ uint16_t As[4*4096];    // [buf][64 rp][8 slot][8]   32 KB
  __shared__ uint16_t Bs[4*12288];   // [buf][192 rp][8 slot][8]  96 KB
  const int K = 2048, N = 6144;

  const int wg = blockIdx.x;
  const int lin = (wg & 7) * 32 + (wg >> 3);
  const int m0 = (lin & 15) * 128;
  const int n0 = (lin >> 4) * 384;

  const int tid = threadIdx.x;
  const int wid = tid >> 6, l = tid & 63;
  const int wm = wid >> 2, wn = wid & 3;       // 2 x 4 wave grid
  const int g = l >> 4, c = l & 15;

  // staging source (inverse-swizzled): rp = tid>>3, slot = tid&7
  const int rp_s = tid >> 3;
  const int s_s  = (tid & 7) ^ (rp_s & 7);
  const size_t srcA0 = (size_t)(m0 + rp_s*2 + (s_s >> 2)) * K + (s_s & 3) * 8;
  const size_t srcB0 = (size_t)(n0 + rp_s*2 + (s_s >> 2)) * K + (s_s & 3) * 8;
  // B chunks j=1,2 at +128 rows, +256 rows
  const size_t bstride = (size_t)128 * K;

  // read-side addressing
  const int pg   = ((c & 1) << 2) | g;
  const int slb  = (pg ^ ((c >> 1) & 7)) << 3;   // slot byte offset (elems)
  const int rpa0 = wm*32 + (c >> 1);             // rows wm*64 + c
  const int rpb0 = wn*48 + (c >> 1);             // rows wn*96 + c

  f32x4 acc[4][6] = {};
  const int NT = K >> 5;                         // 64

  // prologue: stage tiles 0,1,2 (4 loads each)
  #pragma unroll
  for (int t0 = 0; t0 < 3; ++t0) {
    g2l16(A + srcA0 + t0*32,             (void*)(As + t0*4096  + tid*8));
    g2l16(B + srcB0 + t0*32,             (void*)(Bs + t0*12288 + tid*8));
    g2l16(B + srcB0 + bstride + t0*32,   (void*)(Bs + t0*12288 + 4096 + tid*8));
    g2l16(B + srcB0 + 2*bstride + t0*32, (void*)(Bs + t0*12288 + 8192 + tid*8));
  }
  asm volatile("s_waitcnt vmcnt(8)" ::: "memory");
  __builtin_amdgcn_s_barrier();

  #pragma unroll 4
  for (int t = 0; t < NT; ++t) {
    const uint16_t* __restrict__ Ab = As + (t & 3)*4096;
    const uint16_t* __restrict__ Bb = Bs + (t & 3)*12288;
    const int t3 = t + 3;
    const bool pf = t3 < NT;
    const int a3 = (t3 & 3)*4096;
    const int b3 = (t3 & 3)*12288;

    // ---- phase 0: read 4 A + 3 B; stage A(t+3)+B0(t+3); MFMA 4x3
    short8 av[4], bv[3];
    #pragma unroll
    for (int mi = 0; mi < 4; ++mi)
      av[mi] = *(const short8*)&Ab[(rpa0 + mi*8)*64 + slb];
    #pragma unroll
    for (int ni = 0; ni < 3; ++ni)
      bv[ni] = *(const short8*)&Bb[(rpb0 + ni*8)*64 + slb];
    if (pf) {
      g2l16(A + srcA0 + t3*32, (void*)(As + a3 + tid*8));
      g2l16(B + srcB0 + t3*32, (void*)(Bs + b3 + tid*8));
    }
    __builtin_amdgcn_s_barrier();
    __builtin_amdgcn_s_setprio(1);
    #pragma unroll
    for (int mi = 0; mi < 4; ++mi)
      #pragma unroll
      for (int ni = 0; ni < 3; ++ni)
        acc[mi][ni] = __builtin_amdgcn_mfma_f32_16x16x32_bf16(av[mi], bv[ni], acc[mi][ni], 0, 0, 0);
    __builtin_amdgcn_s_setprio(0);
    __builtin_amdgcn_s_barrier();

    // ---- phase 1: read 3 B; stage B1,B2(t+3); MFMA 4x3 (reuse av)
    short8 bw[3];
    #pragma unroll
    for (int ni = 0; ni < 3; ++ni)
      bw[ni] = *(const short8*)&Bb[(rpb0 + (ni+3)*8)*64 + slb];
    if (pf) {
      g2l16(B + srcB0 + bstride + t3*32,   (void*)(Bs + b3 + 4096 + tid*8));
      g2l16(B + srcB0 + 2*bstride + t3*32, (void*)(Bs + b3 + 8192 + tid*8));
    }
    __builtin_amdgcn_s_barrier();
    __builtin_amdgcn_s_setprio(1);
    #pragma unroll
    for (int mi = 0; mi < 4; ++mi)
      #pragma unroll
      for (int ni = 0; ni < 3; ++ni)
        acc[mi][ni+3] = __builtin_amdgcn_mfma_f32_16x16x32_bf16(av[mi], bw[ni], acc[mi][ni+3], 0, 0, 0);
    __builtin_amdgcn_s_setprio(0);
    // counted boundary wait: t+1 resident, t+2/t+3 stay in flight
    asm volatile("s_waitcnt vmcnt(8)" ::: "memory");
    __builtin_amdgcn_s_barrier();
  }

  // epilogue: bias + bf16 store
  #pragma unroll
  for (int ni = 0; ni < 6; ++ni) {
    const int col = n0 + wn*96 + ni*16 + c;
    const float bvl = bias[col];
    #pragma unroll
    for (int mi = 0; mi < 4; ++mi) {
      const int row0 = m0 + wm*64 + mi*16 + g*4;
      #pragma unroll
      for (int j = 0; j < 4; ++j)
        C[(size_t)(row0 + j)*N + col] = f2b(acc[mi][ni][j] + bvl);
    }
  }
}

// ---------------- 128x128 GEMM, BK=32, 4-buffer counted-vmcnt, f32 out ----------------
// 8 waves (2Mx4N), per-wave 64x32 output. Grid (M/128)x(N/128) blocks. Unrolled x4.
__global__ __launch_bounds__(512, 1) void k_gemm128(const uint16_t* __restrict__ A,
                                                    const uint16_t* __restrict__ B,
                                                    const float* __restrict__ bias,
                                                    float* __restrict__ C,
                                                    int M, int N, int K, int nbm){
  __shared__ uint16_t As[4*4096];   // [buf][rp(64)][slot8][8]
  __shared__ uint16_t Bs[4*4096];

  const int nwg = gridDim.x;
  const int wg = blockIdx.x;
  const int lin = (wg & 7) * (nwg >> 3) + (wg >> 3);
  const int m0 = (lin % nbm) * 128;
  const int n0 = (lin / nbm) * 128;

  const int tid = threadIdx.x;
  const int wid = tid >> 6, l = tid & 63;
  const int wm = wid >> 2, wn = wid & 3;
  const int g = l >> 4, c = l & 15;

  const int rp_s = tid >> 3, q_s = tid & 7, s_s = q_s ^ (rp_s & 7);
  const int srcA = (m0 + rp_s*2 + (s_s >> 2)) * K + (s_s & 3) * 8;
  const int srcB = (n0 + rp_s*2 + (s_s >> 2)) * K + (s_s & 3) * 8;

  const int pg  = ((c & 1) << 2) | g;
  const int slb = (pg ^ ((c >> 1) & 7)) << 3;
  const int ra0 = wm*32 + (c >> 1);            // rows wm*64+c
  const int rb0 = wn*16 + (c >> 1);            // rows wn*32+c

  f32x4 acc[4][2] = {};
  const int NT = K >> 5;

  #pragma unroll
  for (int t0 = 0; t0 < 3; ++t0) {
    g2l16(A + srcA + t0*32, (void*)(As + t0*4096 + tid*8));
    g2l16(B + srcB + t0*32, (void*)(Bs + t0*4096 + tid*8));
  }
  asm volatile("s_waitcnt vmcnt(4)" ::: "memory");
  __builtin_amdgcn_s_barrier();

  #pragma unroll 4
  for (int t = 0; t < NT; ++t) {
    const uint16_t* __restrict__ Ab = As + (t & 3)*4096;
    const uint16_t* __restrict__ Bb = Bs + (t & 3)*4096;
    const int t3 = t + 3;
    const int b3 = (t3 & 3)*4096;

    short8 av[4], bv[2];
    #pragma unroll
    for (int mi = 0; mi < 4; ++mi)
      av[mi] = *(const short8*)&Ab[(ra0 + mi*8)*64 + slb];
    #pragma unroll
    for (int ni = 0; ni < 2; ++ni)
      bv[ni] = *(const short8*)&Bb[(rb0 + ni*8)*64 + slb];
    if (t3 < NT) {
      g2l16(A + srcA + t3*32, (void*)(As + b3 + tid*8));
      g2l16(B + srcB + t3*32, (void*)(Bs + b3 + tid*8));
    }
    __builtin_amdgcn_s_barrier();
    __builtin_amdgcn_s_setprio(1);
    #pragma unroll
    for (int mi = 0; mi < 4; ++mi)
      #pragma unroll
      for (int ni = 0; ni < 2; ++ni)
        acc[mi][ni] = __builtin_amdgcn_mfma_f32_16x16x32_bf16(av[mi], bv[ni], acc[mi][ni], 0, 0, 0);
    __builtin_amdgcn_s_setprio(0);
    asm volatile("s_waitcnt vmcnt(4)" ::: "memory");
    __builtin_amdgcn_s_barrier();
  }

  #pragma unroll
  for (int ni = 0; ni < 2; ++ni) {
    const int col = n0 + wn*32 + ni*16 + c;
    const float bvl = bias[col];
    #pragma unroll
    for (int mi = 0; mi < 4; ++mi) {
      const int row0 = m0 + wm*64 + mi*16 + g*4;
      #pragma unroll
      for (int j = 0; j < 4; ++j)
        C[(size_t)(row0 + j)*N + col] = acc[mi][ni][j] + bvl;
    }
  }
}

// ---------------- fused RoPE head-split (Q,K) + V transpose ----------------
// blocks 0..4095: rope; blocks 4096..5119: vt
__global__ __launch_bounds__(256) void k_rope_vt(const uint16_t* __restrict__ qkv,
                                                 const float* __restrict__ ct,
                                                 const float* __restrict__ st,
                                                 uint16_t* __restrict__ qo,
                                                 uint16_t* __restrict__ ko,
                                                 uint16_t* __restrict__ vt){
  const int blk = blockIdx.x, tid = threadIdx.x;
  if (blk < 4096) {
    int idx = blk * 256 + tid;   // which(2) x h(16) x s(2048) x db(16)
    int db = idx & 15;
    int s  = (idx >> 4) & 2047;
    int h  = (idx >> 15) & 15;
    int which = idx >> 19;
    const uint16_t* src = qkv + (size_t)s * QKV_N + which * 2048 + h * 128;
    uint16_t* dst = (which ? ko : qo) + (((size_t)(h*2048 + s)) << 7) + db*8;
    const float scale = which ? 1.0f : ATT_SCALE;
    int d0 = db * 8;
    union { short8 v; uint16_t u[8]; } o;
    if (d0 >= 64) {
      short8 xv = *(const short8*)(src + d0);
      #pragma unroll
      for (int e = 0; e < 8; ++e) o.u[e] = f2b(b2f((uint16_t)xv[e]) * scale);
    } else {
      int dd = d0 & 31;
      short8 a = *(const short8*)(src + dd);
      short8 b = *(const short8*)(src + dd + 32);
      float4 c0 = *(const float4*)(ct + s*32 + dd);
      float4 c1 = *(const float4*)(ct + s*32 + dd + 4);
      float4 s0 = *(const float4*)(st + s*32 + dd);
      float4 s1 = *(const float4*)(st + s*32 + dd + 4);
      float cc[8] = {c0.x,c0.y,c0.z,c0.w,c1.x,c1.y,c1.z,c1.w};
      float ss[8] = {s0.x,s0.y,s0.z,s0.w,s1.x,s1.y,s1.z,s1.w};
      #pragma unroll
      for (int e = 0; e < 8; ++e) {
        float x1 = b2f((uint16_t)a[e]), x2 = b2f((uint16_t)b[e]);
        float v = (d0 < 32) ? (x1*cc[e] - x2*ss[e]) : (x1*ss[e] + x2*cc[e]);
        o.u[e] = f2b(v * scale);
      }
    }
    *(short8*)dst = o.v;
  } else {
    __shared__ uint16_t tl[64][80];
    const int b = blk - 4096;               // h(16) x dt(2) x st(32)
    const int st_ = b & 31, dt = (b >> 5) & 1, h = b >> 6;
    const int s_l = tid >> 2, cch = (tid & 3) * 16;
    const uint16_t* src = qkv + (size_t)(st_*64 + s_l) * QKV_N + 4096 + h*128 + dt*64 + cch;
    short8 a = *(const short8*)src;
    short8 b2 = *(const short8*)(src + 8);
    #pragma unroll
    for (int e = 0; e < 8; ++e) {
      tl[cch + e][s_l]     = (uint16_t)a[e];
      tl[cch + 8 + e][s_l] = (uint16_t)b2[e];
    }
    __syncthreads();
    const int d_l = tid >> 2;
    uint16_t* dst = vt + ((size_t)h << 18) + (size_t)(dt*64 + d_l) * 2048 + st_*64 + cch;
    *(short8*)dst       = *(const short8*)&tl[d_l][cch];
    *(short8*)(dst + 8) = *(const short8*)&tl[d_l][cch + 8];
  }
}

// ---------------- causal flash attention v4: 8 waves, even/odd KV split ----------------
__global__ __launch_bounds__(512, 1) void k_attn(const uint16_t* __restrict__ Q,
                                                 const uint16_t* __restrict__ Kb,
                                                 const uint16_t* __restrict__ Vtg,
                                                 uint16_t* __restrict__ Out){
  __shared__ uint16_t Ks[2][2][64*128];   // [group][buf][k][d], swizzled
  __shared__ uint16_t Vs[2][2][128*64];   // [group][buf][d][k], swizzled
  __shared__ uint16_t Ps[8][16*88];       // per-wave P [q][k], stride 88

  const int bid = blockIdx.x;             // 256 blocks
  const int lin = (bid & 7) * 32 + (bid >> 3);
  const int h = lin >> 4;                 // XCD x gets heads {2x, 2x+1}
  const int pair = lin & 15;              // fold-pair within head

  const int tid = threadIdx.x, w = tid >> 6, l = tid & 63;
  const int gid = w >> 2, wq = w & 3;     // group, wave-in-group
  const int tg = tid & 255;               // thread index within group
  const int g = l >> 4, c = l & 15;
  const int swz = (c & 7) << 4;           // read-side byte swizzle

  const uint16_t* __restrict__ Qh = Q   + ((size_t)h << 18);
  const uint16_t* __restrict__ Kh = Kb  + ((size_t)h << 18);
  const uint16_t* __restrict__ Vh = Vtg + ((size_t)h << 18);
  float* scratch = (float*)&Ks[0][0][0];  // merge scratch (safe after last barrier)

  int koff[4], voff[4];
  #pragma unroll
  for (int j = 0; j < 4; ++j) {
    int kr = j*16 + (tg >> 4);                           // K row in tile
    koff[j] = kr*128 + (((tg & 15) ^ (kr & 7)) << 3);
    int vd = j*32 + (tg >> 3);                           // V^T row (d)
    voff[j] = vd*2048 + (((tg & 7) ^ (vd & 7)) << 3);
  }

  uint16_t* KsG = &Ks[gid][0][0];   // my group's K buffers (2 x 8192 elems)
  uint16_t* VsG = &Vs[gid][0][0];

  #pragma unroll 1
  for (int half = 0; half < 2; ++half) {
    const int qt = half ? (31 - pair) : pair;   // 64-row q-tile index
    const int nt = qt + 1;                      // KV tiles (KVBLK=64)
    const int nsteps = (nt + 1) >> 1;
    const int qrow = qt*64 + wq*16 + c;

    short8 qf[4];
    #pragma unroll
    for (int t = 0; t < 4; ++t)
      qf[t] = *(const short8*)&Qh[(size_t)qrow*128 + t*32 + g*8];

    f32x4 acc[8] = {};
    float mrow[4], lrow[4];
    #pragma unroll
    for (int j = 0; j < 4; ++j) { mrow[j] = -3e38f; lrow[j] = 0.0f; }

    if (gid < nt) {
      #pragma unroll
      for (int j = 0; j < 4; ++j) {
        g2l16(Kh + (size_t)gid*8192 + koff[j], (void*)(KsG + j*2048 + tg*8));
        g2l16(Vh + gid*64 + voff[j],           (void*)(VsG + j*2048 + tg*8));
      }
    }
    asm volatile("s_waitcnt vmcnt(0)" ::: "memory");
    __syncthreads();

    #pragma unroll 1
    for (int step = 0; step < nsteps; ++step) {
      const int kt = 2*step + gid;
      const int cur = step & 1;
      if (kt + 2 < nt) {
        const int k1 = kt + 2;
        #pragma unroll
        for (int j = 0; j < 4; ++j) {
          g2l16(Kh + (size_t)k1*8192 + koff[j], (void*)(KsG + (cur^1)*8192 + j*2048 + tg*8));
          g2l16(Vh + k1*64 + voff[j],           (void*)(VsG + (cur^1)*8192 + j*2048 + tg*8));
        }
      }

      if (kt < nt) {
        const int k0 = kt * 64;
        const uint16_t* Kcur = KsG + cur*8192;
        const uint16_t* Vcur = VsG + cur*8192;

        f32x4 sc4[4] = {};
        #pragma unroll
        for (int ct2 = 0; ct2 < 4; ++ct2) {
          const char* krp = (const char*)Kcur + (ct2*16 + c)*256;
          #pragma unroll
          for (int t = 0; t < 4; ++t) {
            short8 kb = *(const short8*)(krp + ((t*64 + g*16) ^ swz));
            sc4[ct2] = __builtin_amdgcn_mfma_f32_16x16x32_bf16(qf[t], kb, sc4[ct2], 0, 0, 0);
          }
        }

        const bool lastt = (kt == nt - 1);
        #pragma unroll
        for (int j = 0; j < 4; ++j) {
          const int qg = qt*64 + wq*16 + g*4 + j;
          float v0 = sc4[0][j], v1 = sc4[1][j], v2 = sc4[2][j], v3 = sc4[3][j];
          if (lastt) {
            if (k0 +      c > qg) v0 = -3e38f;
            if (k0 + 16 + c > qg) v1 = -3e38f;
            if (k0 + 32 + c > qg) v2 = -3e38f;
            if (k0 + 48 + c > qg) v3 = -3e38f;
          }
          float t0 = fmaxf(fmaxf(v0, v1), fmaxf(v2, v3));
          #pragma unroll
          for (int d2 = 1; d2 < 16; d2 <<= 1) t0 = fmaxf(t0, __shfl_xor(t0, d2, 64));
          const float mn = fmaxf(mrow[j], t0);
          const float scl = __expf(mrow[j] - mn);
          const float p0 = __expf(v0 - mn), p1 = __expf(v1 - mn),
                      p2 = __expf(v2 - mn), p3 = __expf(v3 - mn);
          float rs = (p0 + p1) + (p2 + p3);
          #pragma unroll
          for (int d2 = 1; d2 < 16; d2 <<= 1) rs += __shfl_xor(rs, d2, 64);
          lrow[j] = lrow[j]*scl + rs;
          mrow[j] = mn;
          #pragma unroll
          for (int n = 0; n < 8; ++n) acc[n][j] *= scl;
          uint16_t* pw = &Ps[w][(g*4 + j)*88];
          pw[c] = f2b(p0); pw[16+c] = f2b(p1); pw[32+c] = f2b(p2); pw[48+c] = f2b(p3);
        }

        #pragma unroll
        for (int kk = 0; kk < 2; ++kk) {
          short8 pf = *(const short8*)&Ps[w][c*88 + kk*32 + g*8];
          #pragma unroll
          for (int n = 0; n < 8; ++n) {
            const char* vrp = (const char*)Vcur + (n*16 + c)*128;
            short8 vf = *(const short8*)(vrp + ((kk*64 + g*16) ^ swz));
            acc[n] = __builtin_amdgcn_mfma_f32_16x16x32_bf16(pf, vf, acc[n], 0, 0, 0);
          }
        }
      }

      asm volatile("s_waitcnt vmcnt(0)" ::: "memory");
      __syncthreads();
    }

    // ---- merge group partial states: B (gid=1) publishes, A (gid=0) combines ----
    float* Up = scratch + wq * 2112;      // U[16][128] + m[16] + l[16]
    if (gid == 1) {
      #pragma unroll
      for (int j = 0; j < 4; ++j) {
        const int row = g*4 + j;
        #pragma unroll
        for (int n = 0; n < 8; ++n)
          Up[row*128 + n*16 + c] = acc[n][j];
        if (c == 0) { Up[2048 + row] = mrow[j]; Up[2064 + row] = lrow[j]; }
      }
    }
    __syncthreads();
    if (gid == 0) {
      #pragma unroll
      for (int j = 0; j < 4; ++j) {
        const int row = g*4 + j;
        const int qg = qt*64 + wq*16 + row;
        const float mB = Up[2048 + row], lB = Up[2064 + row];
        const float mn = fmaxf(mrow[j], mB);
        const float e1 = __expf(mrow[j] - mn);
        const float e2 = __expf(mB - mn);
        const float inv = 1.0f / (lrow[j]*e1 + lB*e2);
        #pragma unroll
        for (int n = 0; n < 8; ++n) {
          const float u = acc[n][j]*e1 + Up[row*128 + n*16 + c]*e2;
          Out[(size_t)qg*2048 + h*128 + n*16 + c] = f2b(u * inv);
        }
      }
    }
    __syncthreads();   // protect scratch before next half's staging overwrites K bufs
  }
}

extern "C" void kernel_launch(void* const* d_in, const int* in_sizes, int n_in,
                              void* d_out, int out_size, void* d_ws, size_t ws_size,
                              hipStream_t stream){
  const float* x    = (const float*)d_in[0];
  const float* Wqkv = (const float*)d_in[1];
  const float* bqkv = (const float*)d_in[2];
  const float* Wo   = (const float*)d_in[3];
  const float* bo   = (const float*)d_in[4];

  char* ws = (char*)d_ws;
  uint16_t* q_bf    = (uint16_t*)(ws);                 //  8.39 MB [16][2048][128]
  uint16_t* k_bf    = (uint16_t*)(ws + 8388608);       //  8.39 MB [16][2048][128]
  uint16_t* vt_bf   = (uint16_t*)(ws + 16777216);      //  8.39 MB [16][128][2048]
  uint16_t* attn_bf = (uint16_t*)(ws + 25165824);      //  8.39 MB (aliased with x_bf)
  uint16_t* x_bf    = attn_bf;                         //  x dead before attn writes
  uint16_t* wqkv_bf = (uint16_t*)(ws + 33554432);      // 25.17 MB
  uint16_t* wo_bf   = (uint16_t*)(ws + 58720256);      //  8.39 MB
  uint16_t* qkv_bf  = (uint16_t*)(ws + 67108864);      // 25.17 MB
  float*    cos_t   = (float*)(ws + 92274688);         //  0.26 MB
  float*    sin_t   = (float*)(ws + 92536832);         //  0.26 MB

  // fused converts + tables
  k_prep<<<dim3(10496), dim3(256), 0, stream>>>(x, Wqkv, Wo, x_bf, wqkv_bf, wo_bf,
                                                cos_t, sin_t);
  // qkv = x @ Wqkv^T + b   -> bf16 [2048][6144]  (128x384 tiles, 256 blocks)
  k_gemmA<<<dim3(256), dim3(512), 0, stream>>>(x_bf, wqkv_bf, bqkv, qkv_bf);
  // RoPE + split Q,K (Q pre-scaled) + V transpose to [h][d][s]
  k_rope_vt<<<dim3(5120), dim3(256), 0, stream>>>(qkv_bf, cos_t, sin_t, q_bf, k_bf, vt_bf);
  // causal flash attention -> attn_bf [2048][2048]
  k_attn<<<dim3(256), dim3(512), 0, stream>>>(q_bf, k_bf, vt_bf, attn_bf);
  // out = attn @ Wo^T + bo -> f32 d_out (128^2 pipeline, 256 blocks)
  k_gemm128<<<dim3(256), dim3(512), 0, stream>>>(attn_bf, wo_bf, bo, (float*)d_out,
                                                 2048, 2048, 2048, 16);
}

// Round 9
// 173.287 us; speedup vs baseline: 2.2361x; 1.0013x over previous
//
#include <hip/hip_runtime.h>
#include <stdint.h>

// Problem constants
#define QKV_N 6144
#define ATT_SCALE 0.08838834764831845f   // 1/sqrt(128)

typedef __attribute__((ext_vector_type(8))) short short8;   // 8 bf16 (4 VGPRs)
typedef __attribute__((ext_vector_type(4))) float f32x4;

__device__ __forceinline__ uint16_t f2b(float x){
  uint32_t u = __float_as_uint(x);
  uint32_t r = (u + 0x7fffu + ((u >> 16) & 1u)) >> 16;   // RNE
  return (uint16_t)r;
}
__device__ __forceinline__ float b2f(uint16_t h){
  return __uint_as_float(((uint32_t)h) << 16);
}
__device__ __forceinline__ void g2l16(const void* g, void* l){
  __builtin_amdgcn_global_load_lds((const __attribute__((address_space(1))) void*)g,
                                   (__attribute__((address_space(3))) void*)l, 16, 0, 0);
}

// ---------------- fused prep: fp32->bf16 converts + RoPE tables ----------------
__device__ __forceinline__ void cvt8(const float* __restrict__ in, uint16_t* __restrict__ out, int i){
  const float4* p = (const float4*)in;
  float4 a = p[2*i], b = p[2*i+1];
  union { short8 v; uint16_t u[8]; } o;
  o.u[0]=f2b(a.x); o.u[1]=f2b(a.y); o.u[2]=f2b(a.z); o.u[3]=f2b(a.w);
  o.u[4]=f2b(b.x); o.u[5]=f2b(b.y); o.u[6]=f2b(b.z); o.u[7]=f2b(b.w);
  ((short8*)out)[i] = o.v;
}

__global__ __launch_bounds__(256) void k_prep(const float* __restrict__ x,
                                              const float* __restrict__ wqkv,
                                              const float* __restrict__ wo,
                                              uint16_t* __restrict__ xb,
                                              uint16_t* __restrict__ wqkvb,
                                              uint16_t* __restrict__ wob,
                                              float* __restrict__ ct,
                                              float* __restrict__ st){
  const int b = blockIdx.x, tid = threadIdx.x;
  if (b < 2048) {                         // x: 4.19M elems
    cvt8(x, xb, b*256 + tid);
  } else if (b < 8192) {                  // Wqkv: 12.58M elems
    cvt8(wqkv, wqkvb, (b - 2048)*256 + tid);
  } else if (b < 10240) {                 // Wo: 4.19M elems
    cvt8(wo, wob, (b - 8192)*256 + tid);
  } else {                                // tables [2048][32]
    int i = (b - 10240)*256 + tid;
    int s = i >> 5, d = i & 31;
    float inv = __expf(-(float)d * (9.210340371976184f / 32.0f));
    float f = (float)s * inv;
    ct[i] = cosf(f);
    st[i] = sinf(f);
  }
}

// ---------------- gemmA: 128x384 tile, BK=32, 4-buffer counted-vmcnt ----------------
// qkv = x @ Wqkv^T + bias, bf16 out. M=2048 N=6144 K=2048.
// 8 waves (2Mx4N), per-wave 64x96 (mi=4, ni=6).
// m-clustered XCD map: XCD x owns m-panels {2x,2x+1} (A 1MB L2-resident,
// shared by 16 concurrent n-blocks); B streams (cross-XCD reuse via L3).
// Uniform 4 loads/thread/tile; boundary wait vmcnt(8) (t+2,t+3 in flight).
// Rowpair swizzle: slot8 = ((row&1)*4+g) ^ ((row>>1)&7).
__global__ __launch_bounds__(512, 1) void k_gemmA(const uint16_t* __restrict__ A,
                                                  const uint16_t* __restrict__ B,
                                                  const float* __restrict__ bias,
                                                  uint16_t* __restrict__ C){
  __shared__ uint16_t As[4*4096];    // [buf][64 rp][8 slot][8]   32 KB
  __shared__ uint16_t Bs[4*12288];   // [buf][192 rp][8 slot][8]  96 KB
  const int K = 2048, N = 6144;

  const int wg = blockIdx.x;
  const int xcd = wg & 7, bi = wg >> 3;
  const int m0 = (xcd*2 + (bi & 1)) * 128;     // XCD x: m-panels {2x, 2x+1}
  const int n0 = (bi >> 1) * 384;              // all 16 n-panels per XCD

  const int tid = threadIdx.x;
  const int wid = tid >> 6, l = tid & 63;
  const int wm = wid >> 2, wn = wid & 3;       // 2 x 4 wave grid
  const int g = l >> 4, c = l & 15;

  // staging source (inverse-swizzled): rp = tid>>3, slot = tid&7
  const int rp_s = tid >> 3;
  const int s_s  = (tid & 7) ^ (rp_s & 7);
  const size_t srcA0 = (size_t)(m0 + rp_s*2 + (s_s >> 2)) * K + (s_s & 3) * 8;
  const size_t srcB0 = (size_t)(n0 + rp_s*2 + (s_s >> 2)) * K + (s_s & 3) * 8;
  const size_t bstride = (size_t)128 * K;

  // read-side addressing
  const int pg   = ((c & 1) << 2) | g;
  const int slb  = (pg ^ ((c >> 1) & 7)) << 3;   // slot offset (elems)
  const int rpa0 = wm*32 + (c >> 1);             // rows wm*64 + c
  const int rpb0 = wn*48 + (c >> 1);             // rows wn*96 + c

  f32x4 acc[4][6] = {};
  const int NT = K >> 5;                         // 64

  // prologue: stage tiles 0,1,2 (4 loads each)
  #pragma unroll
  for (int t0 = 0; t0 < 3; ++t0) {
    g2l16(A + srcA0 + t0*32,             (void*)(As + t0*4096  + tid*8));
    g2l16(B + srcB0 + t0*32,             (void*)(Bs + t0*12288 + tid*8));
    g2l16(B + srcB0 + bstride + t0*32,   (void*)(Bs + t0*12288 + 4096 + tid*8));
    g2l16(B + srcB0 + 2*bstride + t0*32, (void*)(Bs + t0*12288 + 8192 + tid*8));
  }
  asm volatile("s_waitcnt vmcnt(8)" ::: "memory");
  __builtin_amdgcn_s_barrier();

  #pragma unroll 4
  for (int t = 0; t < NT; ++t) {
    const uint16_t* __restrict__ Ab = As + (t & 3)*4096;
    const uint16_t* __restrict__ Bb = Bs + (t & 3)*12288;
    const int t3 = t + 3;
    const bool pf = t3 < NT;
    const int a3 = (t3 & 3)*4096;
    const int b3 = (t3 & 3)*12288;

    // ---- phase 0: read 4 A + 3 B; stage A(t+3)+B0(t+3); MFMA 4x3
    short8 av[4], bv[3];
    #pragma unroll
    for (int mi = 0; mi < 4; ++mi)
      av[mi] = *(const short8*)&Ab[(rpa0 + mi*8)*64 + slb];
    #pragma unroll
    for (int ni = 0; ni < 3; ++ni)
      bv[ni] = *(const short8*)&Bb[(rpb0 + ni*8)*64 + slb];
    if (pf) {
      g2l16(A + srcA0 + t3*32, (void*)(As + a3 + tid*8));
      g2l16(B + srcB0 + t3*32, (void*)(Bs + b3 + tid*8));
    }
    __builtin_amdgcn_s_barrier();
    __builtin_amdgcn_s_setprio(1);
    #pragma unroll
    for (int mi = 0; mi < 4; ++mi)
      #pragma unroll
      for (int ni = 0; ni < 3; ++ni)
        acc[mi][ni] = __builtin_amdgcn_mfma_f32_16x16x32_bf16(av[mi], bv[ni], acc[mi][ni], 0, 0, 0);
    __builtin_amdgcn_s_setprio(0);
    __builtin_amdgcn_s_barrier();

    // ---- phase 1: read 3 B; stage B1,B2(t+3); MFMA 4x3 (reuse av)
    short8 bw[3];
    #pragma unroll
    for (int ni = 0; ni < 3; ++ni)
      bw[ni] = *(const short8*)&Bb[(rpb0 + (ni+3)*8)*64 + slb];
    if (pf) {
      g2l16(B + srcB0 + bstride + t3*32,   (void*)(Bs + b3 + 4096 + tid*8));
      g2l16(B + srcB0 + 2*bstride + t3*32, (void*)(Bs + b3 + 8192 + tid*8));
    }
    __builtin_amdgcn_s_barrier();
    __builtin_amdgcn_s_setprio(1);
    #pragma unroll
    for (int mi = 0; mi < 4; ++mi)
      #pragma unroll
      for (int ni = 0; ni < 3; ++ni)
        acc[mi][ni+3] = __builtin_amdgcn_mfma_f32_16x16x32_bf16(av[mi], bw[ni], acc[mi][ni+3], 0, 0, 0);
    __builtin_amdgcn_s_setprio(0);
    // counted boundary wait: t+1 resident, t+2/t+3 stay in flight
    asm volatile("s_waitcnt vmcnt(8)" ::: "memory");
    __builtin_amdgcn_s_barrier();
  }

  // epilogue: bias + bf16 store
  #pragma unroll
  for (int ni = 0; ni < 6; ++ni) {
    const int col = n0 + wn*96 + ni*16 + c;
    const float bvl = bias[col];
    #pragma unroll
    for (int mi = 0; mi < 4; ++mi) {
      const int row0 = m0 + wm*64 + mi*16 + g*4;
      #pragma unroll
      for (int j = 0; j < 4; ++j)
        C[(size_t)(row0 + j)*N + col] = f2b(acc[mi][ni][j] + bvl);
    }
  }
}

// ---------------- 128x128 GEMM, BK=32, 4-buffer counted-vmcnt, f32 out ----------------
// 8 waves (2Mx4N), per-wave 64x32 output. m-clustered XCD map (A L2-resident).
__global__ __launch_bounds__(512, 1) void k_gemm128(const uint16_t* __restrict__ A,
                                                    const uint16_t* __restrict__ B,
                                                    const float* __restrict__ bias,
                                                    float* __restrict__ C,
                                                    int M, int N, int K){
  __shared__ uint16_t As[4*4096];   // [buf][rp(64)][slot8][8]
  __shared__ uint16_t Bs[4*4096];

  const int wg = blockIdx.x;
  const int xcd = wg & 7, bi = wg >> 3;
  const int m0 = (xcd*2 + (bi & 1)) * 128;     // XCD x: m-panels {2x, 2x+1}
  const int n0 = (bi >> 1) * 128;              // all 16 n-panels per XCD

  const int tid = threadIdx.x;
  const int wid = tid >> 6, l = tid & 63;
  const int wm = wid >> 2, wn = wid & 3;
  const int g = l >> 4, c = l & 15;

  const int rp_s = tid >> 3, q_s = tid & 7, s_s = q_s ^ (rp_s & 7);
  const int srcA = (m0 + rp_s*2 + (s_s >> 2)) * K + (s_s & 3) * 8;
  const int srcB = (n0 + rp_s*2 + (s_s >> 2)) * K + (s_s & 3) * 8;

  const int pg  = ((c & 1) << 2) | g;
  const int slb = (pg ^ ((c >> 1) & 7)) << 3;
  const int ra0 = wm*32 + (c >> 1);            // rows wm*64+c
  const int rb0 = wn*16 + (c >> 1);            // rows wn*32+c

  f32x4 acc[4][2] = {};
  const int NT = K >> 5;

  #pragma unroll
  for (int t0 = 0; t0 < 3; ++t0) {
    g2l16(A + srcA + t0*32, (void*)(As + t0*4096 + tid*8));
    g2l16(B + srcB + t0*32, (void*)(Bs + t0*4096 + tid*8));
  }
  asm volatile("s_waitcnt vmcnt(4)" ::: "memory");
  __builtin_amdgcn_s_barrier();

  #pragma unroll 4
  for (int t = 0; t < NT; ++t) {
    const uint16_t* __restrict__ Ab = As + (t & 3)*4096;
    const uint16_t* __restrict__ Bb = Bs + (t & 3)*4096;
    const int t3 = t + 3;
    const int b3 = (t3 & 3)*4096;

    short8 av[4], bv[2];
    #pragma unroll
    for (int mi = 0; mi < 4; ++mi)
      av[mi] = *(const short8*)&Ab[(ra0 + mi*8)*64 + slb];
    #pragma unroll
    for (int ni = 0; ni < 2; ++ni)
      bv[ni] = *(const short8*)&Bb[(rb0 + ni*8)*64 + slb];
    if (t3 < NT) {
      g2l16(A + srcA + t3*32, (void*)(As + b3 + tid*8));
      g2l16(B + srcB + t3*32, (void*)(Bs + b3 + tid*8));
    }
    __builtin_amdgcn_s_barrier();
    __builtin_amdgcn_s_setprio(1);
    #pragma unroll
    for (int mi = 0; mi < 4; ++mi)
      #pragma unroll
      for (int ni = 0; ni < 2; ++ni)
        acc[mi][ni] = __builtin_amdgcn_mfma_f32_16x16x32_bf16(av[mi], bv[ni], acc[mi][ni], 0, 0, 0);
    __builtin_amdgcn_s_setprio(0);
    asm volatile("s_waitcnt vmcnt(4)" ::: "memory");
    __builtin_amdgcn_s_barrier();
  }

  #pragma unroll
  for (int ni = 0; ni < 2; ++ni) {
    const int col = n0 + wn*32 + ni*16 + c;
    const float bvl = bias[col];
    #pragma unroll
    for (int mi = 0; mi < 4; ++mi) {
      const int row0 = m0 + wm*64 + mi*16 + g*4;
      #pragma unroll
      for (int j = 0; j < 4; ++j)
        C[(size_t)(row0 + j)*N + col] = acc[mi][ni][j] + bvl;
    }
  }
}

// ---------------- fused RoPE head-split (Q,K) + V transpose ----------------
// blocks 0..4095: rope; blocks 4096..5119: vt
__global__ __launch_bounds__(256) void k_rope_vt(const uint16_t* __restrict__ qkv,
                                                 const float* __restrict__ ct,
                                                 const float* __restrict__ st,
                                                 uint16_t* __restrict__ qo,
                                                 uint16_t* __restrict__ ko,
                                                 uint16_t* __restrict__ vt){
  const int blk = blockIdx.x, tid = threadIdx.x;
  if (blk < 4096) {
    int idx = blk * 256 + tid;   // which(2) x h(16) x s(2048) x db(16)
    int db = idx & 15;
    int s  = (idx >> 4) & 2047;
    int h  = (idx >> 15) & 15;
    int which = idx >> 19;
    const uint16_t* src = qkv + (size_t)s * QKV_N + which * 2048 + h * 128;
    uint16_t* dst = (which ? ko : qo) + (((size_t)(h*2048 + s)) << 7) + db*8;
    const float scale = which ? 1.0f : ATT_SCALE;
    int d0 = db * 8;
    union { short8 v; uint16_t u[8]; } o;
    if (d0 >= 64) {
      short8 xv = *(const short8*)(src + d0);
      #pragma unroll
      for (int e = 0; e < 8; ++e) o.u[e] = f2b(b2f((uint16_t)xv[e]) * scale);
    } else {
      int dd = d0 & 31;
      short8 a = *(const short8*)(src + dd);
      short8 b = *(const short8*)(src + dd + 32);
      float4 c0 = *(const float4*)(ct + s*32 + dd);
      float4 c1 = *(const float4*)(ct + s*32 + dd + 4);
      float4 s0 = *(const float4*)(st + s*32 + dd);
      float4 s1 = *(const float4*)(st + s*32 + dd + 4);
      float cc[8] = {c0.x,c0.y,c0.z,c0.w,c1.x,c1.y,c1.z,c1.w};
      float ss[8] = {s0.x,s0.y,s0.z,s0.w,s1.x,s1.y,s1.z,s1.w};
      #pragma unroll
      for (int e = 0; e < 8; ++e) {
        float x1 = b2f((uint16_t)a[e]), x2 = b2f((uint16_t)b[e]);
        float v = (d0 < 32) ? (x1*cc[e] - x2*ss[e]) : (x1*ss[e] + x2*cc[e]);
        o.u[e] = f2b(v * scale);
      }
    }
    *(short8*)dst = o.v;
  } else {
    __shared__ uint16_t tl[64][80];
    const int b = blk - 4096;               // h(16) x dt(2) x st(32)
    const int st_ = b & 31, dt = (b >> 5) & 1, h = b >> 6;
    const int s_l = tid >> 2, cch = (tid & 3) * 16;
    const uint16_t* src = qkv + (size_t)(st_*64 + s_l) * QKV_N + 4096 + h*128 + dt*64 + cch;
    short8 a = *(const short8*)src;
    short8 b2 = *(const short8*)(src + 8);
    #pragma unroll
    for (int e = 0; e < 8; ++e) {
      tl[cch + e][s_l]     = (uint16_t)a[e];
      tl[cch + 8 + e][s_l] = (uint16_t)b2[e];
    }
    __syncthreads();
    const int d_l = tid >> 2;
    uint16_t* dst = vt + ((size_t)h << 18) + (size_t)(dt*64 + d_l) * 2048 + st_*64 + cch;
    *(short8*)dst       = *(const short8*)&tl[d_l][cch];
    *(short8*)(dst + 8) = *(const short8*)&tl[d_l][cch + 8];
  }
}

// ---------------- causal flash attention v4: 8 waves, even/odd KV split ----------------
__global__ __launch_bounds__(512, 1) void k_attn(const uint16_t* __restrict__ Q,
                                                 const uint16_t* __restrict__ Kb,
                                                 const uint16_t* __restrict__ Vtg,
                                                 uint16_t* __restrict__ Out){
  __shared__ uint16_t Ks[2][2][64*128];   // [group][buf][k][d], swizzled
  __shared__ uint16_t Vs[2][2][128*64];   // [group][buf][d][k], swizzled
  __shared__ uint16_t Ps[8][16*88];       // per-wave P [q][k], stride 88

  const int bid = blockIdx.x;             // 256 blocks
  const int lin = (bid & 7) * 32 + (bid >> 3);
  const int h = lin >> 4;                 // XCD x gets heads {2x, 2x+1}
  const int pair = lin & 15;              // fold-pair within head

  const int tid = threadIdx.x, w = tid >> 6, l = tid & 63;
  const int gid = w >> 2, wq = w & 3;     // group, wave-in-group
  const int tg = tid & 255;               // thread index within group
  const int g = l >> 4, c = l & 15;
  const int swz = (c & 7) << 4;           // read-side byte swizzle

  const uint16_t* __restrict__ Qh = Q   + ((size_t)h << 18);
  const uint16_t* __restrict__ Kh = Kb  + ((size_t)h << 18);
  const uint16_t* __restrict__ Vh = Vtg + ((size_t)h << 18);
  float* scratch = (float*)&Ks[0][0][0];  // merge scratch (safe after last barrier)

  int koff[4], voff[4];
  #pragma unroll
  for (int j = 0; j < 4; ++j) {
    int kr = j*16 + (tg >> 4);                           // K row in tile
    koff[j] = kr*128 + (((tg & 15) ^ (kr & 7)) << 3);
    int vd = j*32 + (tg >> 3);                           // V^T row (d)
    voff[j] = vd*2048 + (((tg & 7) ^ (vd & 7)) << 3);
  }

  uint16_t* KsG = &Ks[gid][0][0];   // my group's K buffers (2 x 8192 elems)
  uint16_t* VsG = &Vs[gid][0][0];

  #pragma unroll 1
  for (int half = 0; half < 2; ++half) {
    const int qt = half ? (31 - pair) : pair;   // 64-row q-tile index
    const int nt = qt + 1;                      // KV tiles (KVBLK=64)
    const int nsteps = (nt + 1) >> 1;
    const int qrow = qt*64 + wq*16 + c;

    short8 qf[4];
    #pragma unroll
    for (int t = 0; t < 4; ++t)
      qf[t] = *(const short8*)&Qh[(size_t)qrow*128 + t*32 + g*8];

    f32x4 acc[8] = {};
    float mrow[4], lrow[4];
    #pragma unroll
    for (int j = 0; j < 4; ++j) { mrow[j] = -3e38f; lrow[j] = 0.0f; }

    if (gid < nt) {
      #pragma unroll
      for (int j = 0; j < 4; ++j) {
        g2l16(Kh + (size_t)gid*8192 + koff[j], (void*)(KsG + j*2048 + tg*8));
        g2l16(Vh + gid*64 + voff[j],           (void*)(VsG + j*2048 + tg*8));
      }
    }
    asm volatile("s_waitcnt vmcnt(0)" ::: "memory");
    __syncthreads();

    #pragma unroll 1
    for (int step = 0; step < nsteps; ++step) {
      const int kt = 2*step + gid;
      const int cur = step & 1;
      if (kt + 2 < nt) {
        const int k1 = kt + 2;
        #pragma unroll
        for (int j = 0; j < 4; ++j) {
          g2l16(Kh + (size_t)k1*8192 + koff[j], (void*)(KsG + (cur^1)*8192 + j*2048 + tg*8));
          g2l16(Vh + k1*64 + voff[j],           (void*)(VsG + (cur^1)*8192 + j*2048 + tg*8));
        }
      }

      if (kt < nt) {
        const int k0 = kt * 64;
        const uint16_t* Kcur = KsG + cur*8192;
        const uint16_t* Vcur = VsG + cur*8192;

        f32x4 sc4[4] = {};
        #pragma unroll
        for (int ct2 = 0; ct2 < 4; ++ct2) {
          const char* krp = (const char*)Kcur + (ct2*16 + c)*256;
          #pragma unroll
          for (int t = 0; t < 4; ++t) {
            short8 kb = *(const short8*)(krp + ((t*64 + g*16) ^ swz));
            sc4[ct2] = __builtin_amdgcn_mfma_f32_16x16x32_bf16(qf[t], kb, sc4[ct2], 0, 0, 0);
          }
        }

        const bool lastt = (kt == nt - 1);
        #pragma unroll
        for (int j = 0; j < 4; ++j) {
          const int qg = qt*64 + wq*16 + g*4 + j;
          float v0 = sc4[0][j], v1 = sc4[1][j], v2 = sc4[2][j], v3 = sc4[3][j];
          if (lastt) {
            if (k0 +      c > qg) v0 = -3e38f;
            if (k0 + 16 + c > qg) v1 = -3e38f;
            if (k0 + 32 + c > qg) v2 = -3e38f;
            if (k0 + 48 + c > qg) v3 = -3e38f;
          }
          float t0 = fmaxf(fmaxf(v0, v1), fmaxf(v2, v3));
          #pragma unroll
          for (int d2 = 1; d2 < 16; d2 <<= 1) t0 = fmaxf(t0, __shfl_xor(t0, d2, 64));
          const float mn = fmaxf(mrow[j], t0);
          const float scl = __expf(mrow[j] - mn);
          const float p0 = __expf(v0 - mn), p1 = __expf(v1 - mn),
                      p2 = __expf(v2 - mn), p3 = __expf(v3 - mn);
          float rs = (p0 + p1) + (p2 + p3);
          #pragma unroll
          for (int d2 = 1; d2 < 16; d2 <<= 1) rs += __shfl_xor(rs, d2, 64);
          lrow[j] = lrow[j]*scl + rs;
          mrow[j] = mn;
          #pragma unroll
          for (int n = 0; n < 8; ++n) acc[n][j] *= scl;
          uint16_t* pw = &Ps[w][(g*4 + j)*88];
          pw[c] = f2b(p0); pw[16+c] = f2b(p1); pw[32+c] = f2b(p2); pw[48+c] = f2b(p3);
        }

        #pragma unroll
        for (int kk = 0; kk < 2; ++kk) {
          short8 pf = *(const short8*)&Ps[w][c*88 + kk*32 + g*8];
          #pragma unroll
          for (int n = 0; n < 8; ++n) {
            const char* vrp = (const char*)Vcur + (n*16 + c)*128;
            short8 vf = *(const short8*)(vrp + ((kk*64 + g*16) ^ swz));
            acc[n] = __builtin_amdgcn_mfma_f32_16x16x32_bf16(pf, vf, acc[n], 0, 0, 0);
          }
        }
      }

      asm volatile("s_waitcnt vmcnt(0)" ::: "memory");
      __syncthreads();
    }

    // ---- merge group partial states: B (gid=1) publishes, A (gid=0) combines ----
    float* Up = scratch + wq * 2112;      // U[16][128] + m[16] + l[16]
    if (gid == 1) {
      #pragma unroll
      for (int j = 0; j < 4; ++j) {
        const int row = g*4 + j;
        #pragma unroll
        for (int n = 0; n < 8; ++n)
          Up[row*128 + n*16 + c] = acc[n][j];
        if (c == 0) { Up[2048 + row] = mrow[j]; Up[2064 + row] = lrow[j]; }
      }
    }
    __syncthreads();
    if (gid == 0) {
      #pragma unroll
      for (int j = 0; j < 4; ++j) {
        const int row = g*4 + j;
        const int qg = qt*64 + wq*16 + row;
        const float mB = Up[2048 + row], lB = Up[2064 + row];
        const float mn = fmaxf(mrow[j], mB);
        const float e1 = __expf(mrow[j] - mn);
        const float e2 = __expf(mB - mn);
        const float inv = 1.0f / (lrow[j]*e1 + lB*e2);
        #pragma unroll
        for (int n = 0; n < 8; ++n) {
          const float u = acc[n][j]*e1 + Up[row*128 + n*16 + c]*e2;
          Out[(size_t)qg*2048 + h*128 + n*16 + c] = f2b(u * inv);
        }
      }
    }
    __syncthreads();   // protect scratch before next half's staging overwrites K bufs
  }
}

extern "C" void kernel_launch(void* const* d_in, const int* in_sizes, int n_in,
                              void* d_out, int out_size, void* d_ws, size_t ws_size,
                              hipStream_t stream){
  const float* x    = (const float*)d_in[0];
  const float* Wqkv = (const float*)d_in[1];
  const float* bqkv = (const float*)d_in[2];
  const float* Wo   = (const float*)d_in[3];
  const float* bo   = (const float*)d_in[4];

  char* ws = (char*)d_ws;
  uint16_t* q_bf    = (uint16_t*)(ws);                 //  8.39 MB [16][2048][128]
  uint16_t* k_bf    = (uint16_t*)(ws + 8388608);       //  8.39 MB [16][2048][128]
  uint16_t* vt_bf   = (uint16_t*)(ws + 16777216);      //  8.39 MB [16][128][2048]
  uint16_t* attn_bf = (uint16_t*)(ws + 25165824);      //  8.39 MB (aliased with x_bf)
  uint16_t* x_bf    = attn_bf;                         //  x dead before attn writes
  uint16_t* wqkv_bf = (uint16_t*)(ws + 33554432);      // 25.17 MB
  uint16_t* wo_bf   = (uint16_t*)(ws + 58720256);      //  8.39 MB
  uint16_t* qkv_bf  = (uint16_t*)(ws + 67108864);      // 25.17 MB
  float*    cos_t   = (float*)(ws + 92274688);         //  0.26 MB
  float*    sin_t   = (float*)(ws + 92536832);         //  0.26 MB

  // fused converts + tables
  k_prep<<<dim3(10496), dim3(256), 0, stream>>>(x, Wqkv, Wo, x_bf, wqkv_bf, wo_bf,
                                                cos_t, sin_t);
  // qkv = x @ Wqkv^T + b   -> bf16 [2048][6144]  (128x384 tiles, 256 blocks)
  k_gemmA<<<dim3(256), dim3(512), 0, stream>>>(x_bf, wqkv_bf, bqkv, qkv_bf);
  // RoPE + split Q,K (Q pre-scaled) + V transpose to [h][d][s]
  k_rope_vt<<<dim3(5120), dim3(256), 0, stream>>>(qkv_bf, cos_t, sin_t, q_bf, k_bf, vt_bf);
  // causal flash attention -> attn_bf [2048][2048]
  k_attn<<<dim3(256), dim3(512), 0, stream>>>(q_bf, k_bf, vt_bf, attn_bf);
  // out = attn @ Wo^T + bo -> f32 d_out (128^2 pipeline, 256 blocks)
  k_gemm128<<<dim3(256), dim3(512), 0, stream>>>(attn_bf, wo_bf, bo, (float*)d_out,
                                                 2048, 2048, 2048);
}